// Round 1
// baseline (2377.560 us; speedup 1.0000x reference)
//
#include <hip/hip_runtime.h>

#define B_    16
#define NTOK  256
#define D_    512
#define HEADS 16
#define DH    32
#define DEPTH 12
#define KCODE 2048
#define M_    (B_*NTOK)   // 4096 token rows
#define BN_S  512         // BN partial blocks

typedef __attribute__((ext_vector_type(8))) short short8;     // 8 bf16 (4 VGPRs)
typedef __attribute__((ext_vector_type(4))) float float4v;
typedef __attribute__((ext_vector_type(4))) unsigned int uint4v;
typedef __attribute__((ext_vector_type(2))) unsigned int uint2v;
typedef unsigned short ushort;

__device__ __forceinline__ ushort f2b(float f){   // fp32 -> bf16 RNE
  union { float f; unsigned u; } v; v.f = f;
  unsigned r = v.u + 0x7FFFu + ((v.u >> 16) & 1u);
  return (ushort)(r >> 16);
}
__device__ __forceinline__ float b2f(ushort h){
  union { unsigned u; float f; } v; v.u = ((unsigned)h) << 16; return v.f;
}
__device__ __forceinline__ float bits2f(unsigned u){
  union { unsigned u; float f; } v; v.u = u; return v.f;
}

// async global->LDS, 16B per lane; LDS dest = wave-uniform base + lane*16
typedef __attribute__((address_space(3))) unsigned int lds_uint;
typedef __attribute__((address_space(1))) const unsigned int glob_uint;
__device__ __forceinline__ void gl_lds16(const ushort* g, ushort* l){
  __builtin_amdgcn_global_load_lds((glob_uint*)g, (lds_uint*)l, 16, 0, 0);
}

// ---------------- prep kernels ----------------

__global__ void k_tok_init(const float* __restrict__ x, const float* __restrict__ pos,
                           float* __restrict__ tok){
  int i = blockIdx.x*256 + threadIdx.x;
  if (i >= B_*NTOK*D_) return;
  int d = i % D_; int r = i / D_; int t = r % NTOK; int b = r / NTOK;
  tok[i] = x[(b*D_ + d)*NTOK + t] + pos[t*D_ + d];
}

__global__ void k_split(const float* __restrict__ src, ushort* __restrict__ oh,
                        ushort* __restrict__ ol, int n){
  int i = blockIdx.x*256 + threadIdx.x;
  if (i >= n) return;
  float v = src[i];
  ushort h = f2b(v);
  oh[i] = h; ol[i] = f2b(v - b2f(h));
}

// split + transpose: src [L][K][N] f32 -> dst hi/lo [L][N][K] bf16
__global__ void k_split_t(const float* __restrict__ src, ushort* __restrict__ oh,
                          ushort* __restrict__ ol, int L, int K, int N){
  int i = blockIdx.x*256 + threadIdx.x;
  if (i >= L*K*N) return;
  int KN = K*N;
  int l = i / KN; int r = i - l*KN;
  int k = r / N;  int n = r - k*N;
  float v = src[i];
  ushort h = f2b(v);
  size_t o = (size_t)l*KN + (size_t)n*K + k;
  oh[o] = h; ol[o] = f2b(v - b2f(h));
}

// conv weights: [Cout][Cin][3][3] f32 -> W9 [9tap][Cout][Cin] bf16
__global__ void k_w9(const float* __restrict__ w, ushort* __restrict__ W9,
                     int Cin, int Cout){
  int i = blockIdx.x*256 + threadIdx.x;
  if (i >= Cout*Cin*9) return;
  int co = i / (Cin*9); int r = i - co*(Cin*9);
  int ci = r / 9; int tap = r - ci*9;
  W9[((size_t)tap*Cout + co)*Cin + ci] = f2b(w[i]);
}

// upconv weights: [Cin][Cout][2][2] f32 -> Wt4 [tap][Cout][Cin] bf16
__global__ void k_upw(const float* __restrict__ w, ushort* __restrict__ Wt4,
                      int Cin, int Cout){
  int i = blockIdx.x*256 + threadIdx.x;
  if (i >= Cin*Cout*4) return;
  int ci = i / (Cout*4); int r = i - ci*(Cout*4);
  int co = r >> 2; int tap = r & 3;
  Wt4[((size_t)tap*Cout + co)*Cin + ci] = f2b(w[i]);
}

// LayerNorm fused with bf16 hi/lo split
__global__ void k_ln_split(const float* __restrict__ in, ushort* __restrict__ oh,
                           ushort* __restrict__ ol, const float* __restrict__ g,
                           const float* __restrict__ bta){
  int row = blockIdx.x; int t = threadIdx.x;
  const float* xr = in + (size_t)row*D_;
  float x0 = xr[t], x1 = xr[t+256];
  __shared__ float r1[256], r2[256];
  r1[t] = x0+x1; r2[t] = x0*x0 + x1*x1;
  __syncthreads();
  for (int off=128; off>0; off>>=1){
    if (t<off){ r1[t]+=r1[t+off]; r2[t]+=r2[t+off]; }
    __syncthreads();
  }
  float mean = r1[0] * (1.f/D_);
  float var  = r2[0] * (1.f/D_) - mean*mean;
  float inv  = rsqrtf(var + 1e-5f);
  float y0 = (x0-mean)*inv*g[t]     + bta[t];
  float y1 = (x1-mean)*inv*g[t+256] + bta[t+256];
  size_t o = (size_t)row*D_;
  ushort h0 = f2b(y0), h1 = f2b(y1);
  oh[o+t] = h0;     ol[o+t]     = f2b(y0 - b2f(h0));
  oh[o+t+256] = h1; ol[o+t+256] = f2b(y1 - b2f(h1));
}

// ------ split-bf16 MFMA GEMM, 128x128 tile (3-term, fp32-accurate) ------
// C[M][N] = A[M][K] @ B^T (B as [N][K]); 4 waves, each 64x64 quadrant (4x4 accs).
// Staging via global_load_lds width=16 into LINEAR [128][32] LDS tiles.
// Bank-conflict fix: seg ^= (row>>1)&3 swizzle applied to the GLOBAL source
// address at stage time and to the read address (same involution both sides).
__global__ __launch_bounds__(256,2) void k_gemm_split(
    const ushort* __restrict__ Ah, const ushort* __restrict__ Al,
    const ushort* __restrict__ Bh, const ushort* __restrict__ Bl,
    float* __restrict__ C, const float* __restrict__ bias,
    const float* __restrict__ resid, int M, int N, int K){
  __shared__ ushort Ash[128][32], Asl[128][32], Bsh[128][32], Bsl[128][32];
  const int tid = threadIdx.x;
  const int m_base = blockIdx.x*128, n_base = blockIdx.y*128;
  const int lane = tid & 63, wv = tid >> 6;
  const int quad = lane >> 4, r16 = lane & 15;
  const int m_off = (wv & 1)*64, n_off = (wv >> 1)*64;
  // gload_lds staging: wave wv covers rows [wv*32, wv*32+32) of each buffer,
  // two 1KB issues of 16 rows each. lane covers (row = base+lane/4, seg = lane&3).
  const int lrow = lane >> 2, lseg = lane & 3;
  const int row0 = wv*32 + lrow;              // rows row0 and row0+16
  const int us   = lseg ^ ((row0 >> 1) & 3);  // (row0+16)>>1 has same &3
  const size_t offA0 = (size_t)(m_base + row0)*K + us*8;
  const size_t offA1 = offA0 + (size_t)16*K;
  const size_t offB0 = (size_t)(n_base + row0)*K + us*8;
  const size_t offB1 = offB0 + (size_t)16*K;
  ushort* lAh = &Ash[0][0] + wv*1024;   // wave-uniform LDS dest (shorts)
  ushort* lAl = &Asl[0][0] + wv*1024;
  ushort* lBh = &Bsh[0][0] + wv*1024;
  ushort* lBl = &Bsl[0][0] + wv*1024;
  float4v acc[4][4];
  #pragma unroll
  for (int i = 0; i < 4; ++i)
    #pragma unroll
    for (int j = 0; j < 4; ++j) acc[i][j] = float4v{0.f,0.f,0.f,0.f};
  for (int k0 = 0; k0 < K; k0 += 32){
    gl_lds16(Ah + offA0 + k0, lAh);
    gl_lds16(Ah + offA1 + k0, lAh + 512);
    gl_lds16(Al + offA0 + k0, lAl);
    gl_lds16(Al + offA1 + k0, lAl + 512);
    gl_lds16(Bh + offB0 + k0, lBh);
    gl_lds16(Bh + offB1 + k0, lBh + 512);
    gl_lds16(Bl + offB0 + k0, lBl);
    gl_lds16(Bl + offB1 + k0, lBl + 512);
    __syncthreads();   // drains vmcnt -> staged data visible
    short8 ah[4], al[4], bh[4], bl[4];
    #pragma unroll
    for (int i = 0; i < 4; ++i){
      int ra = m_off + i*16 + r16;
      int rb = n_off + i*16 + r16;
      int sa = (quad ^ ((ra >> 1) & 3))*8;
      int sb = (quad ^ ((rb >> 1) & 3))*8;
      ah[i] = *(const short8*)&Ash[ra][sa];
      al[i] = *(const short8*)&Asl[ra][sa];
      bh[i] = *(const short8*)&Bsh[rb][sb];
      bl[i] = *(const short8*)&Bsl[rb][sb];
    }
    #pragma unroll
    for (int i = 0; i < 4; ++i)
      #pragma unroll
      for (int j = 0; j < 4; ++j){
        acc[i][j] = __builtin_amdgcn_mfma_f32_16x16x32_bf16(bh[j], ah[i], acc[i][j], 0,0,0);
        acc[i][j] = __builtin_amdgcn_mfma_f32_16x16x32_bf16(bh[j], al[i], acc[i][j], 0,0,0);
        acc[i][j] = __builtin_amdgcn_mfma_f32_16x16x32_bf16(bl[j], ah[i], acc[i][j], 0,0,0);
      }
    __syncthreads();
  }
  #pragma unroll
  for (int i = 0; i < 4; ++i){
    int m = m_base + m_off + i*16 + r16;
    #pragma unroll
    for (int j = 0; j < 4; ++j){
      int n = n_base + n_off + j*16 + quad*4;
      float4v v = acc[i][j];
      if (bias)  v += *(const float4v*)(bias + n);
      if (resid) v += *(const float4v*)(resid + (size_t)m*N + n);
      *(float4v*)(C + (size_t)m*N + n) = v;
    }
  }
}

// ---------------- attention: one block per (b,h), K/V in LDS ----------------
// 512 threads: thread t and t+256 split the 256-token j-loop for query token
// (t&255); partials combined through the then-dead K/V LDS. 8 waves/CU.
__global__ __launch_bounds__(512) void k_attn2(const float* __restrict__ qkv,
                                               ushort* __restrict__ oh,
                                               ushort* __restrict__ ol){
  __shared__ float4v smem[NTOK*16];          // [0,2048)=K, [2048,4096)=V
  float4v* ks = smem;
  float4v* vs = smem + NTOK*8;
  const int h = blockIdx.x, b = blockIdx.y, t = threadIdx.x;
  const int tq = t & 255, half = t >> 8;
  const float* base = qkv + (size_t)b*NTOK*1536;
  const int koff = 512 + h*DH, voff = 1024 + h*DH;
  for (int i = t; i < NTOK*8; i += 512){
    int j = i >> 3, d4 = i & 7;
    ks[i] = *(const float4v*)(base + (size_t)j*1536 + koff + d4*4);
    vs[i] = *(const float4v*)(base + (size_t)j*1536 + voff + d4*4);
  }
  float4v q8[8];
  const float* qrow = base + (size_t)tq*1536 + h*DH;
  #pragma unroll
  for (int d4 = 0; d4 < 8; ++d4) q8[d4] = *(const float4v*)(qrow + d4*4);
  __syncthreads();
  float4v o8[8];
  #pragma unroll
  for (int d4 = 0; d4 < 8; ++d4) o8[d4] = float4v{0.f,0.f,0.f,0.f};
  float l = 0.f;
  const int j0 = half*128, j1 = j0 + 128;
  for (int j = j0; j < j1; ++j){
    float s = 0.f;
    #pragma unroll
    for (int d4 = 0; d4 < 8; ++d4){
      float4v kk = ks[j*8 + d4];
      s += q8[d4].x*kk.x + q8[d4].y*kk.y + q8[d4].z*kk.z + q8[d4].w*kk.w;
    }
    float e = __expf(s * 0.17677669529663689f);
    l += e;
    #pragma unroll
    for (int d4 = 0; d4 < 8; ++d4){
      float4v vv = vs[j*8 + d4];
      o8[d4].x += e*vv.x; o8[d4].y += e*vv.y; o8[d4].z += e*vv.z; o8[d4].w += e*vv.w;
    }
  }
  __syncthreads();                           // everyone done with K/V
  if (half){
    float4v* st = smem + (size_t)tq*9;       // stride 9 to dodge bank aliasing
    #pragma unroll
    for (int d4 = 0; d4 < 8; ++d4) st[d4] = o8[d4];
    ((float*)smem)[9216 + tq] = l;
  }
  __syncthreads();
  if (!half){
    const float4v* st = smem + (size_t)tq*9;
    #pragma unroll
    for (int d4 = 0; d4 < 8; ++d4) o8[d4] += st[d4];
    l += ((float*)smem)[9216 + tq];
    float inv = 1.f / l;
    size_t ob = (size_t)(b*NTOK + tq)*D_ + h*DH;
    #pragma unroll
    for (int d4 = 0; d4 < 8; ++d4){
      float vals[4] = {o8[d4].x*inv, o8[d4].y*inv, o8[d4].z*inv, o8[d4].w*inv};
      #pragma unroll
      for (int r = 0; r < 4; ++r){
        ushort hh = f2b(vals[r]);
        oh[ob + d4*4 + r] = hh;
        ol[ob + d4*4 + r] = f2b(vals[r] - b2f(hh));
      }
    }
  }
}

// ---------------- VQ ----------------
__global__ void k_cnorm(const float* __restrict__ cb, float* __restrict__ cnorm){
  int k = blockIdx.x, t = threadIdx.x;
  float v1 = cb[(size_t)k*D_ + t];
  float v2 = cb[(size_t)k*D_ + t + 256];
  __shared__ float r[256];
  r[t] = v1*v1 + v2*v2;
  __syncthreads();
  for (int off=128; off>0; off>>=1){
    if (t<off) r[t]+=r[t+off];
    __syncthreads();
  }
  if (t==0) cnorm[k] = r[0];
}

__global__ void k_argmin(const float* __restrict__ d2, const float* __restrict__ cnorm,
                         int* __restrict__ idx){
  int m = blockIdx.x, t = threadIdx.x;
  float best = 3.4e38f; int bk = 0;
  for (int k = t; k < KCODE; k += 256){
    float s = cnorm[k] - 2.f*d2[(size_t)m*KCODE + k];
    if (s < best){ best = s; bk = k; }
  }
  __shared__ float bs[256]; __shared__ int bi[256];
  bs[t]=best; bi[t]=bk;
  __syncthreads();
  for (int off=128; off>0; off>>=1){
    if (t<off){
      if (bs[t+off] < bs[t] || (bs[t+off]==bs[t] && bi[t+off]<bi[t])){
        bs[t]=bs[t+off]; bi[t]=bi[t+off];
      }
    }
    __syncthreads();
  }
  if (t==0) idx[m] = bi[0];
}

// y0 NHWC bf16: y0[b][t][d] = codebook[idx[b,t]][d]
__global__ void k_gather_nhwc(const float* __restrict__ cb, const int* __restrict__ idx,
                              ushort* __restrict__ y0){
  int i = blockIdx.x*256 + threadIdx.x;
  if (i >= B_*NTOK*D_) return;
  int d = i % D_; int r = i / D_; int t = r % NTOK; int b = r / NTOK;
  y0[i] = f2b(cb[(size_t)idx[b*NTOK + t]*D_ + d]);
}

// ---------------- decoder (NHWC bf16) ----------------

// 3x3 conv pad1, patch-staged implicit GEMM + LDS-staged weights.
// 8x8 pixel tile -> 10x10 patch; weights [9][64co][32ch] cooperatively staged.
// grid ((H/8)*(W/8), Cout/64, B_).
__global__ __launch_bounds__(256) void k_conv_nhwc(
    const ushort* __restrict__ X, const ushort* __restrict__ W9,
    float* __restrict__ Y, int Cin, int Cout, int H, int W){
  __shared__ ushort Xs[128][36];      // 10x10 patch rows x 32ch (100 rows used)
  __shared__ ushort Ws[576][36];      // 9 taps x 64 co x 32 ch
  const int HW = H*W;
  const int tid = threadIdx.x;
  const int b = blockIdx.z;
  const int tiles_w = W >> 3;
  const int th0 = (blockIdx.x / tiles_w) * 8;
  const int tw0 = (blockIdx.x - (blockIdx.x / tiles_w)*tiles_w) * 8;
  const int n_base = blockIdx.y*64;
  const int lane = tid & 63, wv = tid >> 6;
  const int quad = lane >> 4, r16 = lane & 15;
  const int m_off = (wv & 1)*32, n_off = (wv >> 1)*32;
  const ushort* Xb = X + (size_t)b*HW*Cin;
  // X staging precompute: 400 items (100 patch rows x 4 ch-segments), 2/thread
  const ushort* sptr[2]; int srw[2], ssg[2]; bool sok[2];
  #pragma unroll
  for (int e = 0; e < 2; ++e){
    int item = tid + e*256;
    int row = (item >> 2) & 127;
    int seg = item & 3;
    int ph = row / 10, pw = row - ph*10;
    int gh = th0 + ph - 1, gw = tw0 + pw - 1;
    bool ok = (item < 400) && gh >= 0 && gh < H && gw >= 0 && gw < W;
    int pidx = ok ? (gh*W + gw) : 0;
    srw[e] = row; ssg[e] = seg; sok[e] = ok;
    sptr[e] = Xb + ((size_t)pidx*Cin + seg*8);
  }
  // W staging precompute: 2304 items (576 rows x 4 segs), 9/thread
  const ushort* wptr[9]; int wrw[9], wsg[9];
  #pragma unroll
  for (int e = 0; e < 9; ++e){
    int item = tid + e*256;
    int row = item >> 2;                 // 0..575
    int seg = item & 3;
    int tap = row >> 6, co = row & 63;
    wrw[e] = row; wsg[e] = seg;
    wptr[e] = W9 + ((size_t)tap*Cout + n_base + co)*Cin + seg*8;
  }
  const uint4v zz = {};
  float4v a00={}, a01={}, a10={}, a11={};
  const int mA = m_off + r16, mB = mA + 16;
  const int rA0 = ((mA>>3))*10 + (mA&7);    // patch row for tap (0,0)
  const int rB0 = ((mB>>3))*10 + (mB&7);
  for (int k0 = 0; k0 < Cin; k0 += 32){
    if (k0) __syncthreads();
    #pragma unroll
    for (int e = 0; e < 2; ++e){
      uint4v v = sok[e] ? *(const uint4v*)(sptr[e] + k0) : zz;
      *(uint4v*)&Xs[srw[e]][ssg[e]*8] = v;
    }
    #pragma unroll
    for (int e = 0; e < 9; ++e)
      *(uint4v*)&Ws[wrw[e]][wsg[e]*8] = *(const uint4v*)(wptr[e] + k0);
    __syncthreads();
    #pragma unroll
    for (int tap = 0; tap < 9; ++tap){
      const int kh = tap/3, kw = tap - (tap/3)*3;
      short8 wf0 = *(const short8*)&Ws[tap*64 + n_off      + r16][quad*8];
      short8 wf1 = *(const short8*)&Ws[tap*64 + n_off + 16 + r16][quad*8];
      short8 xf0 = *(const short8*)&Xs[rA0 + kh*10 + kw][quad*8];
      short8 xf1 = *(const short8*)&Xs[rB0 + kh*10 + kw][quad*8];
      a00 = __builtin_amdgcn_mfma_f32_16x16x32_bf16(wf0, xf0, a00, 0,0,0);
      a01 = __builtin_amdgcn_mfma_f32_16x16x32_bf16(wf0, xf1, a01, 0,0,0);
      a10 = __builtin_amdgcn_mfma_f32_16x16x32_bf16(wf1, xf0, a10, 0,0,0);
      a11 = __builtin_amdgcn_mfma_f32_16x16x32_bf16(wf1, xf1, a11, 0,0,0);
    }
  }
  float* Yb = Y + (size_t)b*HW*Cout;
  int pA = (th0 + (mA>>3))*W + tw0 + (mA&7);
  int pB = (th0 + (mB>>3))*W + tw0 + (mB&7);
  int co0 = n_base + n_off + quad*4, co1 = co0 + 16;
  *(float4v*)(Yb + (size_t)pA*Cout + co0) = a00;
  *(float4v*)(Yb + (size_t)pB*Cout + co0) = a01;
  *(float4v*)(Yb + (size_t)pA*Cout + co1) = a10;
  *(float4v*)(Yb + (size_t)pB*Cout + co1) = a11;
}

// ConvTranspose2d k=2 s=2: X staged once per K-chunk, 4 weight taps share it.
__global__ __launch_bounds__(256) void k_upconv_nhwc(
    const ushort* __restrict__ X, const ushort* __restrict__ Wt4,
    const float* __restrict__ bias, ushort* __restrict__ CC,
    int Cin, int Cout, int Hi, int Wi, int Ctot){
  __shared__ ushort Xs[64][40], Ws[4][64][40];
  const int HWi = Hi*Wi;
  const int tid = threadIdx.x;
  const int b = blockIdx.z;
  const int m_base = blockIdx.x*64;
  const int n_base = blockIdx.y*64;
  const int lane = tid & 63, wv = tid >> 6;
  const int quad = lane >> 4, r16 = lane & 15;
  const int m_off = (wv & 1)*32, n_off = (wv >> 1)*32;
  const int srow = tid & 63, skq = tid >> 6;
  const ushort* xrow = X + ((size_t)b*HWi + m_base + srow)*Cin + skq*8;
  const ushort* w0 = Wt4 + ((size_t)0*Cout + n_base + srow)*Cin + skq*8;
  const ushort* w1 = Wt4 + ((size_t)1*Cout + n_base + srow)*Cin + skq*8;
  const ushort* w2 = Wt4 + ((size_t)2*Cout + n_base + srow)*Cin + skq*8;
  const ushort* w3 = Wt4 + ((size_t)3*Cout + n_base + srow)*Cin + skq*8;
  float4v acc[4][4];
  #pragma unroll
  for (int t = 0; t < 4; ++t)
    #pragma unroll
    for (int q = 0; q < 4; ++q) acc[t][q] = float4v{0.f,0.f,0.f,0.f};
  for (int k0 = 0; k0 < Cin; k0 += 32){
    *(uint4v*)&Xs[srow][skq*8]    = *(const uint4v*)(xrow + k0);
    *(uint4v*)&Ws[0][srow][skq*8] = *(const uint4v*)(w0 + k0);
    *(uint4v*)&Ws[1][srow][skq*8] = *(const uint4v*)(w1 + k0);
    *(uint4v*)&Ws[2][srow][skq*8] = *(const uint4v*)(w2 + k0);
    *(uint4v*)&Ws[3][srow][skq*8] = *(const uint4v*)(w3 + k0);
    __syncthreads();
    short8 xf0 = *(const short8*)&Xs[m_off      + r16][quad*8];
    short8 xf1 = *(const short8*)&Xs[m_off + 16 + r16][quad*8];
    #pragma unroll
    for (int t = 0; t < 4; ++t){
      short8 wf0 = *(const short8*)&Ws[t][n_off      + r16][quad*8];
      short8 wf1 = *(const short8*)&Ws[t][n_off + 16 + r16][quad*8];
      acc[t][0] = __builtin_amdgcn_mfma_f32_16x16x32_bf16(wf0, xf0, acc[t][0], 0,0,0);
      acc[t][1] = __builtin_amdgcn_mfma_f32_16x16x32_bf16(wf0, xf1, acc[t][1], 0,0,0);
      acc[t][2] = __builtin_amdgcn_mfma_f32_16x16x32_bf16(wf1, xf0, acc[t][2], 0,0,0);
      acc[t][3] = __builtin_amdgcn_mfma_f32_16x16x32_bf16(wf1, xf1, acc[t][3], 0,0,0);
    }
    __syncthreads();
  }
  const int Wo = 2*Wi, HWo = 4*HWi;
  int co0 = n_base + n_off + quad*4, co1 = co0 + 16;
  float4v bv0 = *(const float4v*)(bias + co0);
  float4v bv1 = *(const float4v*)(bias + co1);
  int px0 = m_base + m_off + r16, px1 = px0 + 16;
  #pragma unroll
  for (int j = 0; j < 2; ++j){
    int p = j ? px1 : px0;
    int r = p / Wi, c = p - r*Wi;
    #pragma unroll
    for (int t = 0; t < 4; ++t){
      int opix = (2*r + (t>>1))*Wo + 2*c + (t&1);
      ushort* o = CC + ((size_t)b*HWo + opix)*Ctot;
      float4v vA = acc[t][0 + j] + bv0;
      float4v vB = acc[t][2 + j] + bv1;
      uint2v pA, pB;
      pA.x = (unsigned)f2b(vA.x) | ((unsigned)f2b(vA.y) << 16);
      pA.y = (unsigned)f2b(vA.z) | ((unsigned)f2b(vA.w) << 16);
      pB.x = (unsigned)f2b(vB.x) | ((unsigned)f2b(vB.y) << 16);
      pB.y = (unsigned)f2b(vB.z) | ((unsigned)f2b(vB.w) << 16);
      *(uint2v*)(o + co0) = pA;
      *(uint2v*)(o + co1) = pB;
    }
  }
}

// NCHW fp32 skip feature -> NHWC bf16 concat channels [Coff, Coff+Cf)
__global__ void k_feat2cc(const float* __restrict__ feat, ushort* __restrict__ cc,
                          int Cf, int Coff, int Ctot, int HW){
  __shared__ ushort t[32][33];
  int pb = blockIdx.x*32, cbs = blockIdx.y*32, b = blockIdx.z;
  int tx = threadIdx.x, ty = threadIdx.y;
  #pragma unroll
  for (int i = 0; i < 4; ++i){
    int c = cbs + ty + i*8;
    t[ty + i*8][tx] = f2b(feat[((size_t)(b*Cf) + c)*HW + pb + tx]);
  }
  __syncthreads();
  #pragma unroll
  for (int i = 0; i < 4; ++i){
    int p = pb + ty + i*8;
    cc[((size_t)b*HW + p)*Ctot + Coff + cbs + tx] = t[tx][ty + i*8];
  }
}

// BN stats phase 1: BN_S blocks, float4 channel-quads, LDS cross-group reduce.
__global__ __launch_bounds__(256) void k_bnstats_nhwc(
    const float* __restrict__ x, float* __restrict__ part, int C, int HW){
  const int s = blockIdx.x, tid = threadIdx.x;
  const int R = B_*HW;
  const int chunk = R / BN_S;
  const int L = C >> 2;
  const int G = 256 / L;
  const int c4 = tid % L, g = tid / L;
  float4v a = {}, q = {};
  const float* xb = x + (size_t)(s*chunk)*C + 4*c4;
  for (int r = g; r < chunk; r += G){
    float4v v = *(const float4v*)(xb + (size_t)r*C);
    a += v; q += v*v;
  }
  __shared__ float4v h1[256], h2[256];
  h1[tid] = a; h2[tid] = q;
  __syncthreads();
  if (tid < L){
    float4v ra = h1[tid], rq = h2[tid];
    for (int gg = 1; gg < G; ++gg){ ra += h1[tid + gg*L]; rq += h2[tid + gg*L]; }
    int c0 = 4*c4;
    part[(size_t)(c0+0)*BN_S + s] = ra.x;
    part[(size_t)(c0+1)*BN_S + s] = ra.y;
    part[(size_t)(c0+2)*BN_S + s] = ra.z;
    part[(size_t)(c0+3)*BN_S + s] = ra.w;
    part[(size_t)(C+c0+0)*BN_S + s] = rq.x;
    part[(size_t)(C+c0+1)*BN_S + s] = rq.y;
    part[(size_t)(C+c0+2)*BN_S + s] = rq.z;
    part[(size_t)(C+c0+3)*BN_S + s] = rq.w;
  }
}

// BN finalize: one block per channel reduces BN_S partials -> scale/shift
__global__ void k_bnfinal(const float* __restrict__ part, const float* __restrict__ g,
                          const float* __restrict__ bb, float* __restrict__ scale,
                          float* __restrict__ shift, int C, int cnt){
  int c = blockIdx.x, t = threadIdx.x;  // 256 threads
  __shared__ float r1[256], r2[256];
  r1[t] = part[(size_t)c*BN_S + t]       + part[(size_t)c*BN_S + t + 256];
  r2[t] = part[(size_t)(C + c)*BN_S + t] + part[(size_t)(C + c)*BN_S + t + 256];
  __syncthreads();
  for (int off = 128; off > 0; off >>= 1){
    if (t < off){ r1[t] += r1[t+off]; r2[t] += r2[t+off]; }
    __syncthreads();
  }
  if (t == 0){
    float m = r1[0]/cnt;
    float v = r2[0]/cnt - m*m;
    float sc = g[c]*rsqrtf(v + 1e-5f);
    scale[c] = sc;
    shift[c] = bb[c] - m*sc;
  }
}

// BN apply + ReLU, fp32 NHWC -> bf16 NHWC
__global__ void k_bnapply_nhwc(const float* __restrict__ x, ushort* __restrict__ y,
                               const float* __restrict__ scale,
                               const float* __restrict__ shift, int C, int n4){
  int i = blockIdx.x*256 + threadIdx.x;
  if (i >= n4) return;
  float4v v = *(const float4v*)(x + (size_t)4*i);
  int c0 = (4*i) % C;
  float4v sc = *(const float4v*)(scale + c0);
  float4v sh = *(const float4v*)(shift + c0);
  float r0 = fmaxf(v.x*sc.x + sh.x, 0.f);
  float r1 = fmaxf(v.y*sc.y + sh.y, 0.f);
  float r2 = fmaxf(v.z*sc.z + sh.z, 0.f);
  float r3 = fmaxf(v.w*sc.w + sh.w, 0.f);
  uint2v pk;
  pk.x = (unsigned)f2b(r0) | ((unsigned)f2b(r1) << 16);
  pk.y = (unsigned)f2b(r2) | ((unsigned)f2b(r3) << 16);
  *(uint2v*)(y + (size_t)4*i) = pk;
}

// final 1x1 conv (64ch NHWC bf16 -> 1) + sigmoid
__global__ void k_last_nhwc(const ushort* __restrict__ x, const float* __restrict__ lw,
                            const float* __restrict__ lb, float* __restrict__ out){
  __shared__ float wsm[64];
  int tid = threadIdx.x;
  if (tid < 64) wsm[tid] = lw[tid];
  __syncthreads();
  int i = blockIdx.x*256 + tid;
  const uint4v* xr = (const uint4v*)(x + (size_t)i*64);
  float acc = lb[0];
  #pragma unroll
  for (int q = 0; q < 8; ++q){
    uint4v u = xr[q];
    unsigned uu[4] = {u.x, u.y, u.z, u.w};
    #pragma unroll
    for (int k = 0; k < 4; ++k){
      acc += bits2f(uu[k] << 16)          * wsm[q*8 + 2*k];
      acc += bits2f(uu[k] & 0xffff0000u)  * wsm[q*8 + 2*k + 1];
    }
  }
  out[i] = 1.f/(1.f + __expf(-acc));
}

// ---------------- host ----------------
#define MBx 1048576ull

static inline void run_conv(const ushort* in, const float* w, ushort* W9,
                            float* out, int Cin, int Cout, int H, int W,
                            hipStream_t stream){
  int total = Cout*Cin*9;
  k_w9<<<(total+255)/256, 256, 0, stream>>>(w, W9, Cin, Cout);
  k_conv_nhwc<<<dim3((H>>3)*(W>>3), Cout/64, B_), 256, 0, stream>>>(in, W9, out, Cin, Cout, H, W);
}

static inline void run_bn(const float* x, ushort* y, float* part, float* scale, float* shift,
                          const float* g, const float* bb, int C, int HW, hipStream_t stream){
  k_bnstats_nhwc<<<BN_S, 256, 0, stream>>>(x, part, C, HW);
  k_bnfinal<<<C, 256, 0, stream>>>(part, g, bb, scale, shift, C, B_*HW);
  int n4 = B_*HW*C/4;
  k_bnapply_nhwc<<<(n4+255)/256, 256, 0, stream>>>(x, y, scale, shift, C, n4);
}

extern "C" void kernel_launch(void* const* d_in, const int* in_sizes, int n_in,
                              void* d_out, int out_size, void* d_ws, size_t ws_size,
                              hipStream_t stream){
  const float* x     = (const float*)d_in[0];
  const float* feat0 = (const float*)d_in[1];
  const float* feat1 = (const float*)d_in[2];
  const float* feat2 = (const float*)d_in[3];
  const float* pos   = (const float*)d_in[4];
  const float* cb    = (const float*)d_in[5];
  const float* ln_g  = (const float*)d_in[6];
  const float* ln_b  = (const float*)d_in[7];
  const float* wqkv  = (const float*)d_in[8];
  const float* wo    = (const float*)d_in[9];
  const float* bo    = (const float*)d_in[10];
  const float* up_w0 = (const float*)d_in[11];
  const float* up_b0 = (const float*)d_in[12];
  const float* cw0a  = (const float*)d_in[13];
  const float* g0a   = (const float*)d_in[14];
  const float* b0a   = (const float*)d_in[15];
  const float* cw0b  = (const float*)d_in[16];
  const float* g0b   = (const float*)d_in[17];
  const float* b0b   = (const float*)d_in[18];
  const float* up_w1 = (const float*)d_in[19];
  const float* up_b1 = (const float*)d_in[20];
  const float* cw1a  = (const float*)d_in[21];
  const float* g1a   = (const float*)d_in[22];
  const float* b1a   = (const float*)d_in[23];
  const float* cw1b  = (const float*)d_in[24];
  const float* g1b   = (const float*)d_in[25];
  const float* b1b   = (const float*)d_in[26];
  const float* up_w2 = (const float*)d_in[27];
  const float* up_b2 = (const float*)d_in[28];
  const float* cw2a  = (const float*)d_in[29];
  const float* g2a   = (const float*)d_in[30];
  const float* b2a   = (const float*)d_in[31];
  const float* cw2b  = (const float*)d_in[32];
  const float* g2b   = (const float*)d_in[33];
  const float* b2b   = (const float*)d_in[34];
  const float* lw    = (const float*)d_in[35];
  const float* lb    = (const float*)d_in[36];

  char* ws = (char*)d_ws;
  // encoder/VQ scratch (region 0..134MB)
  float*  tok     = (float*) (ws);
  ushort* xn_hi   = (ushort*)(ws +  8388608ull);
  ushort* xn_lo   = (ushort*)(ws + 12582912ull);
  float*  qkv     = (float*) (ws + 16777216ull);
  ushort* at_hi   = (ushort*)(ws + 41943040ull);
  ushort* at_lo   = (ushort*)(ws + 46137344ull);
  ushort* tok_hi  = (ushort*)(ws + 50331648ull);
  ushort* tok_lo  = (ushort*)(ws + 54525952ull);
  ushort* Wq_hi   = (ushort*)(ws + 58720256ull);
  ushort* Wq_lo   = (ushort*)(ws + 77594624ull);
  ushort* Wo_hi   = (ushort*)(ws + 96468992ull);
  ushort* Wo_lo   = (ushort*)(ws + 102760448ull);
  ushort* cb_hi   = (ushort*)(ws + 109051904ull);
  ushort* cb_lo   = (ushort*)(ws + 111149056ull);
  float*  cnorm   = (float*) (ws + 113246208ull);
  int*    idx     = (int*)   (ws + 113254400ull);
  float*  d2      = (float*) (ws + 58720256ull);   // overlaps Wq (dead at VQ time)
  // tail: weights + bn scratch + y0
  ushort* W9   = (ushort*)(ws + 134*MBx);          // 2.25 MB max
  float* bnsc  = (float*) (ws + 136*MBx + 524288); // 1 KB
  float* bnsh  = (float*) (ws + 136*MBx + 528384); // 1 KB
  ushort* Wt4  = (ushort*)(ws + 137*MBx);          // 1 MB max
  float* bnp   = (float*) (ws + 138*MBx);          // 1 MB max
  ushort* y0   = (ushort*)(ws + 139*MBx);
  // decoder ping-pong
  ushort* cc0 = (ushort*)(ws + 146*MBx);
  float*  va0 = (float*) (ws + 163*MBx);
  ushort* xa0 = (ushort*)(ws + 180*MBx);
  float*  vb0 = (float*) (ws + 146*MBx);
  ushort* xb0 = (ushort*)(ws + 189*MBx);
  ushort* cc1 = (ushort*)(ws + 0*MBx);
  float*  va1 = (float*) (ws + 34*MBx);
  ushort* xa1 = (ushort*)(ws + 68*MBx);
  float*  vb1 = (float*) (ws + 85*MBx);
  ushort* xb1 = (ushort*)(ws + 146*MBx);
  ushort* cc2 = (ushort*)(ws + 0*MBx);
  float*  va2 = (float*) (ws + 67*MBx);
  ushort* xa2 = (ushort*)(ws + 146*MBx);
  float*  vb2 = (float*) (ws + 0*MBx);
  ushort* xb2 = (ushort*)(ws + 67*MBx);

  // ---- weight prep ----
  k_split_t<<<(DEPTH*D_*1536+255)/256, 256, 0, stream>>>(wqkv, Wq_hi, Wq_lo, DEPTH, D_, 1536);
  k_split_t<<<(DEPTH*D_*D_+255)/256, 256, 0, stream>>>(wo, Wo_hi, Wo_lo, DEPTH, D_, D_);
  k_split<<<(KCODE*D_+255)/256, 256, 0, stream>>>(cb, cb_hi, cb_lo, KCODE*D_);
  k_cnorm<<<KCODE, 256, 0, stream>>>(cb, cnorm);

  // ---- encoder ----
  k_tok_init<<<(B_*NTOK*D_)/256, 256, 0, stream>>>(x, pos, tok);
  for (int l = 0; l < DEPTH; ++l){
    k_ln_split<<<M_, 256, 0, stream>>>(tok, xn_hi, xn_lo, ln_g + l*D_, ln_b + l*D_);
    k_gemm_split<<<dim3(M_/128, 1536/128), 256, 0, stream>>>(
        xn_hi, xn_lo, Wq_hi + (size_t)l*1536*D_, Wq_lo + (size_t)l*1536*D_,
        qkv, nullptr, nullptr, M_, 1536, D_);
    k_attn2<<<dim3(HEADS, B_), 512, 0, stream>>>(qkv, at_hi, at_lo);
    k_gemm_split<<<dim3(M_/128, D_/128), 256, 0, stream>>>(
        at_hi, at_lo, Wo_hi + (size_t)l*D_*D_, Wo_lo + (size_t)l*D_*D_,
        tok, bo + l*D_, tok, M_, D_, D_);
  }

  // ---- VQ ----
  k_split<<<(M_*D_+255)/256, 256, 0, stream>>>(tok, tok_hi, tok_lo, M_*D_);
  k_gemm_split<<<dim3(M_/128, KCODE/128), 256, 0, stream>>>(
      tok_hi, tok_lo, cb_hi, cb_lo, d2, nullptr, nullptr, M_, KCODE, D_);
  k_argmin<<<M_, 256, 0, stream>>>(d2, cnorm, idx);
  k_gather_nhwc<<<(B_*NTOK*D_)/256, 256, 0, stream>>>(cb, idx, y0);

  // ---- decoder stage 0: 16x16 -> 32x32, Ctot=512 ----
  k_upw<<<(512*256*4+255)/256, 256, 0, stream>>>(up_w0, Wt4, 512, 256);
  k_upconv_nhwc<<<dim3(256/64, 256/64, B_), 256, 0, stream>>>(y0, Wt4, up_b0, cc0, 512, 256, 16, 16, 512);
  k_feat2cc<<<dim3(1024/32, 256/32, B_), dim3(32,8), 0, stream>>>(feat2, cc0, 256, 256, 512, 1024);
  run_conv(cc0, cw0a, W9, va0, 512, 256, 32, 32, stream);
  run_bn(va0, xa0, bnp, bnsc, bnsh, g0a, b0a, 256, 1024, stream);
  run_conv(xa0, cw0b, W9, vb0, 256, 256, 32, 32, stream);
  run_bn(vb0, xb0, bnp, bnsc, bnsh, g0b, b0b, 256, 1024, stream);

  // ---- decoder stage 1: 32x32 -> 64x64, Ctot=256 ----
  k_upw<<<(256*128*4+255)/256, 256, 0, stream>>>(up_w1, Wt4, 256, 128);
  k_upconv_nhwc<<<dim3(1024/64, 128/64, B_), 256, 0, stream>>>(xb0, Wt4, up_b1, cc1, 256, 128, 32, 32, 256);
  k_feat2cc<<<dim3(4096/32, 128/32, B_), dim3(32,8), 0, stream>>>(feat1, cc1, 128, 128, 256, 4096);
  run_conv(cc1, cw1a, W9, va1, 256, 128, 64, 64, stream);
  run_bn(va1, xa1, bnp, bnsc, bnsh, g1a, b1a, 128, 4096, stream);
  run_conv(xa1, cw1b, W9, vb1, 128, 128, 64, 64, stream);
  run_bn(vb1, xb1, bnp, bnsc, bnsh, g1b, b1b, 128, 4096, stream);

  // ---- decoder stage 2: 64x64 -> 128x128, Ctot=128 ----
  k_upw<<<(128*64*4+255)/256, 256, 0, stream>>>(up_w2, Wt4, 128, 64);
  k_upconv_nhwc<<<dim3(4096/64, 64/64, B_), 256, 0, stream>>>(xb1, Wt4, up_b2, cc2, 128, 64, 64, 64, 128);
  k_feat2cc<<<dim3(16384/32, 64/32, B_), dim3(32,8), 0, stream>>>(feat0, cc2, 64, 64, 128, 16384);
  run_conv(cc2, cw2a, W9, va2, 128, 64, 128, 128, stream);
  run_bn(va2, xa2, bnp, bnsc, bnsh, g2a, b2a, 64, 16384, stream);
  run_conv(xa2, cw2b, W9, vb2, 64, 64, 128, 128, stream);
  run_bn(vb2, xb2, bnp, bnsc, bnsh, g2b, b2b, 64, 16384, stream);

  // ---- head ----
  k_last_nhwc<<<(B_*16384)/256, 256, 0, stream>>>(xb2, lw, lb, (float*)d_out);
}

// Round 2
// 2235.259 us; speedup vs baseline: 1.0637x; 1.0637x over previous
//
#include <hip/hip_runtime.h>

#define B_    16
#define NTOK  256
#define D_    512
#define HEADS 16
#define DH    32
#define DEPTH 12
#define KCODE 2048
#define M_    (B_*NTOK)   // 4096 token rows
#define BN_S  512         // BN partial blocks

typedef __attribute__((ext_vector_type(8))) short short8;     // 8 bf16 (4 VGPRs)
typedef __attribute__((ext_vector_type(4))) float float4v;
typedef __attribute__((ext_vector_type(4))) unsigned int uint4v;
typedef __attribute__((ext_vector_type(2))) unsigned int uint2v;
typedef unsigned short ushort;

__device__ __forceinline__ ushort f2b(float f){   // fp32 -> bf16 RNE
  union { float f; unsigned u; } v; v.f = f;
  unsigned r = v.u + 0x7FFFu + ((v.u >> 16) & 1u);
  return (ushort)(r >> 16);
}
__device__ __forceinline__ float b2f(ushort h){
  union { unsigned u; float f; } v; v.u = ((unsigned)h) << 16; return v.f;
}
__device__ __forceinline__ float bits2f(unsigned u){
  union { unsigned u; float f; } v; v.u = u; return v.f;
}

// async global->LDS, 16B per lane; LDS dest = wave-uniform base + lane*16
typedef __attribute__((address_space(3))) unsigned int lds_uint;
typedef __attribute__((address_space(1))) const unsigned int glob_uint;
__device__ __forceinline__ void gl_lds16(const ushort* g, ushort* l){
  __builtin_amdgcn_global_load_lds((glob_uint*)g, (lds_uint*)l, 16, 0, 0);
}

// ---------------- prep kernels ----------------

// tiled transpose: x [b][D][NTOK] -> tok [b][NTOK][D], + pos.  32x32 LDS tile,
// coalesced on both sides. grid (NTOK/32, D/32, B), block (32,8).
__global__ void k_tok_init(const float* __restrict__ x, const float* __restrict__ pos,
                           float* __restrict__ tok){
  __shared__ float t[32][33];
  const int t0 = blockIdx.x*32, d0 = blockIdx.y*32, b = blockIdx.z;
  const int tx = threadIdx.x, ty = threadIdx.y;
  #pragma unroll
  for (int i = 0; i < 4; ++i){
    int d = d0 + ty + i*8;
    t[ty + i*8][tx] = x[((size_t)(b*D_ + d))*NTOK + t0 + tx];
  }
  __syncthreads();
  #pragma unroll
  for (int i = 0; i < 4; ++i){
    int tt = t0 + ty + i*8;
    tok[((size_t)(b*NTOK + tt))*D_ + d0 + tx] = t[tx][ty + i*8] + pos[(size_t)tt*D_ + d0 + tx];
  }
}

__global__ void k_split(const float* __restrict__ src, ushort* __restrict__ oh,
                        ushort* __restrict__ ol, int n){
  int i = blockIdx.x*256 + threadIdx.x;
  if (i >= n) return;
  float v = src[i];
  ushort h = f2b(v);
  oh[i] = h; ol[i] = f2b(v - b2f(h));
}

// split + transpose: src [L][K][N] f32 -> dst hi/lo [L][N][K] bf16.
// 32x32 LDS tile, coalesced read (along N) and write (along K).
// grid (N/32, K/32, L), block (32,8). K,N multiples of 32.
__global__ void k_split_t(const float* __restrict__ src, ushort* __restrict__ oh,
                          ushort* __restrict__ ol, int K, int N){
  __shared__ float t[32][33];
  const int n0 = blockIdx.x*32, k0 = blockIdx.y*32;
  const size_t lb = (size_t)blockIdx.z*K*N;
  const int tx = threadIdx.x, ty = threadIdx.y;
  #pragma unroll
  for (int i = 0; i < 4; ++i){
    int k = k0 + ty + i*8;
    t[ty + i*8][tx] = src[lb + (size_t)k*N + n0 + tx];
  }
  __syncthreads();
  #pragma unroll
  for (int i = 0; i < 4; ++i){
    int n = n0 + ty + i*8;
    float v = t[tx][ty + i*8];
    ushort h = f2b(v);
    size_t o = lb + (size_t)n*K + k0 + tx;
    oh[o] = h; ol[o] = f2b(v - b2f(h));
  }
}

// conv weights: [Cout][Cin][3][3] f32 -> W9 [9tap][Cout][Cin] bf16
__global__ void k_w9(const float* __restrict__ w, ushort* __restrict__ W9,
                     int Cin, int Cout){
  int i = blockIdx.x*256 + threadIdx.x;
  if (i >= Cout*Cin*9) return;
  int co = i / (Cin*9); int r = i - co*(Cin*9);
  int ci = r / 9; int tap = r - ci*9;
  W9[((size_t)tap*Cout + co)*Cin + ci] = f2b(w[i]);
}

// upconv weights: [Cin][Cout][2][2] f32 -> Wt4 [tap][Cout][Cin] bf16
__global__ void k_upw(const float* __restrict__ w, ushort* __restrict__ Wt4,
                      int Cin, int Cout){
  int i = blockIdx.x*256 + threadIdx.x;
  if (i >= Cin*Cout*4) return;
  int ci = i / (Cout*4); int r = i - ci*(Cout*4);
  int co = r >> 2; int tap = r & 3;
  Wt4[((size_t)tap*Cout + co)*Cin + ci] = f2b(w[i]);
}

// LayerNorm fused with bf16 hi/lo split
__global__ void k_ln_split(const float* __restrict__ in, ushort* __restrict__ oh,
                           ushort* __restrict__ ol, const float* __restrict__ g,
                           const float* __restrict__ bta){
  int row = blockIdx.x; int t = threadIdx.x;
  const float* xr = in + (size_t)row*D_;
  float x0 = xr[t], x1 = xr[t+256];
  __shared__ float r1[256], r2[256];
  r1[t] = x0+x1; r2[t] = x0*x0 + x1*x1;
  __syncthreads();
  for (int off=128; off>0; off>>=1){
    if (t<off){ r1[t]+=r1[t+off]; r2[t]+=r2[t+off]; }
    __syncthreads();
  }
  float mean = r1[0] * (1.f/D_);
  float var  = r2[0] * (1.f/D_) - mean*mean;
  float inv  = rsqrtf(var + 1e-5f);
  float y0 = (x0-mean)*inv*g[t]     + bta[t];
  float y1 = (x1-mean)*inv*g[t+256] + bta[t+256];
  size_t o = (size_t)row*D_;
  ushort h0 = f2b(y0), h1 = f2b(y1);
  oh[o+t] = h0;     ol[o+t]     = f2b(y0 - b2f(h0));
  oh[o+t+256] = h1; ol[o+t+256] = f2b(y1 - b2f(h1));
}

// ------ split-bf16 MFMA GEMM, 128x128 tile (3-term, fp32-accurate) ------
// C[M][N] = A[M][K] @ B^T (B as [N][K]); 4 waves, each 64x64 quadrant (4x4 accs).
// Staging via global_load_lds width=16 into LINEAR [128][32] LDS tiles.
// Bank-conflict fix: seg ^= (row>>1)&3 swizzle applied to the GLOBAL source
// address at stage time and to the read address (same involution both sides).
__global__ __launch_bounds__(256,2) void k_gemm_split(
    const ushort* __restrict__ Ah, const ushort* __restrict__ Al,
    const ushort* __restrict__ Bh, const ushort* __restrict__ Bl,
    float* __restrict__ C, const float* __restrict__ bias,
    const float* __restrict__ resid, int M, int N, int K){
  __shared__ ushort Ash[128][32], Asl[128][32], Bsh[128][32], Bsl[128][32];
  const int tid = threadIdx.x;
  const int m_base = blockIdx.x*128, n_base = blockIdx.y*128;
  const int lane = tid & 63, wv = tid >> 6;
  const int quad = lane >> 4, r16 = lane & 15;
  const int m_off = (wv & 1)*64, n_off = (wv >> 1)*64;
  // gload_lds staging: wave wv covers rows [wv*32, wv*32+32) of each buffer,
  // two 1KB issues of 16 rows each. lane covers (row = base+lane/4, seg = lane&3).
  const int lrow = lane >> 2, lseg = lane & 3;
  const int row0 = wv*32 + lrow;              // rows row0 and row0+16
  const int us   = lseg ^ ((row0 >> 1) & 3);  // (row0+16)>>1 has same &3
  const size_t offA0 = (size_t)(m_base + row0)*K + us*8;
  const size_t offA1 = offA0 + (size_t)16*K;
  const size_t offB0 = (size_t)(n_base + row0)*K + us*8;
  const size_t offB1 = offB0 + (size_t)16*K;
  ushort* lAh = &Ash[0][0] + wv*1024;   // wave-uniform LDS dest (shorts)
  ushort* lAl = &Asl[0][0] + wv*1024;
  ushort* lBh = &Bsh[0][0] + wv*1024;
  ushort* lBl = &Bsl[0][0] + wv*1024;
  float4v acc[4][4];
  #pragma unroll
  for (int i = 0; i < 4; ++i)
    #pragma unroll
    for (int j = 0; j < 4; ++j) acc[i][j] = float4v{0.f,0.f,0.f,0.f};
  for (int k0 = 0; k0 < K; k0 += 32){
    gl_lds16(Ah + offA0 + k0, lAh);
    gl_lds16(Ah + offA1 + k0, lAh + 512);
    gl_lds16(Al + offA0 + k0, lAl);
    gl_lds16(Al + offA1 + k0, lAl + 512);
    gl_lds16(Bh + offB0 + k0, lBh);
    gl_lds16(Bh + offB1 + k0, lBh + 512);
    gl_lds16(Bl + offB0 + k0, lBl);
    gl_lds16(Bl + offB1 + k0, lBl + 512);
    __syncthreads();   // drains vmcnt -> staged data visible
    short8 ah[4], al[4], bh[4], bl[4];
    #pragma unroll
    for (int i = 0; i < 4; ++i){
      int ra = m_off + i*16 + r16;
      int rb = n_off + i*16 + r16;
      int sa = (quad ^ ((ra >> 1) & 3))*8;
      int sb = (quad ^ ((rb >> 1) & 3))*8;
      ah[i] = *(const short8*)&Ash[ra][sa];
      al[i] = *(const short8*)&Asl[ra][sa];
      bh[i] = *(const short8*)&Bsh[rb][sb];
      bl[i] = *(const short8*)&Bsl[rb][sb];
    }
    #pragma unroll
    for (int i = 0; i < 4; ++i)
      #pragma unroll
      for (int j = 0; j < 4; ++j){
        acc[i][j] = __builtin_amdgcn_mfma_f32_16x16x32_bf16(bh[j], ah[i], acc[i][j], 0,0,0);
        acc[i][j] = __builtin_amdgcn_mfma_f32_16x16x32_bf16(bh[j], al[i], acc[i][j], 0,0,0);
        acc[i][j] = __builtin_amdgcn_mfma_f32_16x16x32_bf16(bl[j], ah[i], acc[i][j], 0,0,0);
      }
    __syncthreads();
  }
  #pragma unroll
  for (int i = 0; i < 4; ++i){
    int m = m_base + m_off + i*16 + r16;
    #pragma unroll
    for (int j = 0; j < 4; ++j){
      int n = n_base + n_off + j*16 + quad*4;
      float4v v = acc[i][j];
      if (bias)  v += *(const float4v*)(bias + n);
      if (resid) v += *(const float4v*)(resid + (size_t)m*N + n);
      *(float4v*)(C + (size_t)m*N + n) = v;
    }
  }
}

// ---------------- attention: one block per (b,h), K/V in LDS ----------------
// 512 threads: thread t and t+256 split the 256-token j-loop for query token
// (t&255); partials combined through the then-dead K/V LDS. 8 waves/CU.
__global__ __launch_bounds__(512) void k_attn2(const float* __restrict__ qkv,
                                               ushort* __restrict__ oh,
                                               ushort* __restrict__ ol){
  __shared__ float4v smem[NTOK*16];          // [0,2048)=K, [2048,4096)=V
  float4v* ks = smem;
  float4v* vs = smem + NTOK*8;
  const int h = blockIdx.x, b = blockIdx.y, t = threadIdx.x;
  const int tq = t & 255, half = t >> 8;
  const float* base = qkv + (size_t)b*NTOK*1536;
  const int koff = 512 + h*DH, voff = 1024 + h*DH;
  for (int i = t; i < NTOK*8; i += 512){
    int j = i >> 3, d4 = i & 7;
    ks[i] = *(const float4v*)(base + (size_t)j*1536 + koff + d4*4);
    vs[i] = *(const float4v*)(base + (size_t)j*1536 + voff + d4*4);
  }
  float4v q8[8];
  const float* qrow = base + (size_t)tq*1536 + h*DH;
  #pragma unroll
  for (int d4 = 0; d4 < 8; ++d4) q8[d4] = *(const float4v*)(qrow + d4*4);
  __syncthreads();
  float4v o8[8];
  #pragma unroll
  for (int d4 = 0; d4 < 8; ++d4) o8[d4] = float4v{0.f,0.f,0.f,0.f};
  float l = 0.f;
  const int j0 = half*128, j1 = j0 + 128;
  for (int j = j0; j < j1; ++j){
    float s = 0.f;
    #pragma unroll
    for (int d4 = 0; d4 < 8; ++d4){
      float4v kk = ks[j*8 + d4];
      s += q8[d4].x*kk.x + q8[d4].y*kk.y + q8[d4].z*kk.z + q8[d4].w*kk.w;
    }
    float e = __expf(s * 0.17677669529663689f);
    l += e;
    #pragma unroll
    for (int d4 = 0; d4 < 8; ++d4){
      float4v vv = vs[j*8 + d4];
      o8[d4].x += e*vv.x; o8[d4].y += e*vv.y; o8[d4].z += e*vv.z; o8[d4].w += e*vv.w;
    }
  }
  __syncthreads();                           // everyone done with K/V
  if (half){
    float4v* st = smem + (size_t)tq*9;       // stride 9 to dodge bank aliasing
    #pragma unroll
    for (int d4 = 0; d4 < 8; ++d4) st[d4] = o8[d4];
    ((float*)smem)[9216 + tq] = l;
  }
  __syncthreads();
  if (!half){
    const float4v* st = smem + (size_t)tq*9;
    #pragma unroll
    for (int d4 = 0; d4 < 8; ++d4) o8[d4] += st[d4];
    l += ((float*)smem)[9216 + tq];
    float inv = 1.f / l;
    size_t ob = (size_t)(b*NTOK + tq)*D_ + h*DH;
    #pragma unroll
    for (int d4 = 0; d4 < 8; ++d4){
      float vals[4] = {o8[d4].x*inv, o8[d4].y*inv, o8[d4].z*inv, o8[d4].w*inv};
      #pragma unroll
      for (int r = 0; r < 4; ++r){
        ushort hh = f2b(vals[r]);
        oh[ob + d4*4 + r] = hh;
        ol[ob + d4*4 + r] = f2b(vals[r] - b2f(hh));
      }
    }
  }
}

// ---------------- VQ ----------------
__global__ void k_cnorm(const float* __restrict__ cb, float* __restrict__ cnorm){
  int k = blockIdx.x, t = threadIdx.x;
  float v1 = cb[(size_t)k*D_ + t];
  float v2 = cb[(size_t)k*D_ + t + 256];
  __shared__ float r[256];
  r[t] = v1*v1 + v2*v2;
  __syncthreads();
  for (int off=128; off>0; off>>=1){
    if (t<off) r[t]+=r[t+off];
    __syncthreads();
  }
  if (t==0) cnorm[k] = r[0];
}

__global__ void k_argmin(const float* __restrict__ d2, const float* __restrict__ cnorm,
                         int* __restrict__ idx){
  int m = blockIdx.x, t = threadIdx.x;
  float best = 3.4e38f; int bk = 0;
  for (int k = t; k < KCODE; k += 256){
    float s = cnorm[k] - 2.f*d2[(size_t)m*KCODE + k];
    if (s < best){ best = s; bk = k; }
  }
  __shared__ float bs[256]; __shared__ int bi[256];
  bs[t]=best; bi[t]=bk;
  __syncthreads();
  for (int off=128; off>0; off>>=1){
    if (t<off){
      if (bs[t+off] < bs[t] || (bs[t+off]==bs[t] && bi[t+off]<bi[t])){
        bs[t]=bs[t+off]; bi[t]=bi[t+off];
      }
    }
    __syncthreads();
  }
  if (t==0) idx[m] = bi[0];
}

// y0 NHWC bf16: y0[b][t][d] = codebook[idx[b,t]][d]
__global__ void k_gather_nhwc(const float* __restrict__ cb, const int* __restrict__ idx,
                              ushort* __restrict__ y0){
  int i = blockIdx.x*256 + threadIdx.x;
  if (i >= B_*NTOK*D_) return;
  int d = i % D_; int r = i / D_; int t = r % NTOK; int b = r / NTOK;
  y0[i] = f2b(cb[(size_t)idx[b*NTOK + t]*D_ + d]);
}

// ---------------- decoder (NHWC bf16) ----------------

// 3x3 conv pad1, patch-staged implicit GEMM + LDS-staged weights.
// 8x8 pixel tile -> 10x10 patch; weights [9][64co][32ch] cooperatively staged.
// grid ((H/8)*(W/8), Cout/64, B_).
__global__ __launch_bounds__(256) void k_conv_nhwc(
    const ushort* __restrict__ X, const ushort* __restrict__ W9,
    float* __restrict__ Y, int Cin, int Cout, int H, int W){
  __shared__ ushort Xs[128][36];      // 10x10 patch rows x 32ch (100 rows used)
  __shared__ ushort Ws[576][36];      // 9 taps x 64 co x 32 ch
  const int HW = H*W;
  const int tid = threadIdx.x;
  const int b = blockIdx.z;
  const int tiles_w = W >> 3;
  const int th0 = (blockIdx.x / tiles_w) * 8;
  const int tw0 = (blockIdx.x - (blockIdx.x / tiles_w)*tiles_w) * 8;
  const int n_base = blockIdx.y*64;
  const int lane = tid & 63, wv = tid >> 6;
  const int quad = lane >> 4, r16 = lane & 15;
  const int m_off = (wv & 1)*32, n_off = (wv >> 1)*32;
  const ushort* Xb = X + (size_t)b*HW*Cin;
  // X staging precompute: 400 items (100 patch rows x 4 ch-segments), 2/thread
  const ushort* sptr[2]; int srw[2], ssg[2]; bool sok[2];
  #pragma unroll
  for (int e = 0; e < 2; ++e){
    int item = tid + e*256;
    int row = (item >> 2) & 127;
    int seg = item & 3;
    int ph = row / 10, pw = row - ph*10;
    int gh = th0 + ph - 1, gw = tw0 + pw - 1;
    bool ok = (item < 400) && gh >= 0 && gh < H && gw >= 0 && gw < W;
    int pidx = ok ? (gh*W + gw) : 0;
    srw[e] = row; ssg[e] = seg; sok[e] = ok;
    sptr[e] = Xb + ((size_t)pidx*Cin + seg*8);
  }
  // W staging precompute: 2304 items (576 rows x 4 segs), 9/thread
  const ushort* wptr[9]; int wrw[9], wsg[9];
  #pragma unroll
  for (int e = 0; e < 9; ++e){
    int item = tid + e*256;
    int row = item >> 2;                 // 0..575
    int seg = item & 3;
    int tap = row >> 6, co = row & 63;
    wrw[e] = row; wsg[e] = seg;
    wptr[e] = W9 + ((size_t)tap*Cout + n_base + co)*Cin + seg*8;
  }
  const uint4v zz = {};
  float4v a00={}, a01={}, a10={}, a11={};
  const int mA = m_off + r16, mB = mA + 16;
  const int rA0 = ((mA>>3))*10 + (mA&7);    // patch row for tap (0,0)
  const int rB0 = ((mB>>3))*10 + (mB&7);
  for (int k0 = 0; k0 < Cin; k0 += 32){
    if (k0) __syncthreads();
    #pragma unroll
    for (int e = 0; e < 2; ++e){
      uint4v v = sok[e] ? *(const uint4v*)(sptr[e] + k0) : zz;
      *(uint4v*)&Xs[srw[e]][ssg[e]*8] = v;
    }
    #pragma unroll
    for (int e = 0; e < 9; ++e)
      *(uint4v*)&Ws[wrw[e]][wsg[e]*8] = *(const uint4v*)(wptr[e] + k0);
    __syncthreads();
    #pragma unroll
    for (int tap = 0; tap < 9; ++tap){
      const int kh = tap/3, kw = tap - (tap/3)*3;
      short8 wf0 = *(const short8*)&Ws[tap*64 + n_off      + r16][quad*8];
      short8 wf1 = *(const short8*)&Ws[tap*64 + n_off + 16 + r16][quad*8];
      short8 xf0 = *(const short8*)&Xs[rA0 + kh*10 + kw][quad*8];
      short8 xf1 = *(const short8*)&Xs[rB0 + kh*10 + kw][quad*8];
      a00 = __builtin_amdgcn_mfma_f32_16x16x32_bf16(wf0, xf0, a00, 0,0,0);
      a01 = __builtin_amdgcn_mfma_f32_16x16x32_bf16(wf0, xf1, a01, 0,0,0);
      a10 = __builtin_amdgcn_mfma_f32_16x16x32_bf16(wf1, xf0, a10, 0,0,0);
      a11 = __builtin_amdgcn_mfma_f32_16x16x32_bf16(wf1, xf1, a11, 0,0,0);
    }
  }
  float* Yb = Y + (size_t)b*HW*Cout;
  int pA = (th0 + (mA>>3))*W + tw0 + (mA&7);
  int pB = (th0 + (mB>>3))*W + tw0 + (mB&7);
  int co0 = n_base + n_off + quad*4, co1 = co0 + 16;
  *(float4v*)(Yb + (size_t)pA*Cout + co0) = a00;
  *(float4v*)(Yb + (size_t)pB*Cout + co0) = a01;
  *(float4v*)(Yb + (size_t)pA*Cout + co1) = a10;
  *(float4v*)(Yb + (size_t)pB*Cout + co1) = a11;
}

// ConvTranspose2d k=2 s=2: X staged once per K-chunk, 4 weight taps share it.
__global__ __launch_bounds__(256) void k_upconv_nhwc(
    const ushort* __restrict__ X, const ushort* __restrict__ Wt4,
    const float* __restrict__ bias, ushort* __restrict__ CC,
    int Cin, int Cout, int Hi, int Wi, int Ctot){
  __shared__ ushort Xs[64][40], Ws[4][64][40];
  const int HWi = Hi*Wi;
  const int tid = threadIdx.x;
  const int b = blockIdx.z;
  const int m_base = blockIdx.x*64;
  const int n_base = blockIdx.y*64;
  const int lane = tid & 63, wv = tid >> 6;
  const int quad = lane >> 4, r16 = lane & 15;
  const int m_off = (wv & 1)*32, n_off = (wv >> 1)*32;
  const int srow = tid & 63, skq = tid >> 6;
  const ushort* xrow = X + ((size_t)b*HWi + m_base + srow)*Cin + skq*8;
  const ushort* w0 = Wt4 + ((size_t)0*Cout + n_base + srow)*Cin + skq*8;
  const ushort* w1 = Wt4 + ((size_t)1*Cout + n_base + srow)*Cin + skq*8;
  const ushort* w2 = Wt4 + ((size_t)2*Cout + n_base + srow)*Cin + skq*8;
  const ushort* w3 = Wt4 + ((size_t)3*Cout + n_base + srow)*Cin + skq*8;
  float4v acc[4][4];
  #pragma unroll
  for (int t = 0; t < 4; ++t)
    #pragma unroll
    for (int q = 0; q < 4; ++q) acc[t][q] = float4v{0.f,0.f,0.f,0.f};
  for (int k0 = 0; k0 < Cin; k0 += 32){
    *(uint4v*)&Xs[srow][skq*8]    = *(const uint4v*)(xrow + k0);
    *(uint4v*)&Ws[0][srow][skq*8] = *(const uint4v*)(w0 + k0);
    *(uint4v*)&Ws[1][srow][skq*8] = *(const uint4v*)(w1 + k0);
    *(uint4v*)&Ws[2][srow][skq*8] = *(const uint4v*)(w2 + k0);
    *(uint4v*)&Ws[3][srow][skq*8] = *(const uint4v*)(w3 + k0);
    __syncthreads();
    short8 xf0 = *(const short8*)&Xs[m_off      + r16][quad*8];
    short8 xf1 = *(const short8*)&Xs[m_off + 16 + r16][quad*8];
    #pragma unroll
    for (int t = 0; t < 4; ++t){
      short8 wf0 = *(const short8*)&Ws[t][n_off      + r16][quad*8];
      short8 wf1 = *(const short8*)&Ws[t][n_off + 16 + r16][quad*8];
      acc[t][0] = __builtin_amdgcn_mfma_f32_16x16x32_bf16(wf0, xf0, acc[t][0], 0,0,0);
      acc[t][1] = __builtin_amdgcn_mfma_f32_16x16x32_bf16(wf0, xf1, acc[t][1], 0,0,0);
      acc[t][2] = __builtin_amdgcn_mfma_f32_16x16x32_bf16(wf1, xf0, acc[t][2], 0,0,0);
      acc[t][3] = __builtin_amdgcn_mfma_f32_16x16x32_bf16(wf1, xf1, acc[t][3], 0,0,0);
    }
    __syncthreads();
  }
  const int Wo = 2*Wi, HWo = 4*HWi;
  int co0 = n_base + n_off + quad*4, co1 = co0 + 16;
  float4v bv0 = *(const float4v*)(bias + co0);
  float4v bv1 = *(const float4v*)(bias + co1);
  int px0 = m_base + m_off + r16, px1 = px0 + 16;
  #pragma unroll
  for (int j = 0; j < 2; ++j){
    int p = j ? px1 : px0;
    int r = p / Wi, c = p - r*Wi;
    #pragma unroll
    for (int t = 0; t < 4; ++t){
      int opix = (2*r + (t>>1))*Wo + 2*c + (t&1);
      ushort* o = CC + ((size_t)b*HWo + opix)*Ctot;
      float4v vA = acc[t][0 + j] + bv0;
      float4v vB = acc[t][2 + j] + bv1;
      uint2v pA, pB;
      pA.x = (unsigned)f2b(vA.x) | ((unsigned)f2b(vA.y) << 16);
      pA.y = (unsigned)f2b(vA.z) | ((unsigned)f2b(vA.w) << 16);
      pB.x = (unsigned)f2b(vB.x) | ((unsigned)f2b(vB.y) << 16);
      pB.y = (unsigned)f2b(vB.z) | ((unsigned)f2b(vB.w) << 16);
      *(uint2v*)(o + co0) = pA;
      *(uint2v*)(o + co1) = pB;
    }
  }
}

// NCHW fp32 skip feature -> NHWC bf16 concat channels [Coff, Coff+Cf)
__global__ void k_feat2cc(const float* __restrict__ feat, ushort* __restrict__ cc,
                          int Cf, int Coff, int Ctot, int HW){
  __shared__ ushort t[32][33];
  int pb = blockIdx.x*32, cbs = blockIdx.y*32, b = blockIdx.z;
  int tx = threadIdx.x, ty = threadIdx.y;
  #pragma unroll
  for (int i = 0; i < 4; ++i){
    int c = cbs + ty + i*8;
    t[ty + i*8][tx] = f2b(feat[((size_t)(b*Cf) + c)*HW + pb + tx]);
  }
  __syncthreads();
  #pragma unroll
  for (int i = 0; i < 4; ++i){
    int p = pb + ty + i*8;
    cc[((size_t)b*HW + p)*Ctot + Coff + cbs + tx] = t[tx][ty + i*8];
  }
}

// BN stats phase 1: BN_S blocks, float4 channel-quads, LDS cross-group reduce.
__global__ __launch_bounds__(256) void k_bnstats_nhwc(
    const float* __restrict__ x, float* __restrict__ part, int C, int HW){
  const int s = blockIdx.x, tid = threadIdx.x;
  const int R = B_*HW;
  const int chunk = R / BN_S;
  const int L = C >> 2;
  const int G = 256 / L;
  const int c4 = tid % L, g = tid / L;
  float4v a = {}, q = {};
  const float* xb = x + (size_t)(s*chunk)*C + 4*c4;
  for (int r = g; r < chunk; r += G){
    float4v v = *(const float4v*)(xb + (size_t)r*C);
    a += v; q += v*v;
  }
  __shared__ float4v h1[256], h2[256];
  h1[tid] = a; h2[tid] = q;
  __syncthreads();
  if (tid < L){
    float4v ra = h1[tid], rq = h2[tid];
    for (int gg = 1; gg < G; ++gg){ ra += h1[tid + gg*L]; rq += h2[tid + gg*L]; }
    int c0 = 4*c4;
    part[(size_t)(c0+0)*BN_S + s] = ra.x;
    part[(size_t)(c0+1)*BN_S + s] = ra.y;
    part[(size_t)(c0+2)*BN_S + s] = ra.z;
    part[(size_t)(c0+3)*BN_S + s] = ra.w;
    part[(size_t)(C+c0+0)*BN_S + s] = rq.x;
    part[(size_t)(C+c0+1)*BN_S + s] = rq.y;
    part[(size_t)(C+c0+2)*BN_S + s] = rq.z;
    part[(size_t)(C+c0+3)*BN_S + s] = rq.w;
  }
}

// BN finalize: one block per channel reduces BN_S partials -> scale/shift
__global__ void k_bnfinal(const float* __restrict__ part, const float* __restrict__ g,
                          const float* __restrict__ bb, float* __restrict__ scale,
                          float* __restrict__ shift, int C, int cnt){
  int c = blockIdx.x, t = threadIdx.x;  // 256 threads
  __shared__ float r1[256], r2[256];
  r1[t] = part[(size_t)c*BN_S + t]       + part[(size_t)c*BN_S + t + 256];
  r2[t] = part[(size_t)(C + c)*BN_S + t] + part[(size_t)(C + c)*BN_S + t + 256];
  __syncthreads();
  for (int off = 128; off > 0; off >>= 1){
    if (t < off){ r1[t] += r1[t+off]; r2[t] += r2[t+off]; }
    __syncthreads();
  }
  if (t == 0){
    float m = r1[0]/cnt;
    float v = r2[0]/cnt - m*m;
    float sc = g[c]*rsqrtf(v + 1e-5f);
    scale[c] = sc;
    shift[c] = bb[c] - m*sc;
  }
}

// BN apply + ReLU, fp32 NHWC -> bf16 NHWC
__global__ void k_bnapply_nhwc(const float* __restrict__ x, ushort* __restrict__ y,
                               const float* __restrict__ scale,
                               const float* __restrict__ shift, int C, int n4){
  int i = blockIdx.x*256 + threadIdx.x;
  if (i >= n4) return;
  float4v v = *(const float4v*)(x + (size_t)4*i);
  int c0 = (4*i) % C;
  float4v sc = *(const float4v*)(scale + c0);
  float4v sh = *(const float4v*)(shift + c0);
  float r0 = fmaxf(v.x*sc.x + sh.x, 0.f);
  float r1 = fmaxf(v.y*sc.y + sh.y, 0.f);
  float r2 = fmaxf(v.z*sc.z + sh.z, 0.f);
  float r3 = fmaxf(v.w*sc.w + sh.w, 0.f);
  uint2v pk;
  pk.x = (unsigned)f2b(r0) | ((unsigned)f2b(r1) << 16);
  pk.y = (unsigned)f2b(r2) | ((unsigned)f2b(r3) << 16);
  *(uint2v*)(y + (size_t)4*i) = pk;
}

// final 1x1 conv (64ch NHWC bf16 -> 1) + sigmoid
__global__ void k_last_nhwc(const ushort* __restrict__ x, const float* __restrict__ lw,
                            const float* __restrict__ lb, float* __restrict__ out){
  __shared__ float wsm[64];
  int tid = threadIdx.x;
  if (tid < 64) wsm[tid] = lw[tid];
  __syncthreads();
  int i = blockIdx.x*256 + tid;
  const uint4v* xr = (const uint4v*)(x + (size_t)i*64);
  float acc = lb[0];
  #pragma unroll
  for (int q = 0; q < 8; ++q){
    uint4v u = xr[q];
    unsigned uu[4] = {u.x, u.y, u.z, u.w};
    #pragma unroll
    for (int k = 0; k < 4; ++k){
      acc += bits2f(uu[k] << 16)          * wsm[q*8 + 2*k];
      acc += bits2f(uu[k] & 0xffff0000u)  * wsm[q*8 + 2*k + 1];
    }
  }
  out[i] = 1.f/(1.f + __expf(-acc));
}

// ---------------- host ----------------
#define MBx 1048576ull

static inline void run_conv(const ushort* in, const float* w, ushort* W9,
                            float* out, int Cin, int Cout, int H, int W,
                            hipStream_t stream){
  int total = Cout*Cin*9;
  k_w9<<<(total+255)/256, 256, 0, stream>>>(w, W9, Cin, Cout);
  k_conv_nhwc<<<dim3((H>>3)*(W>>3), Cout/64, B_), 256, 0, stream>>>(in, W9, out, Cin, Cout, H, W);
}

static inline void run_bn(const float* x, ushort* y, float* part, float* scale, float* shift,
                          const float* g, const float* bb, int C, int HW, hipStream_t stream){
  k_bnstats_nhwc<<<BN_S, 256, 0, stream>>>(x, part, C, HW);
  k_bnfinal<<<C, 256, 0, stream>>>(part, g, bb, scale, shift, C, B_*HW);
  int n4 = B_*HW*C/4;
  k_bnapply_nhwc<<<(n4+255)/256, 256, 0, stream>>>(x, y, scale, shift, C, n4);
}

extern "C" void kernel_launch(void* const* d_in, const int* in_sizes, int n_in,
                              void* d_out, int out_size, void* d_ws, size_t ws_size,
                              hipStream_t stream){
  const float* x     = (const float*)d_in[0];
  const float* feat0 = (const float*)d_in[1];
  const float* feat1 = (const float*)d_in[2];
  const float* feat2 = (const float*)d_in[3];
  const float* pos   = (const float*)d_in[4];
  const float* cb    = (const float*)d_in[5];
  const float* ln_g  = (const float*)d_in[6];
  const float* ln_b  = (const float*)d_in[7];
  const float* wqkv  = (const float*)d_in[8];
  const float* wo    = (const float*)d_in[9];
  const float* bo    = (const float*)d_in[10];
  const float* up_w0 = (const float*)d_in[11];
  const float* up_b0 = (const float*)d_in[12];
  const float* cw0a  = (const float*)d_in[13];
  const float* g0a   = (const float*)d_in[14];
  const float* b0a   = (const float*)d_in[15];
  const float* cw0b  = (const float*)d_in[16];
  const float* g0b   = (const float*)d_in[17];
  const float* b0b   = (const float*)d_in[18];
  const float* up_w1 = (const float*)d_in[19];
  const float* up_b1 = (const float*)d_in[20];
  const float* cw1a  = (const float*)d_in[21];
  const float* g1a   = (const float*)d_in[22];
  const float* b1a   = (const float*)d_in[23];
  const float* cw1b  = (const float*)d_in[24];
  const float* g1b   = (const float*)d_in[25];
  const float* b1b   = (const float*)d_in[26];
  const float* up_w2 = (const float*)d_in[27];
  const float* up_b2 = (const float*)d_in[28];
  const float* cw2a  = (const float*)d_in[29];
  const float* g2a   = (const float*)d_in[30];
  const float* b2a   = (const float*)d_in[31];
  const float* cw2b  = (const float*)d_in[32];
  const float* g2b   = (const float*)d_in[33];
  const float* b2b   = (const float*)d_in[34];
  const float* lw    = (const float*)d_in[35];
  const float* lb    = (const float*)d_in[36];

  char* ws = (char*)d_ws;
  // encoder/VQ scratch (region 0..134MB)
  float*  tok     = (float*) (ws);
  ushort* xn_hi   = (ushort*)(ws +  8388608ull);
  ushort* xn_lo   = (ushort*)(ws + 12582912ull);
  float*  qkv     = (float*) (ws + 16777216ull);
  ushort* at_hi   = (ushort*)(ws + 41943040ull);
  ushort* at_lo   = (ushort*)(ws + 46137344ull);
  ushort* tok_hi  = (ushort*)(ws + 50331648ull);
  ushort* tok_lo  = (ushort*)(ws + 54525952ull);
  ushort* Wq_hi   = (ushort*)(ws + 58720256ull);
  ushort* Wq_lo   = (ushort*)(ws + 77594624ull);
  ushort* Wo_hi   = (ushort*)(ws + 96468992ull);
  ushort* Wo_lo   = (ushort*)(ws + 102760448ull);
  ushort* cb_hi   = (ushort*)(ws + 109051904ull);
  ushort* cb_lo   = (ushort*)(ws + 111149056ull);
  float*  cnorm   = (float*) (ws + 113246208ull);
  int*    idx     = (int*)   (ws + 113254400ull);
  float*  d2      = (float*) (ws + 58720256ull);   // overlaps Wq (dead at VQ time)
  // tail: weights + bn scratch + y0
  ushort* W9   = (ushort*)(ws + 134*MBx);          // 2.25 MB max
  float* bnsc  = (float*) (ws + 136*MBx + 524288); // 1 KB
  float* bnsh  = (float*) (ws + 136*MBx + 528384); // 1 KB
  ushort* Wt4  = (ushort*)(ws + 137*MBx);          // 1 MB max
  float* bnp   = (float*) (ws + 138*MBx);          // 1 MB max
  ushort* y0   = (ushort*)(ws + 139*MBx);
  // decoder ping-pong
  ushort* cc0 = (ushort*)(ws + 146*MBx);
  float*  va0 = (float*) (ws + 163*MBx);
  ushort* xa0 = (ushort*)(ws + 180*MBx);
  float*  vb0 = (float*) (ws + 146*MBx);
  ushort* xb0 = (ushort*)(ws + 189*MBx);
  ushort* cc1 = (ushort*)(ws + 0*MBx);
  float*  va1 = (float*) (ws + 34*MBx);
  ushort* xa1 = (ushort*)(ws + 68*MBx);
  float*  vb1 = (float*) (ws + 85*MBx);
  ushort* xb1 = (ushort*)(ws + 146*MBx);
  ushort* cc2 = (ushort*)(ws + 0*MBx);
  float*  va2 = (float*) (ws + 67*MBx);
  ushort* xa2 = (ushort*)(ws + 146*MBx);
  float*  vb2 = (float*) (ws + 0*MBx);
  ushort* xb2 = (ushort*)(ws + 67*MBx);

  // ---- weight prep ----
  k_split_t<<<dim3(1536/32, D_/32, DEPTH), dim3(32,8), 0, stream>>>(wqkv, Wq_hi, Wq_lo, D_, 1536);
  k_split_t<<<dim3(D_/32, D_/32, DEPTH), dim3(32,8), 0, stream>>>(wo, Wo_hi, Wo_lo, D_, D_);
  k_split<<<(KCODE*D_+255)/256, 256, 0, stream>>>(cb, cb_hi, cb_lo, KCODE*D_);
  k_cnorm<<<KCODE, 256, 0, stream>>>(cb, cnorm);

  // ---- encoder ----
  k_tok_init<<<dim3(NTOK/32, D_/32, B_), dim3(32,8), 0, stream>>>(x, pos, tok);
  for (int l = 0; l < DEPTH; ++l){
    k_ln_split<<<M_, 256, 0, stream>>>(tok, xn_hi, xn_lo, ln_g + l*D_, ln_b + l*D_);
    k_gemm_split<<<dim3(M_/128, 1536/128), 256, 0, stream>>>(
        xn_hi, xn_lo, Wq_hi + (size_t)l*1536*D_, Wq_lo + (size_t)l*1536*D_,
        qkv, nullptr, nullptr, M_, 1536, D_);
    k_attn2<<<dim3(HEADS, B_), 512, 0, stream>>>(qkv, at_hi, at_lo);
    k_gemm_split<<<dim3(M_/128, D_/128), 256, 0, stream>>>(
        at_hi, at_lo, Wo_hi + (size_t)l*D_*D_, Wo_lo + (size_t)l*D_*D_,
        tok, bo + l*D_, tok, M_, D_, D_);
  }

  // ---- VQ ----
  k_split<<<(M_*D_+255)/256, 256, 0, stream>>>(tok, tok_hi, tok_lo, M_*D_);
  k_gemm_split<<<dim3(M_/128, KCODE/128), 256, 0, stream>>>(
      tok_hi, tok_lo, cb_hi, cb_lo, d2, nullptr, nullptr, M_, KCODE, D_);
  k_argmin<<<M_, 256, 0, stream>>>(d2, cnorm, idx);
  k_gather_nhwc<<<(B_*NTOK*D_)/256, 256, 0, stream>>>(cb, idx, y0);

  // ---- decoder stage 0: 16x16 -> 32x32, Ctot=512 ----
  k_upw<<<(512*256*4+255)/256, 256, 0, stream>>>(up_w0, Wt4, 512, 256);
  k_upconv_nhwc<<<dim3(256/64, 256/64, B_), 256, 0, stream>>>(y0, Wt4, up_b0, cc0, 512, 256, 16, 16, 512);
  k_feat2cc<<<dim3(1024/32, 256/32, B_), dim3(32,8), 0, stream>>>(feat2, cc0, 256, 256, 512, 1024);
  run_conv(cc0, cw0a, W9, va0, 512, 256, 32, 32, stream);
  run_bn(va0, xa0, bnp, bnsc, bnsh, g0a, b0a, 256, 1024, stream);
  run_conv(xa0, cw0b, W9, vb0, 256, 256, 32, 32, stream);
  run_bn(vb0, xb0, bnp, bnsc, bnsh, g0b, b0b, 256, 1024, stream);

  // ---- decoder stage 1: 32x32 -> 64x64, Ctot=256 ----
  k_upw<<<(256*128*4+255)/256, 256, 0, stream>>>(up_w1, Wt4, 256, 128);
  k_upconv_nhwc<<<dim3(1024/64, 128/64, B_), 256, 0, stream>>>(xb0, Wt4, up_b1, cc1, 256, 128, 32, 32, 256);
  k_feat2cc<<<dim3(4096/32, 128/32, B_), dim3(32,8), 0, stream>>>(feat1, cc1, 128, 128, 256, 4096);
  run_conv(cc1, cw1a, W9, va1, 256, 128, 64, 64, stream);
  run_bn(va1, xa1, bnp, bnsc, bnsh, g1a, b1a, 128, 4096, stream);
  run_conv(xa1, cw1b, W9, vb1, 128, 128, 64, 64, stream);
  run_bn(vb1, xb1, bnp, bnsc, bnsh, g1b, b1b, 128, 4096, stream);

  // ---- decoder stage 2: 64x64 -> 128x128, Ctot=128 ----
  k_upw<<<(128*64*4+255)/256, 256, 0, stream>>>(up_w2, Wt4, 128, 64);
  k_upconv_nhwc<<<dim3(4096/64, 64/64, B_), 256, 0, stream>>>(xb1, Wt4, up_b2, cc2, 128, 64, 64, 64, 128);
  k_feat2cc<<<dim3(16384/32, 64/32, B_), dim3(32,8), 0, stream>>>(feat0, cc2, 64, 64, 128, 16384);
  run_conv(cc2, cw2a, W9, va2, 128, 64, 128, 128, stream);
  run_bn(va2, xa2, bnp, bnsc, bnsh, g2a, b2a, 64, 16384, stream);
  run_conv(xa2, cw2b, W9, vb2, 64, 64, 128, 128, stream);
  run_bn(vb2, xb2, bnp, bnsc, bnsh, g2b, b2b, 64, 16384, stream);

  // ---- head ----
  k_last_nhwc<<<(B_*16384)/256, 256, 0, stream>>>(xb2, lw, lb, (float*)d_out);
}

// Round 3
// 2187.224 us; speedup vs baseline: 1.0870x; 1.0220x over previous
//
#include <hip/hip_runtime.h>

#define B_    16
#define NTOK  256
#define D_    512
#define HEADS 16
#define DH    32
#define DEPTH 12
#define KCODE 2048
#define M_    (B_*NTOK)   // 4096 token rows
#define BN_S  512         // BN partial blocks

typedef __attribute__((ext_vector_type(8))) short short8;     // 8 bf16 (4 VGPRs)
typedef __attribute__((ext_vector_type(4))) float float4v;
typedef __attribute__((ext_vector_type(16))) float float16v;  // 32x32 MFMA acc
typedef __attribute__((ext_vector_type(4))) unsigned int uint4v;
typedef __attribute__((ext_vector_type(2))) unsigned int uint2v;
typedef unsigned short ushort;

__device__ __forceinline__ ushort f2b(float f){   // fp32 -> bf16 RNE
  union { float f; unsigned u; } v; v.f = f;
  unsigned r = v.u + 0x7FFFu + ((v.u >> 16) & 1u);
  return (ushort)(r >> 16);
}
__device__ __forceinline__ float b2f(ushort h){
  union { unsigned u; float f; } v; v.u = ((unsigned)h) << 16; return v.f;
}
__device__ __forceinline__ float bits2f(unsigned u){
  union { unsigned u; float f; } v; v.u = u; return v.f;
}

// async global->LDS, 16B per lane; LDS dest = wave-uniform base + lane*16
typedef __attribute__((address_space(3))) unsigned int lds_uint;
typedef __attribute__((address_space(1))) const unsigned int glob_uint;
__device__ __forceinline__ void gl_lds16(const ushort* g, ushort* l){
  __builtin_amdgcn_global_load_lds((glob_uint*)g, (lds_uint*)l, 16, 0, 0);
}

// ---------------- prep kernels ----------------

// tiled transpose: x [b][D][NTOK] -> tok [b][NTOK][D], + pos.  32x32 LDS tile,
// coalesced on both sides. grid (NTOK/32, D/32, B), block (32,8).
__global__ void k_tok_init(const float* __restrict__ x, const float* __restrict__ pos,
                           float* __restrict__ tok){
  __shared__ float t[32][33];
  const int t0 = blockIdx.x*32, d0 = blockIdx.y*32, b = blockIdx.z;
  const int tx = threadIdx.x, ty = threadIdx.y;
  #pragma unroll
  for (int i = 0; i < 4; ++i){
    int d = d0 + ty + i*8;
    t[ty + i*8][tx] = x[((size_t)(b*D_ + d))*NTOK + t0 + tx];
  }
  __syncthreads();
  #pragma unroll
  for (int i = 0; i < 4; ++i){
    int tt = t0 + ty + i*8;
    tok[((size_t)(b*NTOK + tt))*D_ + d0 + tx] = t[tx][ty + i*8] + pos[(size_t)tt*D_ + d0 + tx];
  }
}

__global__ void k_split(const float* __restrict__ src, ushort* __restrict__ oh,
                        ushort* __restrict__ ol, int n){
  int i = blockIdx.x*256 + threadIdx.x;
  if (i >= n) return;
  float v = src[i];
  ushort h = f2b(v);
  oh[i] = h; ol[i] = f2b(v - b2f(h));
}

// split + transpose: src [L][K][N] f32 -> dst hi/lo [L][N][K] bf16.
// 32x32 LDS tile, coalesced read (along N) and write (along K).
// grid (N/32, K/32, L), block (32,8). K,N multiples of 32.
__global__ void k_split_t(const float* __restrict__ src, ushort* __restrict__ oh,
                          ushort* __restrict__ ol, int K, int N){
  __shared__ float t[32][33];
  const int n0 = blockIdx.x*32, k0 = blockIdx.y*32;
  const size_t lb = (size_t)blockIdx.z*K*N;
  const int tx = threadIdx.x, ty = threadIdx.y;
  #pragma unroll
  for (int i = 0; i < 4; ++i){
    int k = k0 + ty + i*8;
    t[ty + i*8][tx] = src[lb + (size_t)k*N + n0 + tx];
  }
  __syncthreads();
  #pragma unroll
  for (int i = 0; i < 4; ++i){
    int n = n0 + ty + i*8;
    float v = t[tx][ty + i*8];
    ushort h = f2b(v);
    size_t o = lb + (size_t)n*K + k0 + tx;
    oh[o] = h; ol[o] = f2b(v - b2f(h));
  }
}

// conv weights: [Cout][Cin][3][3] f32 -> W9 [9tap][Cout][Cin] bf16
__global__ void k_w9(const float* __restrict__ w, ushort* __restrict__ W9,
                     int Cin, int Cout){
  int i = blockIdx.x*256 + threadIdx.x;
  if (i >= Cout*Cin*9) return;
  int co = i / (Cin*9); int r = i - co*(Cin*9);
  int ci = r / 9; int tap = r - ci*9;
  W9[((size_t)tap*Cout + co)*Cin + ci] = f2b(w[i]);
}

// upconv weights: [Cin][Cout][2][2] f32 -> Wt4 [tap][Cout][Cin] bf16
__global__ void k_upw(const float* __restrict__ w, ushort* __restrict__ Wt4,
                      int Cin, int Cout){
  int i = blockIdx.x*256 + threadIdx.x;
  if (i >= Cin*Cout*4) return;
  int ci = i / (Cout*4); int r = i - ci*(Cout*4);
  int co = r >> 2; int tap = r & 3;
  Wt4[((size_t)tap*Cout + co)*Cin + ci] = f2b(w[i]);
}

// LayerNorm fused with bf16 hi/lo split
__global__ void k_ln_split(const float* __restrict__ in, ushort* __restrict__ oh,
                           ushort* __restrict__ ol, const float* __restrict__ g,
                           const float* __restrict__ bta){
  int row = blockIdx.x; int t = threadIdx.x;
  const float* xr = in + (size_t)row*D_;
  float x0 = xr[t], x1 = xr[t+256];
  __shared__ float r1[256], r2[256];
  r1[t] = x0+x1; r2[t] = x0*x0 + x1*x1;
  __syncthreads();
  for (int off=128; off>0; off>>=1){
    if (t<off){ r1[t]+=r1[t+off]; r2[t]+=r2[t+off]; }
    __syncthreads();
  }
  float mean = r1[0] * (1.f/D_);
  float var  = r2[0] * (1.f/D_) - mean*mean;
  float inv  = rsqrtf(var + 1e-5f);
  float y0 = (x0-mean)*inv*g[t]     + bta[t];
  float y1 = (x1-mean)*inv*g[t+256] + bta[t+256];
  size_t o = (size_t)row*D_;
  ushort h0 = f2b(y0), h1 = f2b(y1);
  oh[o+t] = h0;     ol[o+t]     = f2b(y0 - b2f(h0));
  oh[o+t+256] = h1; ol[o+t+256] = f2b(y1 - b2f(h1));
}

// ------ split-bf16 MFMA GEMM, 128x128 tile (3-term, fp32-accurate) ------
__global__ __launch_bounds__(256,2) void k_gemm_split(
    const ushort* __restrict__ Ah, const ushort* __restrict__ Al,
    const ushort* __restrict__ Bh, const ushort* __restrict__ Bl,
    float* __restrict__ C, const float* __restrict__ bias,
    const float* __restrict__ resid, int M, int N, int K){
  __shared__ ushort Ash[128][32], Asl[128][32], Bsh[128][32], Bsl[128][32];
  const int tid = threadIdx.x;
  const int m_base = blockIdx.x*128, n_base = blockIdx.y*128;
  const int lane = tid & 63, wv = tid >> 6;
  const int quad = lane >> 4, r16 = lane & 15;
  const int m_off = (wv & 1)*64, n_off = (wv >> 1)*64;
  const int lrow = lane >> 2, lseg = lane & 3;
  const int row0 = wv*32 + lrow;              // rows row0 and row0+16
  const int us   = lseg ^ ((row0 >> 1) & 3);  // (row0+16)>>1 has same &3
  const size_t offA0 = (size_t)(m_base + row0)*K + us*8;
  const size_t offA1 = offA0 + (size_t)16*K;
  const size_t offB0 = (size_t)(n_base + row0)*K + us*8;
  const size_t offB1 = offB0 + (size_t)16*K;
  ushort* lAh = &Ash[0][0] + wv*1024;   // wave-uniform LDS dest (shorts)
  ushort* lAl = &Asl[0][0] + wv*1024;
  ushort* lBh = &Bsh[0][0] + wv*1024;
  ushort* lBl = &Bsl[0][0] + wv*1024;
  float4v acc[4][4];
  #pragma unroll
  for (int i = 0; i < 4; ++i)
    #pragma unroll
    for (int j = 0; j < 4; ++j) acc[i][j] = float4v{0.f,0.f,0.f,0.f};
  for (int k0 = 0; k0 < K; k0 += 32){
    gl_lds16(Ah + offA0 + k0, lAh);
    gl_lds16(Ah + offA1 + k0, lAh + 512);
    gl_lds16(Al + offA0 + k0, lAl);
    gl_lds16(Al + offA1 + k0, lAl + 512);
    gl_lds16(Bh + offB0 + k0, lBh);
    gl_lds16(Bh + offB1 + k0, lBh + 512);
    gl_lds16(Bl + offB0 + k0, lBl);
    gl_lds16(Bl + offB1 + k0, lBl + 512);
    __syncthreads();   // drains vmcnt -> staged data visible
    short8 ah[4], al[4], bh[4], bl[4];
    #pragma unroll
    for (int i = 0; i < 4; ++i){
      int ra = m_off + i*16 + r16;
      int rb = n_off + i*16 + r16;
      int sa = (quad ^ ((ra >> 1) & 3))*8;
      int sb = (quad ^ ((rb >> 1) & 3))*8;
      ah[i] = *(const short8*)&Ash[ra][sa];
      al[i] = *(const short8*)&Asl[ra][sa];
      bh[i] = *(const short8*)&Bsh[rb][sb];
      bl[i] = *(const short8*)&Bsl[rb][sb];
    }
    #pragma unroll
    for (int i = 0; i < 4; ++i)
      #pragma unroll
      for (int j = 0; j < 4; ++j){
        acc[i][j] = __builtin_amdgcn_mfma_f32_16x16x32_bf16(bh[j], ah[i], acc[i][j], 0,0,0);
        acc[i][j] = __builtin_amdgcn_mfma_f32_16x16x32_bf16(bh[j], al[i], acc[i][j], 0,0,0);
        acc[i][j] = __builtin_amdgcn_mfma_f32_16x16x32_bf16(bl[j], ah[i], acc[i][j], 0,0,0);
      }
    __syncthreads();
  }
  #pragma unroll
  for (int i = 0; i < 4; ++i){
    int m = m_base + m_off + i*16 + r16;
    #pragma unroll
    for (int j = 0; j < 4; ++j){
      int n = n_base + n_off + j*16 + quad*4;
      float4v v = acc[i][j];
      if (bias)  v += *(const float4v*)(bias + n);
      if (resid) v += *(const float4v*)(resid + (size_t)m*N + n);
      *(float4v*)(C + (size_t)m*N + n) = v;
    }
  }
}

// ---------------- attention: one block per (b,h), K/V in LDS ----------------
__global__ __launch_bounds__(512) void k_attn2(const float* __restrict__ qkv,
                                               ushort* __restrict__ oh,
                                               ushort* __restrict__ ol){
  __shared__ float4v smem[NTOK*16];          // [0,2048)=K, [2048,4096)=V
  float4v* ks = smem;
  float4v* vs = smem + NTOK*8;
  const int h = blockIdx.x, b = blockIdx.y, t = threadIdx.x;
  const int tq = t & 255, half = t >> 8;
  const float* base = qkv + (size_t)b*NTOK*1536;
  const int koff = 512 + h*DH, voff = 1024 + h*DH;
  for (int i = t; i < NTOK*8; i += 512){
    int j = i >> 3, d4 = i & 7;
    ks[i] = *(const float4v*)(base + (size_t)j*1536 + koff + d4*4);
    vs[i] = *(const float4v*)(base + (size_t)j*1536 + voff + d4*4);
  }
  float4v q8[8];
  const float* qrow = base + (size_t)tq*1536 + h*DH;
  #pragma unroll
  for (int d4 = 0; d4 < 8; ++d4) q8[d4] = *(const float4v*)(qrow + d4*4);
  __syncthreads();
  float4v o8[8];
  #pragma unroll
  for (int d4 = 0; d4 < 8; ++d4) o8[d4] = float4v{0.f,0.f,0.f,0.f};
  float l = 0.f;
  const int j0 = half*128, j1 = j0 + 128;
  for (int j = j0; j < j1; ++j){
    float s = 0.f;
    #pragma unroll
    for (int d4 = 0; d4 < 8; ++d4){
      float4v kk = ks[j*8 + d4];
      s += q8[d4].x*kk.x + q8[d4].y*kk.y + q8[d4].z*kk.z + q8[d4].w*kk.w;
    }
    float e = __expf(s * 0.17677669529663689f);
    l += e;
    #pragma unroll
    for (int d4 = 0; d4 < 8; ++d4){
      float4v vv = vs[j*8 + d4];
      o8[d4].x += e*vv.x; o8[d4].y += e*vv.y; o8[d4].z += e*vv.z; o8[d4].w += e*vv.w;
    }
  }
  __syncthreads();                           // everyone done with K/V
  if (half){
    float4v* st = smem + (size_t)tq*9;       // stride 9 to dodge bank aliasing
    #pragma unroll
    for (int d4 = 0; d4 < 8; ++d4) st[d4] = o8[d4];
    ((float*)smem)[9216 + tq] = l;
  }
  __syncthreads();
  if (!half){
    const float4v* st = smem + (size_t)tq*9;
    #pragma unroll
    for (int d4 = 0; d4 < 8; ++d4) o8[d4] += st[d4];
    l += ((float*)smem)[9216 + tq];
    float inv = 1.f / l;
    size_t ob = (size_t)(b*NTOK + tq)*D_ + h*DH;
    #pragma unroll
    for (int d4 = 0; d4 < 8; ++d4){
      float vals[4] = {o8[d4].x*inv, o8[d4].y*inv, o8[d4].z*inv, o8[d4].w*inv};
      #pragma unroll
      for (int r = 0; r < 4; ++r){
        ushort hh = f2b(vals[r]);
        oh[ob + d4*4 + r] = hh;
        ol[ob + d4*4 + r] = f2b(vals[r] - b2f(hh));
      }
    }
  }
}

// ---------------- VQ ----------------
__global__ void k_cnorm(const float* __restrict__ cb, float* __restrict__ cnorm){
  int k = blockIdx.x, t = threadIdx.x;
  float v1 = cb[(size_t)k*D_ + t];
  float v2 = cb[(size_t)k*D_ + t + 256];
  __shared__ float r[256];
  r[t] = v1*v1 + v2*v2;
  __syncthreads();
  for (int off=128; off>0; off>>=1){
    if (t<off) r[t]+=r[t+off];
    __syncthreads();
  }
  if (t==0) cnorm[k] = r[0];
}

__global__ void k_argmin(const float* __restrict__ d2, const float* __restrict__ cnorm,
                         int* __restrict__ idx){
  int m = blockIdx.x, t = threadIdx.x;
  float best = 3.4e38f; int bk = 0;
  for (int k = t; k < KCODE; k += 256){
    float s = cnorm[k] - 2.f*d2[(size_t)m*KCODE + k];
    if (s < best){ best = s; bk = k; }
  }
  __shared__ float bs[256]; __shared__ int bi[256];
  bs[t]=best; bi[t]=bk;
  __syncthreads();
  for (int off=128; off>0; off>>=1){
    if (t<off){
      if (bs[t+off] < bs[t] || (bs[t+off]==bs[t] && bi[t+off]<bi[t])){
        bs[t]=bs[t+off]; bi[t]=bi[t+off];
      }
    }
    __syncthreads();
  }
  if (t==0) idx[m] = bi[0];
}

// y0 NHWC bf16: y0[b][t][d] = codebook[idx[b,t]][d]
__global__ void k_gather_nhwc(const float* __restrict__ cb, const int* __restrict__ idx,
                              ushort* __restrict__ y0){
  int i = blockIdx.x*256 + threadIdx.x;
  if (i >= B_*NTOK*D_) return;
  int d = i % D_; int r = i / D_; int t = r % NTOK; int b = r / NTOK;
  y0[i] = f2b(cb[(size_t)idx[b*NTOK + t]*D_ + d]);
}

// ---------------- decoder (NHWC bf16) ----------------

// 3x3 conv pad1, 8x8 tile, 16x16x32 MFMA (kept for stage 0, H=32).
__global__ __launch_bounds__(256) void k_conv_nhwc(
    const ushort* __restrict__ X, const ushort* __restrict__ W9,
    float* __restrict__ Y, int Cin, int Cout, int H, int W){
  __shared__ ushort Xs[128][36];      // 10x10 patch rows x 32ch (100 rows used)
  __shared__ ushort Ws[576][36];      // 9 taps x 64 co x 32 ch
  const int HW = H*W;
  const int tid = threadIdx.x;
  const int b = blockIdx.z;
  const int tiles_w = W >> 3;
  const int th0 = (blockIdx.x / tiles_w) * 8;
  const int tw0 = (blockIdx.x - (blockIdx.x / tiles_w)*tiles_w) * 8;
  const int n_base = blockIdx.y*64;
  const int lane = tid & 63, wv = tid >> 6;
  const int quad = lane >> 4, r16 = lane & 15;
  const int m_off = (wv & 1)*32, n_off = (wv >> 1)*32;
  const ushort* Xb = X + (size_t)b*HW*Cin;
  const ushort* sptr[2]; int srw[2], ssg[2]; bool sok[2];
  #pragma unroll
  for (int e = 0; e < 2; ++e){
    int item = tid + e*256;
    int row = (item >> 2) & 127;
    int seg = item & 3;
    int ph = row / 10, pw = row - ph*10;
    int gh = th0 + ph - 1, gw = tw0 + pw - 1;
    bool ok = (item < 400) && gh >= 0 && gh < H && gw >= 0 && gw < W;
    int pidx = ok ? (gh*W + gw) : 0;
    srw[e] = row; ssg[e] = seg; sok[e] = ok;
    sptr[e] = Xb + ((size_t)pidx*Cin + seg*8);
  }
  const ushort* wptr[9]; int wrw[9], wsg[9];
  #pragma unroll
  for (int e = 0; e < 9; ++e){
    int item = tid + e*256;
    int row = item >> 2;                 // 0..575
    int seg = item & 3;
    int tap = row >> 6, co = row & 63;
    wrw[e] = row; wsg[e] = seg;
    wptr[e] = W9 + ((size_t)tap*Cout + n_base + co)*Cin + seg*8;
  }
  const uint4v zz = {};
  float4v a00={}, a01={}, a10={}, a11={};
  const int mA = m_off + r16, mB = mA + 16;
  const int rA0 = ((mA>>3))*10 + (mA&7);    // patch row for tap (0,0)
  const int rB0 = ((mB>>3))*10 + (mB&7);
  for (int k0 = 0; k0 < Cin; k0 += 32){
    if (k0) __syncthreads();
    #pragma unroll
    for (int e = 0; e < 2; ++e){
      uint4v v = sok[e] ? *(const uint4v*)(sptr[e] + k0) : zz;
      *(uint4v*)&Xs[srw[e]][ssg[e]*8] = v;
    }
    #pragma unroll
    for (int e = 0; e < 9; ++e)
      *(uint4v*)&Ws[wrw[e]][wsg[e]*8] = *(const uint4v*)(wptr[e] + k0);
    __syncthreads();
    #pragma unroll
    for (int tap = 0; tap < 9; ++tap){
      const int kh = tap/3, kw = tap - (tap/3)*3;
      short8 wf0 = *(const short8*)&Ws[tap*64 + n_off      + r16][quad*8];
      short8 wf1 = *(const short8*)&Ws[tap*64 + n_off + 16 + r16][quad*8];
      short8 xf0 = *(const short8*)&Xs[rA0 + kh*10 + kw][quad*8];
      short8 xf1 = *(const short8*)&Xs[rB0 + kh*10 + kw][quad*8];
      a00 = __builtin_amdgcn_mfma_f32_16x16x32_bf16(wf0, xf0, a00, 0,0,0);
      a01 = __builtin_amdgcn_mfma_f32_16x16x32_bf16(wf0, xf1, a01, 0,0,0);
      a10 = __builtin_amdgcn_mfma_f32_16x16x32_bf16(wf1, xf0, a10, 0,0,0);
      a11 = __builtin_amdgcn_mfma_f32_16x16x32_bf16(wf1, xf1, a11, 0,0,0);
    }
  }
  float* Yb = Y + (size_t)b*HW*Cout;
  int pA = (th0 + (mA>>3))*W + tw0 + (mA&7);
  int pB = (th0 + (mB>>3))*W + tw0 + (mB&7);
  int co0 = n_base + n_off + quad*4, co1 = co0 + 16;
  *(float4v*)(Yb + (size_t)pA*Cout + co0) = a00;
  *(float4v*)(Yb + (size_t)pB*Cout + co0) = a01;
  *(float4v*)(Yb + (size_t)pA*Cout + co1) = a10;
  *(float4v*)(Yb + (size_t)pB*Cout + co1) = a11;
}

// 3x3 conv pad1, 16x16 pixel tile, 32x32x16 MFMA. 4 waves, each 64px x 64co
// (2x2 32-frags). 18x18 patch (324 rows) x 32ch staged; weights 9x64 rows.
// LDS rows padded to 34 shorts (68B): bank stride 17 coprime 32 -> fragment
// reads across 32 consecutive rows are bank-conflict-free.
// grid ((H/16)*(W/16), Cout/64, B_).
__global__ __launch_bounds__(256,2) void k_conv16(
    const ushort* __restrict__ X, const ushort* __restrict__ W9,
    float* __restrict__ Y, int Cin, int Cout, int H, int W){
  __shared__ ushort Xs[324][34];
  __shared__ ushort Ws[576][34];
  const int HW = H*W;
  const int tid = threadIdx.x;
  const int b = blockIdx.z;
  const int tiles_w = W >> 4;
  const int th0 = (blockIdx.x / tiles_w) * 16;
  const int tw0 = (blockIdx.x - (blockIdx.x / tiles_w)*tiles_w) * 16;
  const int n_base = blockIdx.y*64;
  const int lane = tid & 63, wv = tid >> 6;
  const int l31 = lane & 31, hi8 = (lane >> 5)*8;
  const ushort* Xb = X + (size_t)b*HW*Cin;
  // X staging: 1296 items (324 patch rows x 4 ch-segs); e=0..4 full, e=5 tid<16
  const ushort* sptr[6]; ushort* sdst[6]; bool sok[6];
  #pragma unroll
  for (int e = 0; e < 6; ++e){
    int item = tid + e*256;
    int row = item >> 2;
    int seg = item & 3;
    if (row > 323) row = 323;            // clamped; e=5 write is guarded
    int ph = row / 18, pw = row - ph*18;
    int gh = th0 + ph - 1, gw = tw0 + pw - 1;
    bool ok = gh >= 0 && gh < H && gw >= 0 && gw < W;
    int pidx = ok ? (gh*W + gw) : 0;
    sok[e] = ok;
    sptr[e] = Xb + ((size_t)pidx*Cin + seg*8);
    sdst[e] = &Xs[row][seg*8];
  }
  // W staging: 2304 items (576 rows x 4 segs), 9/thread
  const ushort* wptr[9]; ushort* wdst[9];
  #pragma unroll
  for (int e = 0; e < 9; ++e){
    int item = tid + e*256;
    int row = item >> 2;                 // 0..575
    int seg = item & 3;
    int tap = row >> 6, co = row & 63;
    wdst[e] = &Ws[row][seg*8];
    wptr[e] = W9 + ((size_t)tap*Cout + n_base + co)*Cin + seg*8;
  }
  const uint4v zz = {};
  float16v a00={}, a01={}, a10={}, a11={};   // a[nfrag][mfrag]
  const int lrow = (lane & 15) + ((lane & 16) ? 18 : 0);
  const int pr0 = wv*72 + lrow;              // patch row, tap(0,0), m-frag 0
  for (int k0 = 0; k0 < Cin; k0 += 32){
    if (k0) __syncthreads();
    #pragma unroll
    for (int e = 0; e < 6; ++e){
      if (e < 5 || tid < 16){
        uint4v v = sok[e] ? *(const uint4v*)(sptr[e] + k0) : zz;
        *(uint4v*)sdst[e] = v;
      }
    }
    #pragma unroll
    for (int e = 0; e < 9; ++e)
      *(uint4v*)wdst[e] = *(const uint4v*)(wptr[e] + k0);
    __syncthreads();
    #pragma unroll
    for (int s = 0; s < 2; ++s){
      const int kc = s*16 + hi8;
      #pragma unroll
      for (int tap = 0; tap < 9; ++tap){
        const int kh = tap/3, kw = tap - (tap/3)*3;
        const int xr = pr0 + kh*18 + kw;
        short8 x0 = *(const short8*)&Xs[xr     ][kc];
        short8 x1 = *(const short8*)&Xs[xr + 36][kc];
        short8 w0 = *(const short8*)&Ws[tap*64      + l31][kc];
        short8 w1 = *(const short8*)&Ws[tap*64 + 32 + l31][kc];
        a00 = __builtin_amdgcn_mfma_f32_32x32x16_bf16(w0, x0, a00, 0,0,0);
        a01 = __builtin_amdgcn_mfma_f32_32x32x16_bf16(w0, x1, a01, 0,0,0);
        a10 = __builtin_amdgcn_mfma_f32_32x32x16_bf16(w1, x0, a10, 0,0,0);
        a11 = __builtin_amdgcn_mfma_f32_32x32x16_bf16(w1, x1, a11, 0,0,0);
      }
    }
  }
  // epilogue: acc reg r -> co = n_base + nfrag*32 + 8*(r>>2) + 4*(lane>>5) + (r&3)
  //           pixel = tile px wv*64 + mfrag*32 + l31
  float* Yb = Y + (size_t)b*HW*Cout;
  const int co4 = (lane >> 5)*4;
  #pragma unroll
  for (int i = 0; i < 2; ++i){
    int p = wv*64 + i*32 + l31;
    int gp = (th0 + (p >> 4))*W + tw0 + (p & 15);
    float* yr = Yb + (size_t)gp*Cout + n_base + co4;
    float16v A0 = i ? a01 : a00;
    float16v A1 = i ? a11 : a10;
    #pragma unroll
    for (int q = 0; q < 4; ++q){
      float4v v0 = {A0[4*q+0], A0[4*q+1], A0[4*q+2], A0[4*q+3]};
      float4v v1 = {A1[4*q+0], A1[4*q+1], A1[4*q+2], A1[4*q+3]};
      *(float4v*)(yr + 8*q)      = v0;
      *(float4v*)(yr + 32 + 8*q) = v1;
    }
  }
}

// ConvTranspose2d k=2 s=2: X staged once per K-chunk, 4 weight taps share it.
__global__ __launch_bounds__(256) void k_upconv_nhwc(
    const ushort* __restrict__ X, const ushort* __restrict__ Wt4,
    const float* __restrict__ bias, ushort* __restrict__ CC,
    int Cin, int Cout, int Hi, int Wi, int Ctot){
  __shared__ ushort Xs[64][40], Ws[4][64][40];
  const int HWi = Hi*Wi;
  const int tid = threadIdx.x;
  const int b = blockIdx.z;
  const int m_base = blockIdx.x*64;
  const int n_base = blockIdx.y*64;
  const int lane = tid & 63, wv = tid >> 6;
  const int quad = lane >> 4, r16 = lane & 15;
  const int m_off = (wv & 1)*32, n_off = (wv >> 1)*32;
  const int srow = tid & 63, skq = tid >> 6;
  const ushort* xrow = X + ((size_t)b*HWi + m_base + srow)*Cin + skq*8;
  const ushort* w0 = Wt4 + ((size_t)0*Cout + n_base + srow)*Cin + skq*8;
  const ushort* w1 = Wt4 + ((size_t)1*Cout + n_base + srow)*Cin + skq*8;
  const ushort* w2 = Wt4 + ((size_t)2*Cout + n_base + srow)*Cin + skq*8;
  const ushort* w3 = Wt4 + ((size_t)3*Cout + n_base + srow)*Cin + skq*8;
  float4v acc[4][4];
  #pragma unroll
  for (int t = 0; t < 4; ++t)
    #pragma unroll
    for (int q = 0; q < 4; ++q) acc[t][q] = float4v{0.f,0.f,0.f,0.f};
  for (int k0 = 0; k0 < Cin; k0 += 32){
    *(uint4v*)&Xs[srow][skq*8]    = *(const uint4v*)(xrow + k0);
    *(uint4v*)&Ws[0][srow][skq*8] = *(const uint4v*)(w0 + k0);
    *(uint4v*)&Ws[1][srow][skq*8] = *(const uint4v*)(w1 + k0);
    *(uint4v*)&Ws[2][srow][skq*8] = *(const uint4v*)(w2 + k0);
    *(uint4v*)&Ws[3][srow][skq*8] = *(const uint4v*)(w3 + k0);
    __syncthreads();
    short8 xf0 = *(const short8*)&Xs[m_off      + r16][quad*8];
    short8 xf1 = *(const short8*)&Xs[m_off + 16 + r16][quad*8];
    #pragma unroll
    for (int t = 0; t < 4; ++t){
      short8 wf0 = *(const short8*)&Ws[t][n_off      + r16][quad*8];
      short8 wf1 = *(const short8*)&Ws[t][n_off + 16 + r16][quad*8];
      acc[t][0] = __builtin_amdgcn_mfma_f32_16x16x32_bf16(wf0, xf0, acc[t][0], 0,0,0);
      acc[t][1] = __builtin_amdgcn_mfma_f32_16x16x32_bf16(wf0, xf1, acc[t][1], 0,0,0);
      acc[t][2] = __builtin_amdgcn_mfma_f32_16x16x32_bf16(wf1, xf0, acc[t][2], 0,0,0);
      acc[t][3] = __builtin_amdgcn_mfma_f32_16x16x32_bf16(wf1, xf1, acc[t][3], 0,0,0);
    }
    __syncthreads();
  }
  const int Wo = 2*Wi, HWo = 4*HWi;
  int co0 = n_base + n_off + quad*4, co1 = co0 + 16;
  float4v bv0 = *(const float4v*)(bias + co0);
  float4v bv1 = *(const float4v*)(bias + co1);
  int px0 = m_base + m_off + r16, px1 = px0 + 16;
  #pragma unroll
  for (int j = 0; j < 2; ++j){
    int p = j ? px1 : px0;
    int r = p / Wi, c = p - r*Wi;
    #pragma unroll
    for (int t = 0; t < 4; ++t){
      int opix = (2*r + (t>>1))*Wo + 2*c + (t&1);
      ushort* o = CC + ((size_t)b*HWo + opix)*Ctot;
      float4v vA = acc[t][0 + j] + bv0;
      float4v vB = acc[t][2 + j] + bv1;
      uint2v pA, pB;
      pA.x = (unsigned)f2b(vA.x) | ((unsigned)f2b(vA.y) << 16);
      pA.y = (unsigned)f2b(vA.z) | ((unsigned)f2b(vA.w) << 16);
      pB.x = (unsigned)f2b(vB.x) | ((unsigned)f2b(vB.y) << 16);
      pB.y = (unsigned)f2b(vB.z) | ((unsigned)f2b(vB.w) << 16);
      *(uint2v*)(o + co0) = pA;
      *(uint2v*)(o + co1) = pB;
    }
  }
}

// NCHW fp32 skip feature -> NHWC bf16 concat channels [Coff, Coff+Cf)
__global__ void k_feat2cc(const float* __restrict__ feat, ushort* __restrict__ cc,
                          int Cf, int Coff, int Ctot, int HW){
  __shared__ ushort t[32][33];
  int pb = blockIdx.x*32, cbs = blockIdx.y*32, b = blockIdx.z;
  int tx = threadIdx.x, ty = threadIdx.y;
  #pragma unroll
  for (int i = 0; i < 4; ++i){
    int c = cbs + ty + i*8;
    t[ty + i*8][tx] = f2b(feat[((size_t)(b*Cf) + c)*HW + pb + tx]);
  }
  __syncthreads();
  #pragma unroll
  for (int i = 0; i < 4; ++i){
    int p = pb + ty + i*8;
    cc[((size_t)b*HW + p)*Ctot + Coff + cbs + tx] = t[tx][ty + i*8];
  }
}

// BN stats phase 1: BN_S blocks, float4 channel-quads, LDS cross-group reduce.
__global__ __launch_bounds__(256) void k_bnstats_nhwc(
    const float* __restrict__ x, float* __restrict__ part, int C, int HW){
  const int s = blockIdx.x, tid = threadIdx.x;
  const int R = B_*HW;
  const int chunk = R / BN_S;
  const int L = C >> 2;
  const int G = 256 / L;
  const int c4 = tid % L, g = tid / L;
  float4v a = {}, q = {};
  const float* xb = x + (size_t)(s*chunk)*C + 4*c4;
  for (int r = g; r < chunk; r += G){
    float4v v = *(const float4v*)(xb + (size_t)r*C);
    a += v; q += v*v;
  }
  __shared__ float4v h1[256], h2[256];
  h1[tid] = a; h2[tid] = q;
  __syncthreads();
  if (tid < L){
    float4v ra = h1[tid], rq = h2[tid];
    for (int gg = 1; gg < G; ++gg){ ra += h1[tid + gg*L]; rq += h2[tid + gg*L]; }
    int c0 = 4*c4;
    part[(size_t)(c0+0)*BN_S + s] = ra.x;
    part[(size_t)(c0+1)*BN_S + s] = ra.y;
    part[(size_t)(c0+2)*BN_S + s] = ra.z;
    part[(size_t)(c0+3)*BN_S + s] = ra.w;
    part[(size_t)(C+c0+0)*BN_S + s] = rq.x;
    part[(size_t)(C+c0+1)*BN_S + s] = rq.y;
    part[(size_t)(C+c0+2)*BN_S + s] = rq.z;
    part[(size_t)(C+c0+3)*BN_S + s] = rq.w;
  }
}

// BN finalize: one block per channel reduces BN_S partials -> scale/shift
__global__ void k_bnfinal(const float* __restrict__ part, const float* __restrict__ g,
                          const float* __restrict__ bb, float* __restrict__ scale,
                          float* __restrict__ shift, int C, int cnt){
  int c = blockIdx.x, t = threadIdx.x;  // 256 threads
  __shared__ float r1[256], r2[256];
  r1[t] = part[(size_t)c*BN_S + t]       + part[(size_t)c*BN_S + t + 256];
  r2[t] = part[(size_t)(C + c)*BN_S + t] + part[(size_t)(C + c)*BN_S + t + 256];
  __syncthreads();
  for (int off = 128; off > 0; off >>= 1){
    if (t < off){ r1[t] += r1[t+off]; r2[t] += r2[t+off]; }
    __syncthreads();
  }
  if (t == 0){
    float m = r1[0]/cnt;
    float v = r2[0]/cnt - m*m;
    float sc = g[c]*rsqrtf(v + 1e-5f);
    scale[c] = sc;
    shift[c] = bb[c] - m*sc;
  }
}

// BN apply + ReLU, fp32 NHWC -> bf16 NHWC
__global__ void k_bnapply_nhwc(const float* __restrict__ x, ushort* __restrict__ y,
                               const float* __restrict__ scale,
                               const float* __restrict__ shift, int C, int n4){
  int i = blockIdx.x*256 + threadIdx.x;
  if (i >= n4) return;
  float4v v = *(const float4v*)(x + (size_t)4*i);
  int c0 = (4*i) % C;
  float4v sc = *(const float4v*)(scale + c0);
  float4v sh = *(const float4v*)(shift + c0);
  float r0 = fmaxf(v.x*sc.x + sh.x, 0.f);
  float r1 = fmaxf(v.y*sc.y + sh.y, 0.f);
  float r2 = fmaxf(v.z*sc.z + sh.z, 0.f);
  float r3 = fmaxf(v.w*sc.w + sh.w, 0.f);
  uint2v pk;
  pk.x = (unsigned)f2b(r0) | ((unsigned)f2b(r1) << 16);
  pk.y = (unsigned)f2b(r2) | ((unsigned)f2b(r3) << 16);
  *(uint2v*)(y + (size_t)4*i) = pk;
}

// final 1x1 conv (64ch NHWC bf16 -> 1) + sigmoid
__global__ void k_last_nhwc(const ushort* __restrict__ x, const float* __restrict__ lw,
                            const float* __restrict__ lb, float* __restrict__ out){
  __shared__ float wsm[64];
  int tid = threadIdx.x;
  if (tid < 64) wsm[tid] = lw[tid];
  __syncthreads();
  int i = blockIdx.x*256 + tid;
  const uint4v* xr = (const uint4v*)(x + (size_t)i*64);
  float acc = lb[0];
  #pragma unroll
  for (int q = 0; q < 8; ++q){
    uint4v u = xr[q];
    unsigned uu[4] = {u.x, u.y, u.z, u.w};
    #pragma unroll
    for (int k = 0; k < 4; ++k){
      acc += bits2f(uu[k] << 16)          * wsm[q*8 + 2*k];
      acc += bits2f(uu[k] & 0xffff0000u)  * wsm[q*8 + 2*k + 1];
    }
  }
  out[i] = 1.f/(1.f + __expf(-acc));
}

// ---------------- host ----------------
#define MBx 1048576ull

static inline void run_conv(const ushort* in, const float* w, ushort* W9,
                            float* out, int Cin, int Cout, int H, int W,
                            hipStream_t stream){
  int total = Cout*Cin*9;
  k_w9<<<(total+255)/256, 256, 0, stream>>>(w, W9, Cin, Cout);
  k_conv_nhwc<<<dim3((H>>3)*(W>>3), Cout/64, B_), 256, 0, stream>>>(in, W9, out, Cin, Cout, H, W);
}

static inline void run_conv16(const ushort* in, const float* w, ushort* W9,
                              float* out, int Cin, int Cout, int H, int W,
                              hipStream_t stream){
  int total = Cout*Cin*9;
  k_w9<<<(total+255)/256, 256, 0, stream>>>(w, W9, Cin, Cout);
  k_conv16<<<dim3((H>>4)*(W>>4), Cout/64, B_), 256, 0, stream>>>(in, W9, out, Cin, Cout, H, W);
}

static inline void run_bn(const float* x, ushort* y, float* part, float* scale, float* shift,
                          const float* g, const float* bb, int C, int HW, hipStream_t stream){
  k_bnstats_nhwc<<<BN_S, 256, 0, stream>>>(x, part, C, HW);
  k_bnfinal<<<C, 256, 0, stream>>>(part, g, bb, scale, shift, C, B_*HW);
  int n4 = B_*HW*C/4;
  k_bnapply_nhwc<<<(n4+255)/256, 256, 0, stream>>>(x, y, scale, shift, C, n4);
}

extern "C" void kernel_launch(void* const* d_in, const int* in_sizes, int n_in,
                              void* d_out, int out_size, void* d_ws, size_t ws_size,
                              hipStream_t stream){
  const float* x     = (const float*)d_in[0];
  const float* feat0 = (const float*)d_in[1];
  const float* feat1 = (const float*)d_in[2];
  const float* feat2 = (const float*)d_in[3];
  const float* pos   = (const float*)d_in[4];
  const float* cb    = (const float*)d_in[5];
  const float* ln_g  = (const float*)d_in[6];
  const float* ln_b  = (const float*)d_in[7];
  const float* wqkv  = (const float*)d_in[8];
  const float* wo    = (const float*)d_in[9];
  const float* bo    = (const float*)d_in[10];
  const float* up_w0 = (const float*)d_in[11];
  const float* up_b0 = (const float*)d_in[12];
  const float* cw0a  = (const float*)d_in[13];
  const float* g0a   = (const float*)d_in[14];
  const float* b0a   = (const float*)d_in[15];
  const float* cw0b  = (const float*)d_in[16];
  const float* g0b   = (const float*)d_in[17];
  const float* b0b   = (const float*)d_in[18];
  const float* up_w1 = (const float*)d_in[19];
  const float* up_b1 = (const float*)d_in[20];
  const float* cw1a  = (const float*)d_in[21];
  const float* g1a   = (const float*)d_in[22];
  const float* b1a   = (const float*)d_in[23];
  const float* cw1b  = (const float*)d_in[24];
  const float* g1b   = (const float*)d_in[25];
  const float* b1b   = (const float*)d_in[26];
  const float* up_w2 = (const float*)d_in[27];
  const float* up_b2 = (const float*)d_in[28];
  const float* cw2a  = (const float*)d_in[29];
  const float* g2a   = (const float*)d_in[30];
  const float* b2a   = (const float*)d_in[31];
  const float* cw2b  = (const float*)d_in[32];
  const float* g2b   = (const float*)d_in[33];
  const float* b2b   = (const float*)d_in[34];
  const float* lw    = (const float*)d_in[35];
  const float* lb    = (const float*)d_in[36];

  char* ws = (char*)d_ws;
  // encoder/VQ scratch (region 0..134MB)
  float*  tok     = (float*) (ws);
  ushort* xn_hi   = (ushort*)(ws +  8388608ull);
  ushort* xn_lo   = (ushort*)(ws + 12582912ull);
  float*  qkv     = (float*) (ws + 16777216ull);
  ushort* at_hi   = (ushort*)(ws + 41943040ull);
  ushort* at_lo   = (ushort*)(ws + 46137344ull);
  ushort* tok_hi  = (ushort*)(ws + 50331648ull);
  ushort* tok_lo  = (ushort*)(ws + 54525952ull);
  ushort* Wq_hi   = (ushort*)(ws + 58720256ull);
  ushort* Wq_lo   = (ushort*)(ws + 77594624ull);
  ushort* Wo_hi   = (ushort*)(ws + 96468992ull);
  ushort* Wo_lo   = (ushort*)(ws + 102760448ull);
  ushort* cb_hi   = (ushort*)(ws + 109051904ull);
  ushort* cb_lo   = (ushort*)(ws + 111149056ull);
  float*  cnorm   = (float*) (ws + 113246208ull);
  int*    idx     = (int*)   (ws + 113254400ull);
  float*  d2      = (float*) (ws + 58720256ull);   // overlaps Wq (dead at VQ time)
  // tail: weights + bn scratch + y0
  ushort* W9   = (ushort*)(ws + 134*MBx);          // 2.25 MB max
  float* bnsc  = (float*) (ws + 136*MBx + 524288); // 1 KB
  float* bnsh  = (float*) (ws + 136*MBx + 528384); // 1 KB
  ushort* Wt4  = (ushort*)(ws + 137*MBx);          // 1 MB max
  float* bnp   = (float*) (ws + 138*MBx);          // 1 MB max
  ushort* y0   = (ushort*)(ws + 139*MBx);
  // decoder ping-pong
  ushort* cc0 = (ushort*)(ws + 146*MBx);
  float*  va0 = (float*) (ws + 163*MBx);
  ushort* xa0 = (ushort*)(ws + 180*MBx);
  float*  vb0 = (float*) (ws + 146*MBx);
  ushort* xb0 = (ushort*)(ws + 189*MBx);
  ushort* cc1 = (ushort*)(ws + 0*MBx);
  float*  va1 = (float*) (ws + 34*MBx);
  ushort* xa1 = (ushort*)(ws + 68*MBx);
  float*  vb1 = (float*) (ws + 85*MBx);
  ushort* xb1 = (ushort*)(ws + 146*MBx);
  ushort* cc2 = (ushort*)(ws + 0*MBx);
  float*  va2 = (float*) (ws + 67*MBx);
  ushort* xa2 = (ushort*)(ws + 146*MBx);
  float*  vb2 = (float*) (ws + 0*MBx);
  ushort* xb2 = (ushort*)(ws + 67*MBx);

  // ---- weight prep ----
  k_split_t<<<dim3(1536/32, D_/32, DEPTH), dim3(32,8), 0, stream>>>(wqkv, Wq_hi, Wq_lo, D_, 1536);
  k_split_t<<<dim3(D_/32, D_/32, DEPTH), dim3(32,8), 0, stream>>>(wo, Wo_hi, Wo_lo, D_, D_);
  k_split<<<(KCODE*D_+255)/256, 256, 0, stream>>>(cb, cb_hi, cb_lo, KCODE*D_);
  k_cnorm<<<KCODE, 256, 0, stream>>>(cb, cnorm);

  // ---- encoder ----
  k_tok_init<<<dim3(NTOK/32, D_/32, B_), dim3(32,8), 0, stream>>>(x, pos, tok);
  for (int l = 0; l < DEPTH; ++l){
    k_ln_split<<<M_, 256, 0, stream>>>(tok, xn_hi, xn_lo, ln_g + l*D_, ln_b + l*D_);
    k_gemm_split<<<dim3(M_/128, 1536/128), 256, 0, stream>>>(
        xn_hi, xn_lo, Wq_hi + (size_t)l*1536*D_, Wq_lo + (size_t)l*1536*D_,
        qkv, nullptr, nullptr, M_, 1536, D_);
    k_attn2<<<dim3(HEADS, B_), 512, 0, stream>>>(qkv, at_hi, at_lo);
    k_gemm_split<<<dim3(M_/128, D_/128), 256, 0, stream>>>(
        at_hi, at_lo, Wo_hi + (size_t)l*D_*D_, Wo_lo + (size_t)l*D_*D_,
        tok, bo + l*D_, tok, M_, D_, D_);
  }

  // ---- VQ ----
  k_split<<<(M_*D_+255)/256, 256, 0, stream>>>(tok, tok_hi, tok_lo, M_*D_);
  k_gemm_split<<<dim3(M_/128, KCODE/128), 256, 0, stream>>>(
      tok_hi, tok_lo, cb_hi, cb_lo, d2, nullptr, nullptr, M_, KCODE, D_);
  k_argmin<<<M_, 256, 0, stream>>>(d2, cnorm, idx);
  k_gather_nhwc<<<(B_*NTOK*D_)/256, 256, 0, stream>>>(cb, idx, y0);

  // ---- decoder stage 0: 16x16 -> 32x32, Ctot=512 ----
  k_upw<<<(512*256*4+255)/256, 256, 0, stream>>>(up_w0, Wt4, 512, 256);
  k_upconv_nhwc<<<dim3(256/64, 256/64, B_), 256, 0, stream>>>(y0, Wt4, up_b0, cc0, 512, 256, 16, 16, 512);
  k_feat2cc<<<dim3(1024/32, 256/32, B_), dim3(32,8), 0, stream>>>(feat2, cc0, 256, 256, 512, 1024);
  run_conv(cc0, cw0a, W9, va0, 512, 256, 32, 32, stream);
  run_bn(va0, xa0, bnp, bnsc, bnsh, g0a, b0a, 256, 1024, stream);
  run_conv(xa0, cw0b, W9, vb0, 256, 256, 32, 32, stream);
  run_bn(vb0, xb0, bnp, bnsc, bnsh, g0b, b0b, 256, 1024, stream);

  // ---- decoder stage 1: 32x32 -> 64x64, Ctot=256 ----
  k_upw<<<(256*128*4+255)/256, 256, 0, stream>>>(up_w1, Wt4, 256, 128);
  k_upconv_nhwc<<<dim3(1024/64, 128/64, B_), 256, 0, stream>>>(xb0, Wt4, up_b1, cc1, 256, 128, 32, 32, 256);
  k_feat2cc<<<dim3(4096/32, 128/32, B_), dim3(32,8), 0, stream>>>(feat1, cc1, 128, 128, 256, 4096);
  run_conv16(cc1, cw1a, W9, va1, 256, 128, 64, 64, stream);
  run_bn(va1, xa1, bnp, bnsc, bnsh, g1a, b1a, 128, 4096, stream);
  run_conv16(xa1, cw1b, W9, vb1, 128, 128, 64, 64, stream);
  run_bn(vb1, xb1, bnp, bnsc, bnsh, g1b, b1b, 128, 4096, stream);

  // ---- decoder stage 2: 64x64 -> 128x128, Ctot=128 ----
  k_upw<<<(128*64*4+255)/256, 256, 0, stream>>>(up_w2, Wt4, 128, 64);
  k_upconv_nhwc<<<dim3(4096/64, 64/64, B_), 256, 0, stream>>>(xb1, Wt4, up_b2, cc2, 128, 64, 64, 64, 128);
  k_feat2cc<<<dim3(16384/32, 64/32, B_), dim3(32,8), 0, stream>>>(feat0, cc2, 64, 64, 128, 16384);
  run_conv16(cc2, cw2a, W9, va2, 128, 64, 128, 128, stream);
  run_bn(va2, xa2, bnp, bnsc, bnsh, g2a, b2a, 64, 16384, stream);
  run_conv16(xa2, cw2b, W9, vb2, 64, 64, 128, 128, stream);
  run_bn(vb2, xb2, bnp, bnsc, bnsh, g2b, b2b, 64, 16384, stream);

  // ---- head ----
  k_last_nhwc<<<(B_*16384)/256, 256, 0, stream>>>(xb2, lw, lb, (float*)d_out);
}

// Round 4
// 2171.692 us; speedup vs baseline: 1.0948x; 1.0072x over previous
//
#include <hip/hip_runtime.h>

#define B_    16
#define NTOK  256
#define D_    512
#define HEADS 16
#define DH    32
#define DEPTH 12
#define KCODE 2048
#define M_    (B_*NTOK)   // 4096 token rows
#define BN_S  512         // BN partial blocks

typedef __attribute__((ext_vector_type(8))) short short8;     // 8 bf16 (4 VGPRs)
typedef __attribute__((ext_vector_type(4))) float float4v;
typedef __attribute__((ext_vector_type(16))) float float16v;  // 32x32 MFMA acc
typedef __attribute__((ext_vector_type(4))) unsigned int uint4v;
typedef __attribute__((ext_vector_type(2))) unsigned int uint2v;
typedef unsigned short ushort;

__device__ __forceinline__ ushort f2b(float f){   // fp32 -> bf16 RNE
  union { float f; unsigned u; } v; v.f = f;
  unsigned r = v.u + 0x7FFFu + ((v.u >> 16) & 1u);
  return (ushort)(r >> 16);
}
__device__ __forceinline__ float b2f(ushort h){
  union { unsigned u; float f; } v; v.u = ((unsigned)h) << 16; return v.f;
}
__device__ __forceinline__ float bits2f(unsigned u){
  union { unsigned u; float f; } v; v.u = u; return v.f;
}

// async global->LDS, 16B per lane; LDS dest = wave-uniform base + lane*16
typedef __attribute__((address_space(3))) unsigned int lds_uint;
typedef __attribute__((address_space(1))) const unsigned int glob_uint;
__device__ __forceinline__ void gl_lds16(const ushort* g, ushort* l){
  __builtin_amdgcn_global_load_lds((glob_uint*)g, (lds_uint*)l, 16, 0, 0);
}

// ---------------- prep kernels ----------------

// tiled transpose: x [b][D][NTOK] -> tok [b][NTOK][D], + pos.  32x32 LDS tile,
// coalesced on both sides. grid (NTOK/32, D/32, B), block (32,8).
__global__ void k_tok_init(const float* __restrict__ x, const float* __restrict__ pos,
                           float* __restrict__ tok){
  __shared__ float t[32][33];
  const int t0 = blockIdx.x*32, d0 = blockIdx.y*32, b = blockIdx.z;
  const int tx = threadIdx.x, ty = threadIdx.y;
  #pragma unroll
  for (int i = 0; i < 4; ++i){
    int d = d0 + ty + i*8;
    t[ty + i*8][tx] = x[((size_t)(b*D_ + d))*NTOK + t0 + tx];
  }
  __syncthreads();
  #pragma unroll
  for (int i = 0; i < 4; ++i){
    int tt = t0 + ty + i*8;
    tok[((size_t)(b*NTOK + tt))*D_ + d0 + tx] = t[tx][ty + i*8] + pos[(size_t)tt*D_ + d0 + tx];
  }
}

__global__ void k_split(const float* __restrict__ src, ushort* __restrict__ oh,
                        ushort* __restrict__ ol, int n){
  int i = blockIdx.x*256 + threadIdx.x;
  if (i >= n) return;
  float v = src[i];
  ushort h = f2b(v);
  oh[i] = h; ol[i] = f2b(v - b2f(h));
}

// split + transpose: src [L][K][N] f32 -> dst hi/lo [L][N][K] bf16.
// 32x32 LDS tile, coalesced read (along N) and write (along K).
// grid (N/32, K/32, L), block (32,8). K,N multiples of 32.
__global__ void k_split_t(const float* __restrict__ src, ushort* __restrict__ oh,
                          ushort* __restrict__ ol, int K, int N){
  __shared__ float t[32][33];
  const int n0 = blockIdx.x*32, k0 = blockIdx.y*32;
  const size_t lb = (size_t)blockIdx.z*K*N;
  const int tx = threadIdx.x, ty = threadIdx.y;
  #pragma unroll
  for (int i = 0; i < 4; ++i){
    int k = k0 + ty + i*8;
    t[ty + i*8][tx] = src[lb + (size_t)k*N + n0 + tx];
  }
  __syncthreads();
  #pragma unroll
  for (int i = 0; i < 4; ++i){
    int n = n0 + ty + i*8;
    float v = t[tx][ty + i*8];
    ushort h = f2b(v);
    size_t o = lb + (size_t)n*K + k0 + tx;
    oh[o] = h; ol[o] = f2b(v - b2f(h));
  }
}

// conv weights: [Cout][Cin][3][3] f32 -> W9 [9tap][Cout][Cin] bf16
__global__ void k_w9(const float* __restrict__ w, ushort* __restrict__ W9,
                     int Cin, int Cout){
  int i = blockIdx.x*256 + threadIdx.x;
  if (i >= Cout*Cin*9) return;
  int co = i / (Cin*9); int r = i - co*(Cin*9);
  int ci = r / 9; int tap = r - ci*9;
  W9[((size_t)tap*Cout + co)*Cin + ci] = f2b(w[i]);
}

// upconv weights: [Cin][Cout][2][2] f32 -> Wt4 [tap][Cout][Cin] bf16
__global__ void k_upw(const float* __restrict__ w, ushort* __restrict__ Wt4,
                      int Cin, int Cout){
  int i = blockIdx.x*256 + threadIdx.x;
  if (i >= Cin*Cout*4) return;
  int ci = i / (Cout*4); int r = i - ci*(Cout*4);
  int co = r >> 2; int tap = r & 3;
  Wt4[((size_t)tap*Cout + co)*Cin + ci] = f2b(w[i]);
}

// LayerNorm fused with bf16 hi/lo split. One wave per row (4 rows/block),
// 8 f32/lane, shuffle butterfly reduction — no LDS, no barriers.
// grid M_/4, block 256.
__global__ __launch_bounds__(256) void k_ln_split(
    const float* __restrict__ in, ushort* __restrict__ oh,
    ushort* __restrict__ ol, const float* __restrict__ g,
    const float* __restrict__ bta){
  const int lane = threadIdx.x & 63;
  const int row  = blockIdx.x*4 + (threadIdx.x >> 6);
  const float* xr = in + (size_t)row*D_ + lane*8;
  float4v v0 = *(const float4v*)xr;
  float4v v1 = *(const float4v*)(xr + 4);
  float s = v0.x+v0.y+v0.z+v0.w + v1.x+v1.y+v1.z+v1.w;
  float q = v0.x*v0.x+v0.y*v0.y+v0.z*v0.z+v0.w*v0.w
          + v1.x*v1.x+v1.y*v1.y+v1.z*v1.z+v1.w*v1.w;
  #pragma unroll
  for (int off = 32; off > 0; off >>= 1){
    s += __shfl_xor(s, off, 64);
    q += __shfl_xor(q, off, 64);
  }
  float mean = s * (1.f/D_);
  float var  = q * (1.f/D_) - mean*mean;
  float inv  = rsqrtf(var + 1e-5f);
  float4v g0 = *(const float4v*)(g + lane*8);
  float4v g1 = *(const float4v*)(g + lane*8 + 4);
  float4v b0 = *(const float4v*)(bta + lane*8);
  float4v b1 = *(const float4v*)(bta + lane*8 + 4);
  float xv[8] = {v0.x,v0.y,v0.z,v0.w,v1.x,v1.y,v1.z,v1.w};
  float gv[8] = {g0.x,g0.y,g0.z,g0.w,g1.x,g1.y,g1.z,g1.w};
  float bv[8] = {b0.x,b0.y,b0.z,b0.w,b1.x,b1.y,b1.z,b1.w};
  unsigned hw[4], lw[4];
  #pragma unroll
  for (int p = 0; p < 4; ++p){
    float ya = (xv[2*p]   - mean)*inv*gv[2*p]   + bv[2*p];
    float yb = (xv[2*p+1] - mean)*inv*gv[2*p+1] + bv[2*p+1];
    ushort ha = f2b(ya), hb = f2b(yb);
    hw[p] = (unsigned)ha | ((unsigned)hb << 16);
    lw[p] = (unsigned)f2b(ya - b2f(ha)) | ((unsigned)f2b(yb - b2f(hb)) << 16);
  }
  size_t o = (size_t)row*D_ + lane*8;
  *(uint4v*)(oh + o) = uint4v{hw[0], hw[1], hw[2], hw[3]};
  *(uint4v*)(ol + o) = uint4v{lw[0], lw[1], lw[2], lw[3]};
}

// ------ split-bf16 MFMA GEMM, 128x128 tile (3-term, fp32-accurate) ------
__global__ __launch_bounds__(256,2) void k_gemm_split(
    const ushort* __restrict__ Ah, const ushort* __restrict__ Al,
    const ushort* __restrict__ Bh, const ushort* __restrict__ Bl,
    float* __restrict__ C, const float* __restrict__ bias,
    const float* __restrict__ resid, int M, int N, int K){
  __shared__ ushort Ash[128][32], Asl[128][32], Bsh[128][32], Bsl[128][32];
  const int tid = threadIdx.x;
  const int m_base = blockIdx.x*128, n_base = blockIdx.y*128;
  const int lane = tid & 63, wv = tid >> 6;
  const int quad = lane >> 4, r16 = lane & 15;
  const int m_off = (wv & 1)*64, n_off = (wv >> 1)*64;
  const int lrow = lane >> 2, lseg = lane & 3;
  const int row0 = wv*32 + lrow;              // rows row0 and row0+16
  const int us   = lseg ^ ((row0 >> 1) & 3);  // (row0+16)>>1 has same &3
  const size_t offA0 = (size_t)(m_base + row0)*K + us*8;
  const size_t offA1 = offA0 + (size_t)16*K;
  const size_t offB0 = (size_t)(n_base + row0)*K + us*8;
  const size_t offB1 = offB0 + (size_t)16*K;
  ushort* lAh = &Ash[0][0] + wv*1024;   // wave-uniform LDS dest (shorts)
  ushort* lAl = &Asl[0][0] + wv*1024;
  ushort* lBh = &Bsh[0][0] + wv*1024;
  ushort* lBl = &Bsl[0][0] + wv*1024;
  float4v acc[4][4];
  #pragma unroll
  for (int i = 0; i < 4; ++i)
    #pragma unroll
    for (int j = 0; j < 4; ++j) acc[i][j] = float4v{0.f,0.f,0.f,0.f};
  for (int k0 = 0; k0 < K; k0 += 32){
    gl_lds16(Ah + offA0 + k0, lAh);
    gl_lds16(Ah + offA1 + k0, lAh + 512);
    gl_lds16(Al + offA0 + k0, lAl);
    gl_lds16(Al + offA1 + k0, lAl + 512);
    gl_lds16(Bh + offB0 + k0, lBh);
    gl_lds16(Bh + offB1 + k0, lBh + 512);
    gl_lds16(Bl + offB0 + k0, lBl);
    gl_lds16(Bl + offB1 + k0, lBl + 512);
    __syncthreads();   // drains vmcnt -> staged data visible
    short8 ah[4], al[4], bh[4], bl[4];
    #pragma unroll
    for (int i = 0; i < 4; ++i){
      int ra = m_off + i*16 + r16;
      int rb = n_off + i*16 + r16;
      int sa = (quad ^ ((ra >> 1) & 3))*8;
      int sb = (quad ^ ((rb >> 1) & 3))*8;
      ah[i] = *(const short8*)&Ash[ra][sa];
      al[i] = *(const short8*)&Asl[ra][sa];
      bh[i] = *(const short8*)&Bsh[rb][sb];
      bl[i] = *(const short8*)&Bsl[rb][sb];
    }
    #pragma unroll
    for (int i = 0; i < 4; ++i)
      #pragma unroll
      for (int j = 0; j < 4; ++j){
        acc[i][j] = __builtin_amdgcn_mfma_f32_16x16x32_bf16(bh[j], ah[i], acc[i][j], 0,0,0);
        acc[i][j] = __builtin_amdgcn_mfma_f32_16x16x32_bf16(bh[j], al[i], acc[i][j], 0,0,0);
        acc[i][j] = __builtin_amdgcn_mfma_f32_16x16x32_bf16(bl[j], ah[i], acc[i][j], 0,0,0);
      }
    __syncthreads();
  }
  #pragma unroll
  for (int i = 0; i < 4; ++i){
    int m = m_base + m_off + i*16 + r16;
    #pragma unroll
    for (int j = 0; j < 4; ++j){
      int n = n_base + n_off + j*16 + quad*4;
      float4v v = acc[i][j];
      if (bias)  v += *(const float4v*)(bias + n);
      if (resid) v += *(const float4v*)(resid + (size_t)m*N + n);
      *(float4v*)(C + (size_t)m*N + n) = v;
    }
  }
}

// ---------------- attention: one block per (b,h), K/V in LDS ----------------
__global__ __launch_bounds__(512) void k_attn2(const float* __restrict__ qkv,
                                               ushort* __restrict__ oh,
                                               ushort* __restrict__ ol){
  __shared__ float4v smem[NTOK*16];          // [0,2048)=K, [2048,4096)=V
  float4v* ks = smem;
  float4v* vs = smem + NTOK*8;
  const int h = blockIdx.x, b = blockIdx.y, t = threadIdx.x;
  const int tq = t & 255, half = t >> 8;
  const float* base = qkv + (size_t)b*NTOK*1536;
  const int koff = 512 + h*DH, voff = 1024 + h*DH;
  for (int i = t; i < NTOK*8; i += 512){
    int j = i >> 3, d4 = i & 7;
    ks[i] = *(const float4v*)(base + (size_t)j*1536 + koff + d4*4);
    vs[i] = *(const float4v*)(base + (size_t)j*1536 + voff + d4*4);
  }
  float4v q8[8];
  const float* qrow = base + (size_t)tq*1536 + h*DH;
  #pragma unroll
  for (int d4 = 0; d4 < 8; ++d4) q8[d4] = *(const float4v*)(qrow + d4*4);
  __syncthreads();
  float4v o8[8];
  #pragma unroll
  for (int d4 = 0; d4 < 8; ++d4) o8[d4] = float4v{0.f,0.f,0.f,0.f};
  float l = 0.f;
  const int j0 = half*128, j1 = j0 + 128;
  for (int j = j0; j < j1; ++j){
    float s = 0.f;
    #pragma unroll
    for (int d4 = 0; d4 < 8; ++d4){
      float4v kk = ks[j*8 + d4];
      s += q8[d4].x*kk.x + q8[d4].y*kk.y + q8[d4].z*kk.z + q8[d4].w*kk.w;
    }
    float e = __expf(s * 0.17677669529663689f);
    l += e;
    #pragma unroll
    for (int d4 = 0; d4 < 8; ++d4){
      float4v vv = vs[j*8 + d4];
      o8[d4].x += e*vv.x; o8[d4].y += e*vv.y; o8[d4].z += e*vv.z; o8[d4].w += e*vv.w;
    }
  }
  __syncthreads();                           // everyone done with K/V
  if (half){
    float4v* st = smem + (size_t)tq*9;       // stride 9 to dodge bank aliasing
    #pragma unroll
    for (int d4 = 0; d4 < 8; ++d4) st[d4] = o8[d4];
    ((float*)smem)[9216 + tq] = l;
  }
  __syncthreads();
  if (!half){
    const float4v* st = smem + (size_t)tq*9;
    #pragma unroll
    for (int d4 = 0; d4 < 8; ++d4) o8[d4] += st[d4];
    l += ((float*)smem)[9216 + tq];
    float inv = 1.f / l;
    size_t ob = (size_t)(b*NTOK + tq)*D_ + h*DH;
    #pragma unroll
    for (int d4 = 0; d4 < 8; ++d4){
      float vals[4] = {o8[d4].x*inv, o8[d4].y*inv, o8[d4].z*inv, o8[d4].w*inv};
      #pragma unroll
      for (int r = 0; r < 4; ++r){
        ushort hh = f2b(vals[r]);
        oh[ob + d4*4 + r] = hh;
        ol[ob + d4*4 + r] = f2b(vals[r] - b2f(hh));
      }
    }
  }
}

// ---------------- VQ ----------------
__global__ void k_cnorm(const float* __restrict__ cb, float* __restrict__ cnorm){
  int k = blockIdx.x, t = threadIdx.x;
  float v1 = cb[(size_t)k*D_ + t];
  float v2 = cb[(size_t)k*D_ + t + 256];
  __shared__ float r[256];
  r[t] = v1*v1 + v2*v2;
  __syncthreads();
  for (int off=128; off>0; off>>=1){
    if (t<off) r[t]+=r[t+off];
    __syncthreads();
  }
  if (t==0) cnorm[k] = r[0];
}

__global__ void k_argmin(const float* __restrict__ d2, const float* __restrict__ cnorm,
                         int* __restrict__ idx){
  int m = blockIdx.x, t = threadIdx.x;
  float best = 3.4e38f; int bk = 0;
  for (int k = t; k < KCODE; k += 256){
    float s = cnorm[k] - 2.f*d2[(size_t)m*KCODE + k];
    if (s < best){ best = s; bk = k; }
  }
  __shared__ float bs[256]; __shared__ int bi[256];
  bs[t]=best; bi[t]=bk;
  __syncthreads();
  for (int off=128; off>0; off>>=1){
    if (t<off){
      if (bs[t+off] < bs[t] || (bs[t+off]==bs[t] && bi[t+off]<bi[t])){
        bs[t]=bs[t+off]; bi[t]=bi[t+off];
      }
    }
    __syncthreads();
  }
  if (t==0) idx[m] = bi[0];
}

// y0 NHWC bf16: y0[b][t][d] = codebook[idx[b,t]][d]
__global__ void k_gather_nhwc(const float* __restrict__ cb, const int* __restrict__ idx,
                              ushort* __restrict__ y0){
  int i = blockIdx.x*256 + threadIdx.x;
  if (i >= B_*NTOK*D_) return;
  int d = i % D_; int r = i / D_; int t = r % NTOK; int b = r / NTOK;
  y0[i] = f2b(cb[(size_t)idx[b*NTOK + t]*D_ + d]);
}

// ---------------- decoder (NHWC bf16) ----------------

// 3x3 conv pad1, 16x16 pixel tile, 32x32x16 MFMA. 4 waves, each 64px x 64co
// (2x2 32-frags). 18x18 patch (324 rows) x 32ch staged; weights 9x64 rows.
// LDS rows padded to 34 shorts (68B): bank stride 17 coprime 32 -> fragment
// reads across 32 consecutive rows are bank-conflict-free.
// grid ((H/16)*(W/16), Cout/64, B_).
__global__ __launch_bounds__(256,2) void k_conv16(
    const ushort* __restrict__ X, const ushort* __restrict__ W9,
    float* __restrict__ Y, int Cin, int Cout, int H, int W){
  __shared__ ushort Xs[324][34];
  __shared__ ushort Ws[576][34];
  const int HW = H*W;
  const int tid = threadIdx.x;
  const int b = blockIdx.z;
  const int tiles_w = W >> 4;
  const int th0 = (blockIdx.x / tiles_w) * 16;
  const int tw0 = (blockIdx.x - (blockIdx.x / tiles_w)*tiles_w) * 16;
  const int n_base = blockIdx.y*64;
  const int lane = tid & 63, wv = tid >> 6;
  const int l31 = lane & 31, hi8 = (lane >> 5)*8;
  const ushort* Xb = X + (size_t)b*HW*Cin;
  // X staging: 1296 items (324 patch rows x 4 ch-segs); e=0..4 full, e=5 tid<16
  const ushort* sptr[6]; ushort* sdst[6]; bool sok[6];
  #pragma unroll
  for (int e = 0; e < 6; ++e){
    int item = tid + e*256;
    int row = item >> 2;
    int seg = item & 3;
    if (row > 323) row = 323;            // clamped; e=5 write is guarded
    int ph = row / 18, pw = row - ph*18;
    int gh = th0 + ph - 1, gw = tw0 + pw - 1;
    bool ok = gh >= 0 && gh < H && gw >= 0 && gw < W;
    int pidx = ok ? (gh*W + gw) : 0;
    sok[e] = ok;
    sptr[e] = Xb + ((size_t)pidx*Cin + seg*8);
    sdst[e] = &Xs[row][seg*8];
  }
  // W staging: 2304 items (576 rows x 4 segs), 9/thread
  const ushort* wptr[9]; ushort* wdst[9];
  #pragma unroll
  for (int e = 0; e < 9; ++e){
    int item = tid + e*256;
    int row = item >> 2;                 // 0..575
    int seg = item & 3;
    int tap = row >> 6, co = row & 63;
    wdst[e] = &Ws[row][seg*8];
    wptr[e] = W9 + ((size_t)tap*Cout + n_base + co)*Cin + seg*8;
  }
  const uint4v zz = {};
  float16v a00={}, a01={}, a10={}, a11={};   // a[nfrag][mfrag]
  const int lrow = (lane & 15) + ((lane & 16) ? 18 : 0);
  const int pr0 = wv*72 + lrow;              // patch row, tap(0,0), m-frag 0
  for (int k0 = 0; k0 < Cin; k0 += 32){
    if (k0) __syncthreads();
    #pragma unroll
    for (int e = 0; e < 6; ++e){
      if (e < 5 || tid < 16){
        uint4v v = sok[e] ? *(const uint4v*)(sptr[e] + k0) : zz;
        *(uint4v*)sdst[e] = v;
      }
    }
    #pragma unroll
    for (int e = 0; e < 9; ++e)
      *(uint4v*)wdst[e] = *(const uint4v*)(wptr[e] + k0);
    __syncthreads();
    #pragma unroll
    for (int s = 0; s < 2; ++s){
      const int kc = s*16 + hi8;
      #pragma unroll
      for (int tap = 0; tap < 9; ++tap){
        const int kh = tap/3, kw = tap - (tap/3)*3;
        const int xr = pr0 + kh*18 + kw;
        short8 x0 = *(const short8*)&Xs[xr     ][kc];
        short8 x1 = *(const short8*)&Xs[xr + 36][kc];
        short8 w0 = *(const short8*)&Ws[tap*64      + l31][kc];
        short8 w1 = *(const short8*)&Ws[tap*64 + 32 + l31][kc];
        a00 = __builtin_amdgcn_mfma_f32_32x32x16_bf16(w0, x0, a00, 0,0,0);
        a01 = __builtin_amdgcn_mfma_f32_32x32x16_bf16(w0, x1, a01, 0,0,0);
        a10 = __builtin_amdgcn_mfma_f32_32x32x16_bf16(w1, x0, a10, 0,0,0);
        a11 = __builtin_amdgcn_mfma_f32_32x32x16_bf16(w1, x1, a11, 0,0,0);
      }
    }
  }
  // epilogue: acc reg r -> co = n_base + nfrag*32 + 8*(r>>2) + 4*(lane>>5) + (r&3)
  //           pixel = tile px wv*64 + mfrag*32 + l31
  float* Yb = Y + (size_t)b*HW*Cout;
  const int co4 = (lane >> 5)*4;
  #pragma unroll
  for (int i = 0; i < 2; ++i){
    int p = wv*64 + i*32 + l31;
    int gp = (th0 + (p >> 4))*W + tw0 + (p & 15);
    float* yr = Yb + (size_t)gp*Cout + n_base + co4;
    float16v A0 = i ? a01 : a00;
    float16v A1 = i ? a11 : a10;
    #pragma unroll
    for (int q = 0; q < 4; ++q){
      float4v v0 = {A0[4*q+0], A0[4*q+1], A0[4*q+2], A0[4*q+3]};
      float4v v1 = {A1[4*q+0], A1[4*q+1], A1[4*q+2], A1[4*q+3]};
      *(float4v*)(yr + 8*q)      = v0;
      *(float4v*)(yr + 32 + 8*q) = v1;
    }
  }
}

// ConvTranspose2d k=2 s=2: X staged once per K-chunk, 4 weight taps share it.
__global__ __launch_bounds__(256) void k_upconv_nhwc(
    const ushort* __restrict__ X, const ushort* __restrict__ Wt4,
    const float* __restrict__ bias, ushort* __restrict__ CC,
    int Cin, int Cout, int Hi, int Wi, int Ctot){
  __shared__ ushort Xs[64][40], Ws[4][64][40];
  const int HWi = Hi*Wi;
  const int tid = threadIdx.x;
  const int b = blockIdx.z;
  const int m_base = blockIdx.x*64;
  const int n_base = blockIdx.y*64;
  const int lane = tid & 63, wv = tid >> 6;
  const int quad = lane >> 4, r16 = lane & 15;
  const int m_off = (wv & 1)*32, n_off = (wv >> 1)*32;
  const int srow = tid & 63, skq = tid >> 6;
  const ushort* xrow = X + ((size_t)b*HWi + m_base + srow)*Cin + skq*8;
  const ushort* w0 = Wt4 + ((size_t)0*Cout + n_base + srow)*Cin + skq*8;
  const ushort* w1 = Wt4 + ((size_t)1*Cout + n_base + srow)*Cin + skq*8;
  const ushort* w2 = Wt4 + ((size_t)2*Cout + n_base + srow)*Cin + skq*8;
  const ushort* w3 = Wt4 + ((size_t)3*Cout + n_base + srow)*Cin + skq*8;
  float4v acc[4][4];
  #pragma unroll
  for (int t = 0; t < 4; ++t)
    #pragma unroll
    for (int q = 0; q < 4; ++q) acc[t][q] = float4v{0.f,0.f,0.f,0.f};
  for (int k0 = 0; k0 < Cin; k0 += 32){
    *(uint4v*)&Xs[srow][skq*8]    = *(const uint4v*)(xrow + k0);
    *(uint4v*)&Ws[0][srow][skq*8] = *(const uint4v*)(w0 + k0);
    *(uint4v*)&Ws[1][srow][skq*8] = *(const uint4v*)(w1 + k0);
    *(uint4v*)&Ws[2][srow][skq*8] = *(const uint4v*)(w2 + k0);
    *(uint4v*)&Ws[3][srow][skq*8] = *(const uint4v*)(w3 + k0);
    __syncthreads();
    short8 xf0 = *(const short8*)&Xs[m_off      + r16][quad*8];
    short8 xf1 = *(const short8*)&Xs[m_off + 16 + r16][quad*8];
    #pragma unroll
    for (int t = 0; t < 4; ++t){
      short8 wf0 = *(const short8*)&Ws[t][n_off      + r16][quad*8];
      short8 wf1 = *(const short8*)&Ws[t][n_off + 16 + r16][quad*8];
      acc[t][0] = __builtin_amdgcn_mfma_f32_16x16x32_bf16(wf0, xf0, acc[t][0], 0,0,0);
      acc[t][1] = __builtin_amdgcn_mfma_f32_16x16x32_bf16(wf0, xf1, acc[t][1], 0,0,0);
      acc[t][2] = __builtin_amdgcn_mfma_f32_16x16x32_bf16(wf1, xf0, acc[t][2], 0,0,0);
      acc[t][3] = __builtin_amdgcn_mfma_f32_16x16x32_bf16(wf1, xf1, acc[t][3], 0,0,0);
    }
    __syncthreads();
  }
  const int Wo = 2*Wi, HWo = 4*HWi;
  int co0 = n_base + n_off + quad*4, co1 = co0 + 16;
  float4v bv0 = *(const float4v*)(bias + co0);
  float4v bv1 = *(const float4v*)(bias + co1);
  int px0 = m_base + m_off + r16, px1 = px0 + 16;
  #pragma unroll
  for (int j = 0; j < 2; ++j){
    int p = j ? px1 : px0;
    int r = p / Wi, c = p - r*Wi;
    #pragma unroll
    for (int t = 0; t < 4; ++t){
      int opix = (2*r + (t>>1))*Wo + 2*c + (t&1);
      ushort* o = CC + ((size_t)b*HWo + opix)*Ctot;
      float4v vA = acc[t][0 + j] + bv0;
      float4v vB = acc[t][2 + j] + bv1;
      uint2v pA, pB;
      pA.x = (unsigned)f2b(vA.x) | ((unsigned)f2b(vA.y) << 16);
      pA.y = (unsigned)f2b(vA.z) | ((unsigned)f2b(vA.w) << 16);
      pB.x = (unsigned)f2b(vB.x) | ((unsigned)f2b(vB.y) << 16);
      pB.y = (unsigned)f2b(vB.z) | ((unsigned)f2b(vB.w) << 16);
      *(uint2v*)(o + co0) = pA;
      *(uint2v*)(o + co1) = pB;
    }
  }
}

// NCHW fp32 skip feature -> NHWC bf16 concat channels [Coff, Coff+Cf)
__global__ void k_feat2cc(const float* __restrict__ feat, ushort* __restrict__ cc,
                          int Cf, int Coff, int Ctot, int HW){
  __shared__ ushort t[32][33];
  int pb = blockIdx.x*32, cbs = blockIdx.y*32, b = blockIdx.z;
  int tx = threadIdx.x, ty = threadIdx.y;
  #pragma unroll
  for (int i = 0; i < 4; ++i){
    int c = cbs + ty + i*8;
    t[ty + i*8][tx] = f2b(feat[((size_t)(b*Cf) + c)*HW + pb + tx]);
  }
  __syncthreads();
  #pragma unroll
  for (int i = 0; i < 4; ++i){
    int p = pb + ty + i*8;
    cc[((size_t)b*HW + p)*Ctot + Coff + cbs + tx] = t[tx][ty + i*8];
  }
}

// BN stats phase 1: BN_S blocks, float4 channel-quads, LDS cross-group reduce.
__global__ __launch_bounds__(256) void k_bnstats_nhwc(
    const float* __restrict__ x, float* __restrict__ part, int C, int HW){
  const int s = blockIdx.x, tid = threadIdx.x;
  const int R = B_*HW;
  const int chunk = R / BN_S;
  const int L = C >> 2;
  const int G = 256 / L;
  const int c4 = tid % L, g = tid / L;
  float4v a = {}, q = {};
  const float* xb = x + (size_t)(s*chunk)*C + 4*c4;
  for (int r = g; r < chunk; r += G){
    float4v v = *(const float4v*)(xb + (size_t)r*C);
    a += v; q += v*v;
  }
  __shared__ float4v h1[256], h2[256];
  h1[tid] = a; h2[tid] = q;
  __syncthreads();
  if (tid < L){
    float4v ra = h1[tid], rq = h2[tid];
    for (int gg = 1; gg < G; ++gg){ ra += h1[tid + gg*L]; rq += h2[tid + gg*L]; }
    int c0 = 4*c4;
    part[(size_t)(c0+0)*BN_S + s] = ra.x;
    part[(size_t)(c0+1)*BN_S + s] = ra.y;
    part[(size_t)(c0+2)*BN_S + s] = ra.z;
    part[(size_t)(c0+3)*BN_S + s] = ra.w;
    part[(size_t)(C+c0+0)*BN_S + s] = rq.x;
    part[(size_t)(C+c0+1)*BN_S + s] = rq.y;
    part[(size_t)(C+c0+2)*BN_S + s] = rq.z;
    part[(size_t)(C+c0+3)*BN_S + s] = rq.w;
  }
}

// BN finalize: one block per channel reduces BN_S partials -> scale/shift
__global__ void k_bnfinal(const float* __restrict__ part, const float* __restrict__ g,
                          const float* __restrict__ bb, float* __restrict__ scale,
                          float* __restrict__ shift, int C, int cnt){
  int c = blockIdx.x, t = threadIdx.x;  // 256 threads
  __shared__ float r1[256], r2[256];
  r1[t] = part[(size_t)c*BN_S + t]       + part[(size_t)c*BN_S + t + 256];
  r2[t] = part[(size_t)(C + c)*BN_S + t] + part[(size_t)(C + c)*BN_S + t + 256];
  __syncthreads();
  for (int off = 128; off > 0; off >>= 1){
    if (t < off){ r1[t] += r1[t+off]; r2[t] += r2[t+off]; }
    __syncthreads();
  }
  if (t == 0){
    float m = r1[0]/cnt;
    float v = r2[0]/cnt - m*m;
    float sc = g[c]*rsqrtf(v + 1e-5f);
    scale[c] = sc;
    shift[c] = bb[c] - m*sc;
  }
}

// BN apply + ReLU, fp32 NHWC -> bf16 NHWC
__global__ void k_bnapply_nhwc(const float* __restrict__ x, ushort* __restrict__ y,
                               const float* __restrict__ scale,
                               const float* __restrict__ shift, int C, int n4){
  int i = blockIdx.x*256 + threadIdx.x;
  if (i >= n4) return;
  float4v v = *(const float4v*)(x + (size_t)4*i);
  int c0 = (4*i) % C;
  float4v sc = *(const float4v*)(scale + c0);
  float4v sh = *(const float4v*)(shift + c0);
  float r0 = fmaxf(v.x*sc.x + sh.x, 0.f);
  float r1 = fmaxf(v.y*sc.y + sh.y, 0.f);
  float r2 = fmaxf(v.z*sc.z + sh.z, 0.f);
  float r3 = fmaxf(v.w*sc.w + sh.w, 0.f);
  uint2v pk;
  pk.x = (unsigned)f2b(r0) | ((unsigned)f2b(r1) << 16);
  pk.y = (unsigned)f2b(r2) | ((unsigned)f2b(r3) << 16);
  *(uint2v*)(y + (size_t)4*i) = pk;
}

// final 1x1 conv (64ch NHWC bf16 -> 1) + sigmoid
__global__ void k_last_nhwc(const ushort* __restrict__ x, const float* __restrict__ lw,
                            const float* __restrict__ lb, float* __restrict__ out){
  __shared__ float wsm[64];
  int tid = threadIdx.x;
  if (tid < 64) wsm[tid] = lw[tid];
  __syncthreads();
  int i = blockIdx.x*256 + tid;
  const uint4v* xr = (const uint4v*)(x + (size_t)i*64);
  float acc = lb[0];
  #pragma unroll
  for (int q = 0; q < 8; ++q){
    uint4v u = xr[q];
    unsigned uu[4] = {u.x, u.y, u.z, u.w};
    #pragma unroll
    for (int k = 0; k < 4; ++k){
      acc += bits2f(uu[k] << 16)          * wsm[q*8 + 2*k];
      acc += bits2f(uu[k] & 0xffff0000u)  * wsm[q*8 + 2*k + 1];
    }
  }
  out[i] = 1.f/(1.f + __expf(-acc));
}

// ---------------- host ----------------
#define MBx 1048576ull

static inline void run_conv16(const ushort* in, const float* w, ushort* W9,
                              float* out, int Cin, int Cout, int H, int W,
                              hipStream_t stream){
  int total = Cout*Cin*9;
  k_w9<<<(total+255)/256, 256, 0, stream>>>(w, W9, Cin, Cout);
  k_conv16<<<dim3((H>>4)*(W>>4), Cout/64, B_), 256, 0, stream>>>(in, W9, out, Cin, Cout, H, W);
}

static inline void run_bn(const float* x, ushort* y, float* part, float* scale, float* shift,
                          const float* g, const float* bb, int C, int HW, hipStream_t stream){
  k_bnstats_nhwc<<<BN_S, 256, 0, stream>>>(x, part, C, HW);
  k_bnfinal<<<C, 256, 0, stream>>>(part, g, bb, scale, shift, C, B_*HW);
  int n4 = B_*HW*C/4;
  k_bnapply_nhwc<<<(n4+255)/256, 256, 0, stream>>>(x, y, scale, shift, C, n4);
}

extern "C" void kernel_launch(void* const* d_in, const int* in_sizes, int n_in,
                              void* d_out, int out_size, void* d_ws, size_t ws_size,
                              hipStream_t stream){
  const float* x     = (const float*)d_in[0];
  const float* feat0 = (const float*)d_in[1];
  const float* feat1 = (const float*)d_in[2];
  const float* feat2 = (const float*)d_in[3];
  const float* pos   = (const float*)d_in[4];
  const float* cb    = (const float*)d_in[5];
  const float* ln_g  = (const float*)d_in[6];
  const float* ln_b  = (const float*)d_in[7];
  const float* wqkv  = (const float*)d_in[8];
  const float* wo    = (const float*)d_in[9];
  const float* bo    = (const float*)d_in[10];
  const float* up_w0 = (const float*)d_in[11];
  const float* up_b0 = (const float*)d_in[12];
  const float* cw0a  = (const float*)d_in[13];
  const float* g0a   = (const float*)d_in[14];
  const float* b0a   = (const float*)d_in[15];
  const float* cw0b  = (const float*)d_in[16];
  const float* g0b   = (const float*)d_in[17];
  const float* b0b   = (const float*)d_in[18];
  const float* up_w1 = (const float*)d_in[19];
  const float* up_b1 = (const float*)d_in[20];
  const float* cw1a  = (const float*)d_in[21];
  const float* g1a   = (const float*)d_in[22];
  const float* b1a   = (const float*)d_in[23];
  const float* cw1b  = (const float*)d_in[24];
  const float* g1b   = (const float*)d_in[25];
  const float* b1b   = (const float*)d_in[26];
  const float* up_w2 = (const float*)d_in[27];
  const float* up_b2 = (const float*)d_in[28];
  const float* cw2a  = (const float*)d_in[29];
  const float* g2a   = (const float*)d_in[30];
  const float* b2a   = (const float*)d_in[31];
  const float* cw2b  = (const float*)d_in[32];
  const float* g2b   = (const float*)d_in[33];
  const float* b2b   = (const float*)d_in[34];
  const float* lw    = (const float*)d_in[35];
  const float* lb    = (const float*)d_in[36];

  char* ws = (char*)d_ws;
  // encoder/VQ scratch (region 0..134MB)
  float*  tok     = (float*) (ws);
  ushort* xn_hi   = (ushort*)(ws +  8388608ull);
  ushort* xn_lo   = (ushort*)(ws + 12582912ull);
  float*  qkv     = (float*) (ws + 16777216ull);
  ushort* at_hi   = (ushort*)(ws + 41943040ull);
  ushort* at_lo   = (ushort*)(ws + 46137344ull);
  ushort* tok_hi  = (ushort*)(ws + 50331648ull);
  ushort* tok_lo  = (ushort*)(ws + 54525952ull);
  ushort* Wq_hi   = (ushort*)(ws + 58720256ull);
  ushort* Wq_lo   = (ushort*)(ws + 77594624ull);
  ushort* Wo_hi   = (ushort*)(ws + 96468992ull);
  ushort* Wo_lo   = (ushort*)(ws + 102760448ull);
  ushort* cb_hi   = (ushort*)(ws + 109051904ull);
  ushort* cb_lo   = (ushort*)(ws + 111149056ull);
  float*  cnorm   = (float*) (ws + 113246208ull);
  int*    idx     = (int*)   (ws + 113254400ull);
  float*  d2      = (float*) (ws + 58720256ull);   // overlaps Wq (dead at VQ time)
  // tail: weights + bn scratch + y0
  ushort* W9   = (ushort*)(ws + 134*MBx);          // 2.25 MB max
  float* bnsc  = (float*) (ws + 136*MBx + 524288); // 1 KB
  float* bnsh  = (float*) (ws + 136*MBx + 528384); // 1 KB
  ushort* Wt4  = (ushort*)(ws + 137*MBx);          // 1 MB max
  float* bnp   = (float*) (ws + 138*MBx);          // 1 MB max
  ushort* y0   = (ushort*)(ws + 139*MBx);
  // decoder ping-pong
  ushort* cc0 = (ushort*)(ws + 146*MBx);
  float*  va0 = (float*) (ws + 163*MBx);
  ushort* xa0 = (ushort*)(ws + 180*MBx);
  float*  vb0 = (float*) (ws + 146*MBx);
  ushort* xb0 = (ushort*)(ws + 189*MBx);
  ushort* cc1 = (ushort*)(ws + 0*MBx);
  float*  va1 = (float*) (ws + 34*MBx);
  ushort* xa1 = (ushort*)(ws + 68*MBx);
  float*  vb1 = (float*) (ws + 85*MBx);
  ushort* xb1 = (ushort*)(ws + 146*MBx);
  ushort* cc2 = (ushort*)(ws + 0*MBx);
  float*  va2 = (float*) (ws + 67*MBx);
  ushort* xa2 = (ushort*)(ws + 146*MBx);
  float*  vb2 = (float*) (ws + 0*MBx);
  ushort* xb2 = (ushort*)(ws + 67*MBx);

  // ---- weight prep ----
  k_split_t<<<dim3(1536/32, D_/32, DEPTH), dim3(32,8), 0, stream>>>(wqkv, Wq_hi, Wq_lo, D_, 1536);
  k_split_t<<<dim3(D_/32, D_/32, DEPTH), dim3(32,8), 0, stream>>>(wo, Wo_hi, Wo_lo, D_, D_);
  k_split<<<(KCODE*D_+255)/256, 256, 0, stream>>>(cb, cb_hi, cb_lo, KCODE*D_);
  k_cnorm<<<KCODE, 256, 0, stream>>>(cb, cnorm);

  // ---- encoder ----
  k_tok_init<<<dim3(NTOK/32, D_/32, B_), dim3(32,8), 0, stream>>>(x, pos, tok);
  for (int l = 0; l < DEPTH; ++l){
    k_ln_split<<<M_/4, 256, 0, stream>>>(tok, xn_hi, xn_lo, ln_g + l*D_, ln_b + l*D_);
    k_gemm_split<<<dim3(M_/128, 1536/128), 256, 0, stream>>>(
        xn_hi, xn_lo, Wq_hi + (size_t)l*1536*D_, Wq_lo + (size_t)l*1536*D_,
        qkv, nullptr, nullptr, M_, 1536, D_);
    k_attn2<<<dim3(HEADS, B_), 512, 0, stream>>>(qkv, at_hi, at_lo);
    k_gemm_split<<<dim3(M_/128, D_/128), 256, 0, stream>>>(
        at_hi, at_lo, Wo_hi + (size_t)l*D_*D_, Wo_lo + (size_t)l*D_*D_,
        tok, bo + l*D_, tok, M_, D_, D_);
  }

  // ---- VQ ----
  k_split<<<(M_*D_+255)/256, 256, 0, stream>>>(tok, tok_hi, tok_lo, M_*D_);
  k_gemm_split<<<dim3(M_/128, KCODE/128), 256, 0, stream>>>(
      tok_hi, tok_lo, cb_hi, cb_lo, d2, nullptr, nullptr, M_, KCODE, D_);
  k_argmin<<<M_, 256, 0, stream>>>(d2, cnorm, idx);
  k_gather_nhwc<<<(B_*NTOK*D_)/256, 256, 0, stream>>>(cb, idx, y0);

  // ---- decoder stage 0: 16x16 -> 32x32, Ctot=512 ----
  k_upw<<<(512*256*4+255)/256, 256, 0, stream>>>(up_w0, Wt4, 512, 256);
  k_upconv_nhwc<<<dim3(256/64, 256/64, B_), 256, 0, stream>>>(y0, Wt4, up_b0, cc0, 512, 256, 16, 16, 512);
  k_feat2cc<<<dim3(1024/32, 256/32, B_), dim3(32,8), 0, stream>>>(feat2, cc0, 256, 256, 512, 1024);
  run_conv16(cc0, cw0a, W9, va0, 512, 256, 32, 32, stream);
  run_bn(va0, xa0, bnp, bnsc, bnsh, g0a, b0a, 256, 1024, stream);
  run_conv16(xa0, cw0b, W9, vb0, 256, 256, 32, 32, stream);
  run_bn(vb0, xb0, bnp, bnsc, bnsh, g0b, b0b, 256, 1024, stream);

  // ---- decoder stage 1: 32x32 -> 64x64, Ctot=256 ----
  k_upw<<<(256*128*4+255)/256, 256, 0, stream>>>(up_w1, Wt4, 256, 128);
  k_upconv_nhwc<<<dim3(1024/64, 128/64, B_), 256, 0, stream>>>(xb0, Wt4, up_b1, cc1, 256, 128, 32, 32, 256);
  k_feat2cc<<<dim3(4096/32, 128/32, B_), dim3(32,8), 0, stream>>>(feat1, cc1, 128, 128, 256, 4096);
  run_conv16(cc1, cw1a, W9, va1, 256, 128, 64, 64, stream);
  run_bn(va1, xa1, bnp, bnsc, bnsh, g1a, b1a, 128, 4096, stream);
  run_conv16(xa1, cw1b, W9, vb1, 128, 128, 64, 64, stream);
  run_bn(vb1, xb1, bnp, bnsc, bnsh, g1b, b1b, 128, 4096, stream);

  // ---- decoder stage 2: 64x64 -> 128x128, Ctot=128 ----
  k_upw<<<(128*64*4+255)/256, 256, 0, stream>>>(up_w2, Wt4, 128, 64);
  k_upconv_nhwc<<<dim3(4096/64, 64/64, B_), 256, 0, stream>>>(xb1, Wt4, up_b2, cc2, 128, 64, 64, 64, 128);
  k_feat2cc<<<dim3(16384/32, 64/32, B_), dim3(32,8), 0, stream>>>(feat0, cc2, 64, 64, 128, 16384);
  run_conv16(cc2, cw2a, W9, va2, 128, 64, 128, 128, stream);
  run_bn(va2, xa2, bnp, bnsc, bnsh, g2a, b2a, 64, 16384, stream);
  run_conv16(xa2, cw2b, W9, vb2, 64, 64, 128, 128, stream);
  run_bn(vb2, xb2, bnp, bnsc, bnsh, g2b, b2b, 64, 16384, stream);

  // ---- head ----
  k_last_nhwc<<<(B_*16384)/256, 256, 0, stream>>>(xb2, lw, lb, (float*)d_out);
}

// Round 5
// 2149.484 us; speedup vs baseline: 1.1061x; 1.0103x over previous
//
#include <hip/hip_runtime.h>

#define B_    16
#define NTOK  256
#define D_    512
#define HEADS 16
#define DH    32
#define DEPTH 12
#define KCODE 2048
#define M_    (B_*NTOK)   // 4096 token rows
#define BN_S  512         // BN partial blocks

typedef __attribute__((ext_vector_type(8))) short short8;     // 8 bf16 (4 VGPRs)
typedef __attribute__((ext_vector_type(4))) float float4v;
typedef __attribute__((ext_vector_type(16))) float float16v;  // 32x32 MFMA acc
typedef __attribute__((ext_vector_type(4))) unsigned int uint4v;
typedef __attribute__((ext_vector_type(2))) unsigned int uint2v;
typedef unsigned short ushort;

__device__ __forceinline__ ushort f2b(float f){   // fp32 -> bf16 RNE
  union { float f; unsigned u; } v; v.f = f;
  unsigned r = v.u + 0x7FFFu + ((v.u >> 16) & 1u);
  return (ushort)(r >> 16);
}
__device__ __forceinline__ float b2f(ushort h){
  union { unsigned u; float f; } v; v.u = ((unsigned)h) << 16; return v.f;
}
__device__ __forceinline__ float bits2f(unsigned u){
  union { unsigned u; float f; } v; v.u = u; return v.f;
}

// async global->LDS, 16B per lane; LDS dest = wave-uniform base + lane*16
typedef __attribute__((address_space(3))) unsigned int lds_uint;
typedef __attribute__((address_space(1))) const unsigned int glob_uint;
__device__ __forceinline__ void gl_lds16(const ushort* g, ushort* l){
  __builtin_amdgcn_global_load_lds((glob_uint*)g, (lds_uint*)l, 16, 0, 0);
}

// ---------------- prep kernels ----------------

// tiled transpose: x [b][D][NTOK] -> tok [b][NTOK][D], + pos.
__global__ void k_tok_init(const float* __restrict__ x, const float* __restrict__ pos,
                           float* __restrict__ tok){
  __shared__ float t[32][33];
  const int t0 = blockIdx.x*32, d0 = blockIdx.y*32, b = blockIdx.z;
  const int tx = threadIdx.x, ty = threadIdx.y;
  #pragma unroll
  for (int i = 0; i < 4; ++i){
    int d = d0 + ty + i*8;
    t[ty + i*8][tx] = x[((size_t)(b*D_ + d))*NTOK + t0 + tx];
  }
  __syncthreads();
  #pragma unroll
  for (int i = 0; i < 4; ++i){
    int tt = t0 + ty + i*8;
    tok[((size_t)(b*NTOK + tt))*D_ + d0 + tx] = t[tx][ty + i*8] + pos[(size_t)tt*D_ + d0 + tx];
  }
}

__global__ void k_split(const float* __restrict__ src, ushort* __restrict__ oh,
                        ushort* __restrict__ ol, int n){
  int i = blockIdx.x*256 + threadIdx.x;
  if (i >= n) return;
  float v = src[i];
  ushort h = f2b(v);
  oh[i] = h; ol[i] = f2b(v - b2f(h));
}

// split + transpose: src [L][K][N] f32 -> dst hi/lo [L][N][K] bf16.
__global__ void k_split_t(const float* __restrict__ src, ushort* __restrict__ oh,
                          ushort* __restrict__ ol, int K, int N){
  __shared__ float t[32][33];
  const int n0 = blockIdx.x*32, k0 = blockIdx.y*32;
  const size_t lb = (size_t)blockIdx.z*K*N;
  const int tx = threadIdx.x, ty = threadIdx.y;
  #pragma unroll
  for (int i = 0; i < 4; ++i){
    int k = k0 + ty + i*8;
    t[ty + i*8][tx] = src[lb + (size_t)k*N + n0 + tx];
  }
  __syncthreads();
  #pragma unroll
  for (int i = 0; i < 4; ++i){
    int n = n0 + ty + i*8;
    float v = t[tx][ty + i*8];
    ushort h = f2b(v);
    size_t o = lb + (size_t)n*K + k0 + tx;
    oh[o] = h; ol[o] = f2b(v - b2f(h));
  }
}

// conv weights: [Cout][Cin][3][3] f32 -> W9 [9tap][Cout][Cin] bf16.
// thread owns (co,ci): 36B contiguous read, 9 coalesced write streams.
__global__ void k_w9(const float* __restrict__ w, ushort* __restrict__ W9,
                     int Cin, int Cout){
  int i = blockIdx.x*256 + threadIdx.x;    // i = co*Cin + ci
  if (i >= Cout*Cin) return;
  const float* src = w + (size_t)i*9;
  float v[9];
  #pragma unroll
  for (int t = 0; t < 9; ++t) v[t] = src[t];
  const size_t CC = (size_t)Cout*Cin;
  #pragma unroll
  for (int t = 0; t < 9; ++t) W9[t*CC + i] = f2b(v[t]);
}

// upconv weights: [Cin][Cout][2][2] f32 -> Wt4 [tap][Cout][Cin] bf16.
// 32x32 LDS tile transpose. grid (Cout/32, Cin/32), block (32,8).
__global__ void k_upw(const float* __restrict__ w, ushort* __restrict__ Wt4,
                      int Cin, int Cout){
  __shared__ ushort t4[4][32][33];
  const int co0 = blockIdx.x*32, ci0 = blockIdx.y*32;
  const int tx = threadIdx.x, ty = threadIdx.y;
  #pragma unroll
  for (int i = 0; i < 4; ++i){
    int ci = ty + i*8;
    float4v v = *(const float4v*)(w + ((size_t)(ci0+ci)*Cout + co0+tx)*4);
    t4[0][tx][ci] = f2b(v.x); t4[1][tx][ci] = f2b(v.y);
    t4[2][tx][ci] = f2b(v.z); t4[3][tx][ci] = f2b(v.w);
  }
  __syncthreads();
  #pragma unroll
  for (int i = 0; i < 4; ++i){
    int co = ty + i*8;
    #pragma unroll
    for (int tap = 0; tap < 4; ++tap)
      Wt4[((size_t)tap*Cout + co0+co)*Cin + ci0 + tx] = t4[tap][co][tx];
  }
}

// LayerNorm fused with bf16 hi/lo split. One wave per row, shuffle reduce.
__global__ __launch_bounds__(256) void k_ln_split(
    const float* __restrict__ in, ushort* __restrict__ oh,
    ushort* __restrict__ ol, const float* __restrict__ g,
    const float* __restrict__ bta){
  const int lane = threadIdx.x & 63;
  const int row  = blockIdx.x*4 + (threadIdx.x >> 6);
  const float* xr = in + (size_t)row*D_ + lane*8;
  float4v v0 = *(const float4v*)xr;
  float4v v1 = *(const float4v*)(xr + 4);
  float s = v0.x+v0.y+v0.z+v0.w + v1.x+v1.y+v1.z+v1.w;
  float q = v0.x*v0.x+v0.y*v0.y+v0.z*v0.z+v0.w*v0.w
          + v1.x*v1.x+v1.y*v1.y+v1.z*v1.z+v1.w*v1.w;
  #pragma unroll
  for (int off = 32; off > 0; off >>= 1){
    s += __shfl_xor(s, off, 64);
    q += __shfl_xor(q, off, 64);
  }
  float mean = s * (1.f/D_);
  float var  = q * (1.f/D_) - mean*mean;
  float inv  = rsqrtf(var + 1e-5f);
  float4v g0 = *(const float4v*)(g + lane*8);
  float4v g1 = *(const float4v*)(g + lane*8 + 4);
  float4v b0 = *(const float4v*)(bta + lane*8);
  float4v b1 = *(const float4v*)(bta + lane*8 + 4);
  float xv[8] = {v0.x,v0.y,v0.z,v0.w,v1.x,v1.y,v1.z,v1.w};
  float gv[8] = {g0.x,g0.y,g0.z,g0.w,g1.x,g1.y,g1.z,g1.w};
  float bv[8] = {b0.x,b0.y,b0.z,b0.w,b1.x,b1.y,b1.z,b1.w};
  unsigned hw[4], lw[4];
  #pragma unroll
  for (int p = 0; p < 4; ++p){
    float ya = (xv[2*p]   - mean)*inv*gv[2*p]   + bv[2*p];
    float yb = (xv[2*p+1] - mean)*inv*gv[2*p+1] + bv[2*p+1];
    ushort ha = f2b(ya), hb = f2b(yb);
    hw[p] = (unsigned)ha | ((unsigned)hb << 16);
    lw[p] = (unsigned)f2b(ya - b2f(ha)) | ((unsigned)f2b(yb - b2f(hb)) << 16);
  }
  size_t o = (size_t)row*D_ + lane*8;
  *(uint4v*)(oh + o) = uint4v{hw[0], hw[1], hw[2], hw[3]};
  *(uint4v*)(ol + o) = uint4v{lw[0], lw[1], lw[2], lw[3]};
}

// ------ split-bf16 MFMA GEMM, 128x128 tile (3-term, fp32-accurate) ------
__global__ __launch_bounds__(256,2) void k_gemm_split(
    const ushort* __restrict__ Ah, const ushort* __restrict__ Al,
    const ushort* __restrict__ Bh, const ushort* __restrict__ Bl,
    float* __restrict__ C, const float* __restrict__ bias,
    const float* __restrict__ resid, int M, int N, int K){
  __shared__ ushort Ash[128][32], Asl[128][32], Bsh[128][32], Bsl[128][32];
  const int tid = threadIdx.x;
  const int m_base = blockIdx.x*128, n_base = blockIdx.y*128;
  const int lane = tid & 63, wv = tid >> 6;
  const int quad = lane >> 4, r16 = lane & 15;
  const int m_off = (wv & 1)*64, n_off = (wv >> 1)*64;
  const int lrow = lane >> 2, lseg = lane & 3;
  const int row0 = wv*32 + lrow;
  const int us   = lseg ^ ((row0 >> 1) & 3);
  const size_t offA0 = (size_t)(m_base + row0)*K + us*8;
  const size_t offA1 = offA0 + (size_t)16*K;
  const size_t offB0 = (size_t)(n_base + row0)*K + us*8;
  const size_t offB1 = offB0 + (size_t)16*K;
  ushort* lAh = &Ash[0][0] + wv*1024;
  ushort* lAl = &Asl[0][0] + wv*1024;
  ushort* lBh = &Bsh[0][0] + wv*1024;
  ushort* lBl = &Bsl[0][0] + wv*1024;
  float4v acc[4][4];
  #pragma unroll
  for (int i = 0; i < 4; ++i)
    #pragma unroll
    for (int j = 0; j < 4; ++j) acc[i][j] = float4v{0.f,0.f,0.f,0.f};
  for (int k0 = 0; k0 < K; k0 += 32){
    gl_lds16(Ah + offA0 + k0, lAh);
    gl_lds16(Ah + offA1 + k0, lAh + 512);
    gl_lds16(Al + offA0 + k0, lAl);
    gl_lds16(Al + offA1 + k0, lAl + 512);
    gl_lds16(Bh + offB0 + k0, lBh);
    gl_lds16(Bh + offB1 + k0, lBh + 512);
    gl_lds16(Bl + offB0 + k0, lBl);
    gl_lds16(Bl + offB1 + k0, lBl + 512);
    __syncthreads();
    short8 ah[4], al[4], bh[4], bl[4];
    #pragma unroll
    for (int i = 0; i < 4; ++i){
      int ra = m_off + i*16 + r16;
      int rb = n_off + i*16 + r16;
      int sa = (quad ^ ((ra >> 1) & 3))*8;
      int sb = (quad ^ ((rb >> 1) & 3))*8;
      ah[i] = *(const short8*)&Ash[ra][sa];
      al[i] = *(const short8*)&Asl[ra][sa];
      bh[i] = *(const short8*)&Bsh[rb][sb];
      bl[i] = *(const short8*)&Bsl[rb][sb];
    }
    #pragma unroll
    for (int i = 0; i < 4; ++i)
      #pragma unroll
      for (int j = 0; j < 4; ++j){
        acc[i][j] = __builtin_amdgcn_mfma_f32_16x16x32_bf16(bh[j], ah[i], acc[i][j], 0,0,0);
        acc[i][j] = __builtin_amdgcn_mfma_f32_16x16x32_bf16(bh[j], al[i], acc[i][j], 0,0,0);
        acc[i][j] = __builtin_amdgcn_mfma_f32_16x16x32_bf16(bl[j], ah[i], acc[i][j], 0,0,0);
      }
    __syncthreads();
  }
  #pragma unroll
  for (int i = 0; i < 4; ++i){
    int m = m_base + m_off + i*16 + r16;
    #pragma unroll
    for (int j = 0; j < 4; ++j){
      int n = n_base + n_off + j*16 + quad*4;
      float4v v = acc[i][j];
      if (bias)  v += *(const float4v*)(bias + n);
      if (resid) v += *(const float4v*)(resid + (size_t)m*N + n);
      *(float4v*)(C + (size_t)m*N + n) = v;
    }
  }
}

// ---------------- attention: one block per (b,h), K/V in LDS ----------------
__global__ __launch_bounds__(512) void k_attn2(const float* __restrict__ qkv,
                                               ushort* __restrict__ oh,
                                               ushort* __restrict__ ol){
  __shared__ float4v smem[NTOK*16];
  float4v* ks = smem;
  float4v* vs = smem + NTOK*8;
  const int h = blockIdx.x, b = blockIdx.y, t = threadIdx.x;
  const int tq = t & 255, half = t >> 8;
  const float* base = qkv + (size_t)b*NTOK*1536;
  const int koff = 512 + h*DH, voff = 1024 + h*DH;
  for (int i = t; i < NTOK*8; i += 512){
    int j = i >> 3, d4 = i & 7;
    ks[i] = *(const float4v*)(base + (size_t)j*1536 + koff + d4*4);
    vs[i] = *(const float4v*)(base + (size_t)j*1536 + voff + d4*4);
  }
  float4v q8[8];
  const float* qrow = base + (size_t)tq*1536 + h*DH;
  #pragma unroll
  for (int d4 = 0; d4 < 8; ++d4) q8[d4] = *(const float4v*)(qrow + d4*4);
  __syncthreads();
  float4v o8[8];
  #pragma unroll
  for (int d4 = 0; d4 < 8; ++d4) o8[d4] = float4v{0.f,0.f,0.f,0.f};
  float l = 0.f;
  const int j0 = half*128, j1 = j0 + 128;
  for (int j = j0; j < j1; ++j){
    float s = 0.f;
    #pragma unroll
    for (int d4 = 0; d4 < 8; ++d4){
      float4v kk = ks[j*8 + d4];
      s += q8[d4].x*kk.x + q8[d4].y*kk.y + q8[d4].z*kk.z + q8[d4].w*kk.w;
    }
    float e = __expf(s * 0.17677669529663689f);
    l += e;
    #pragma unroll
    for (int d4 = 0; d4 < 8; ++d4){
      float4v vv = vs[j*8 + d4];
      o8[d4].x += e*vv.x; o8[d4].y += e*vv.y; o8[d4].z += e*vv.z; o8[d4].w += e*vv.w;
    }
  }
  __syncthreads();
  if (half){
    float4v* st = smem + (size_t)tq*9;
    #pragma unroll
    for (int d4 = 0; d4 < 8; ++d4) st[d4] = o8[d4];
    ((float*)smem)[9216 + tq] = l;
  }
  __syncthreads();
  if (!half){
    const float4v* st = smem + (size_t)tq*9;
    #pragma unroll
    for (int d4 = 0; d4 < 8; ++d4) o8[d4] += st[d4];
    l += ((float*)smem)[9216 + tq];
    float inv = 1.f / l;
    size_t ob = (size_t)(b*NTOK + tq)*D_ + h*DH;
    #pragma unroll
    for (int d4 = 0; d4 < 8; ++d4){
      float vals[4] = {o8[d4].x*inv, o8[d4].y*inv, o8[d4].z*inv, o8[d4].w*inv};
      #pragma unroll
      for (int r = 0; r < 4; ++r){
        ushort hh = f2b(vals[r]);
        oh[ob + d4*4 + r] = hh;
        ol[ob + d4*4 + r] = f2b(vals[r] - b2f(hh));
      }
    }
  }
}

// ---------------- VQ ----------------
__global__ void k_cnorm(const float* __restrict__ cb, float* __restrict__ cnorm){
  int k = blockIdx.x, t = threadIdx.x;
  float v1 = cb[(size_t)k*D_ + t];
  float v2 = cb[(size_t)k*D_ + t + 256];
  __shared__ float r[256];
  r[t] = v1*v1 + v2*v2;
  __syncthreads();
  for (int off=128; off>0; off>>=1){
    if (t<off) r[t]+=r[t+off];
    __syncthreads();
  }
  if (t==0) cnorm[k] = r[0];
}

__global__ void k_argmin(const float* __restrict__ d2, const float* __restrict__ cnorm,
                         int* __restrict__ idx){
  int m = blockIdx.x, t = threadIdx.x;
  float best = 3.4e38f; int bk = 0;
  for (int k = t; k < KCODE; k += 256){
    float s = cnorm[k] - 2.f*d2[(size_t)m*KCODE + k];
    if (s < best){ best = s; bk = k; }
  }
  __shared__ float bs[256]; __shared__ int bi[256];
  bs[t]=best; bi[t]=bk;
  __syncthreads();
  for (int off=128; off>0; off>>=1){
    if (t<off){
      if (bs[t+off] < bs[t] || (bs[t+off]==bs[t] && bi[t+off]<bi[t])){
        bs[t]=bs[t+off]; bi[t]=bi[t+off];
      }
    }
    __syncthreads();
  }
  if (t==0) idx[m] = bi[0];
}

__global__ void k_gather_nhwc(const float* __restrict__ cb, const int* __restrict__ idx,
                              ushort* __restrict__ y0){
  int i = blockIdx.x*256 + threadIdx.x;
  if (i >= B_*NTOK*D_) return;
  int d = i % D_; int r = i / D_; int t = r % NTOK; int b = r / NTOK;
  y0[i] = f2b(cb[(size_t)idx[b*NTOK + t]*D_ + d]);
}

// ---------------- decoder (NHWC bf16) ----------------

// 3x3 conv pad1, 16x16 tile, 32x32x16 MFMA, optional split-K.
// grid ((H/16)*(W/16), Cout/64, B_*ksplit); split p writes Y + p*B_*HW*Cout.
__global__ __launch_bounds__(256,2) void k_conv16(
    const ushort* __restrict__ X, const ushort* __restrict__ W9,
    float* __restrict__ Y, int Cin, int Cout, int H, int W, int ksplit){
  __shared__ ushort Xs[324][34];
  __shared__ ushort Ws[576][34];
  const int HW = H*W;
  const int tid = threadIdx.x;
  const int b = blockIdx.z % B_;
  const int split = blockIdx.z / B_;
  const int CinS = Cin / ksplit;
  const int kbeg = split*CinS, kend = kbeg + CinS;
  const int tiles_w = W >> 4;
  const int th0 = (blockIdx.x / tiles_w) * 16;
  const int tw0 = (blockIdx.x - (blockIdx.x / tiles_w)*tiles_w) * 16;
  const int n_base = blockIdx.y*64;
  const int lane = tid & 63, wv = tid >> 6;
  const int l31 = lane & 31, hi8 = (lane >> 5)*8;
  const ushort* Xb = X + (size_t)b*HW*Cin;
  const ushort* sptr[6]; ushort* sdst[6]; bool sok[6];
  #pragma unroll
  for (int e = 0; e < 6; ++e){
    int item = tid + e*256;
    int row = item >> 2;
    int seg = item & 3;
    if (row > 323) row = 323;
    int ph = row / 18, pw = row - ph*18;
    int gh = th0 + ph - 1, gw = tw0 + pw - 1;
    bool ok = gh >= 0 && gh < H && gw >= 0 && gw < W;
    int pidx = ok ? (gh*W + gw) : 0;
    sok[e] = ok;
    sptr[e] = Xb + ((size_t)pidx*Cin + seg*8);
    sdst[e] = &Xs[row][seg*8];
  }
  const ushort* wptr[9]; ushort* wdst[9];
  #pragma unroll
  for (int e = 0; e < 9; ++e){
    int item = tid + e*256;
    int row = item >> 2;
    int seg = item & 3;
    int tap = row >> 6, co = row & 63;
    wdst[e] = &Ws[row][seg*8];
    wptr[e] = W9 + ((size_t)tap*Cout + n_base + co)*Cin + seg*8;
  }
  const uint4v zz = {};
  float16v a00={}, a01={}, a10={}, a11={};
  const int lrow = (lane & 15) + ((lane & 16) ? 18 : 0);
  const int pr0 = wv*72 + lrow;
  for (int k0 = kbeg; k0 < kend; k0 += 32){
    if (k0 != kbeg) __syncthreads();
    #pragma unroll
    for (int e = 0; e < 6; ++e){
      if (e < 5 || tid < 16){
        uint4v v = sok[e] ? *(const uint4v*)(sptr[e] + k0) : zz;
        *(uint4v*)sdst[e] = v;
      }
    }
    #pragma unroll
    for (int e = 0; e < 9; ++e)
      *(uint4v*)wdst[e] = *(const uint4v*)(wptr[e] + k0);
    __syncthreads();
    #pragma unroll
    for (int s = 0; s < 2; ++s){
      const int kc = s*16 + hi8;
      #pragma unroll
      for (int tap = 0; tap < 9; ++tap){
        const int kh = tap/3, kw = tap - (tap/3)*3;
        const int xr = pr0 + kh*18 + kw;
        short8 x0 = *(const short8*)&Xs[xr     ][kc];
        short8 x1 = *(const short8*)&Xs[xr + 36][kc];
        short8 w0 = *(const short8*)&Ws[tap*64      + l31][kc];
        short8 w1 = *(const short8*)&Ws[tap*64 + 32 + l31][kc];
        a00 = __builtin_amdgcn_mfma_f32_32x32x16_bf16(w0, x0, a00, 0,0,0);
        a01 = __builtin_amdgcn_mfma_f32_32x32x16_bf16(w0, x1, a01, 0,0,0);
        a10 = __builtin_amdgcn_mfma_f32_32x32x16_bf16(w1, x0, a10, 0,0,0);
        a11 = __builtin_amdgcn_mfma_f32_32x32x16_bf16(w1, x1, a11, 0,0,0);
      }
    }
  }
  float* Yb = Y + ((size_t)split*B_ + b)*HW*Cout;
  const int co4 = (lane >> 5)*4;
  #pragma unroll
  for (int i = 0; i < 2; ++i){
    int p = wv*64 + i*32 + l31;
    int gp = (th0 + (p >> 4))*W + tw0 + (p & 15);
    float* yr = Yb + (size_t)gp*Cout + n_base + co4;
    float16v A0 = i ? a01 : a00;
    float16v A1 = i ? a11 : a10;
    #pragma unroll
    for (int q = 0; q < 4; ++q){
      float4v v0 = {A0[4*q+0], A0[4*q+1], A0[4*q+2], A0[4*q+3]};
      float4v v1 = {A1[4*q+0], A1[4*q+1], A1[4*q+2], A1[4*q+3]};
      *(float4v*)(yr + 8*q)      = v0;
      *(float4v*)(yr + 32 + 8*q) = v1;
    }
  }
}

// ConvTranspose2d k=2 s=2
__global__ __launch_bounds__(256) void k_upconv_nhwc(
    const ushort* __restrict__ X, const ushort* __restrict__ Wt4,
    const float* __restrict__ bias, ushort* __restrict__ CC,
    int Cin, int Cout, int Hi, int Wi, int Ctot){
  __shared__ ushort Xs[64][40], Ws[4][64][40];
  const int HWi = Hi*Wi;
  const int tid = threadIdx.x;
  const int b = blockIdx.z;
  const int m_base = blockIdx.x*64;
  const int n_base = blockIdx.y*64;
  const int lane = tid & 63, wv = tid >> 6;
  const int quad = lane >> 4, r16 = lane & 15;
  const int m_off = (wv & 1)*32, n_off = (wv >> 1)*32;
  const int srow = tid & 63, skq = tid >> 6;
  const ushort* xrow = X + ((size_t)b*HWi + m_base + srow)*Cin + skq*8;
  const ushort* w0 = Wt4 + ((size_t)0*Cout + n_base + srow)*Cin + skq*8;
  const ushort* w1 = Wt4 + ((size_t)1*Cout + n_base + srow)*Cin + skq*8;
  const ushort* w2 = Wt4 + ((size_t)2*Cout + n_base + srow)*Cin + skq*8;
  const ushort* w3 = Wt4 + ((size_t)3*Cout + n_base + srow)*Cin + skq*8;
  float4v acc[4][4];
  #pragma unroll
  for (int t = 0; t < 4; ++t)
    #pragma unroll
    for (int q = 0; q < 4; ++q) acc[t][q] = float4v{0.f,0.f,0.f,0.f};
  for (int k0 = 0; k0 < Cin; k0 += 32){
    *(uint4v*)&Xs[srow][skq*8]    = *(const uint4v*)(xrow + k0);
    *(uint4v*)&Ws[0][srow][skq*8] = *(const uint4v*)(w0 + k0);
    *(uint4v*)&Ws[1][srow][skq*8] = *(const uint4v*)(w1 + k0);
    *(uint4v*)&Ws[2][srow][skq*8] = *(const uint4v*)(w2 + k0);
    *(uint4v*)&Ws[3][srow][skq*8] = *(const uint4v*)(w3 + k0);
    __syncthreads();
    short8 xf0 = *(const short8*)&Xs[m_off      + r16][quad*8];
    short8 xf1 = *(const short8*)&Xs[m_off + 16 + r16][quad*8];
    #pragma unroll
    for (int t = 0; t < 4; ++t){
      short8 wf0 = *(const short8*)&Ws[t][n_off      + r16][quad*8];
      short8 wf1 = *(const short8*)&Ws[t][n_off + 16 + r16][quad*8];
      acc[t][0] = __builtin_amdgcn_mfma_f32_16x16x32_bf16(wf0, xf0, acc[t][0], 0,0,0);
      acc[t][1] = __builtin_amdgcn_mfma_f32_16x16x32_bf16(wf0, xf1, acc[t][1], 0,0,0);
      acc[t][2] = __builtin_amdgcn_mfma_f32_16x16x32_bf16(wf1, xf0, acc[t][2], 0,0,0);
      acc[t][3] = __builtin_amdgcn_mfma_f32_16x16x32_bf16(wf1, xf1, acc[t][3], 0,0,0);
    }
    __syncthreads();
  }
  const int Wo = 2*Wi, HWo = 4*HWi;
  int co0 = n_base + n_off + quad*4, co1 = co0 + 16;
  float4v bv0 = *(const float4v*)(bias + co0);
  float4v bv1 = *(const float4v*)(bias + co1);
  int px0 = m_base + m_off + r16, px1 = px0 + 16;
  #pragma unroll
  for (int j = 0; j < 2; ++j){
    int p = j ? px1 : px0;
    int r = p / Wi, c = p - r*Wi;
    #pragma unroll
    for (int t = 0; t < 4; ++t){
      int opix = (2*r + (t>>1))*Wo + 2*c + (t&1);
      ushort* o = CC + ((size_t)b*HWo + opix)*Ctot;
      float4v vA = acc[t][0 + j] + bv0;
      float4v vB = acc[t][2 + j] + bv1;
      uint2v pA, pB;
      pA.x = (unsigned)f2b(vA.x) | ((unsigned)f2b(vA.y) << 16);
      pA.y = (unsigned)f2b(vA.z) | ((unsigned)f2b(vA.w) << 16);
      pB.x = (unsigned)f2b(vB.x) | ((unsigned)f2b(vB.y) << 16);
      pB.y = (unsigned)f2b(vB.z) | ((unsigned)f2b(vB.w) << 16);
      *(uint2v*)(o + co0) = pA;
      *(uint2v*)(o + co1) = pB;
    }
  }
}

// NCHW fp32 skip feature -> NHWC bf16 concat channels
__global__ void k_feat2cc(const float* __restrict__ feat, ushort* __restrict__ cc,
                          int Cf, int Coff, int Ctot, int HW){
  __shared__ ushort t[32][33];
  int pb = blockIdx.x*32, cbs = blockIdx.y*32, b = blockIdx.z;
  int tx = threadIdx.x, ty = threadIdx.y;
  #pragma unroll
  for (int i = 0; i < 4; ++i){
    int c = cbs + ty + i*8;
    t[ty + i*8][tx] = f2b(feat[((size_t)(b*Cf) + c)*HW + pb + tx]);
  }
  __syncthreads();
  #pragma unroll
  for (int i = 0; i < 4; ++i){
    int p = pb + ty + i*8;
    cc[((size_t)b*HW + p)*Ctot + Coff + cbs + tx] = t[tx][ty + i*8];
  }
}

// BN stats phase 1; optional second partial input (split-K conv) summed in.
__global__ __launch_bounds__(256) void k_bnstats_nhwc(
    const float* __restrict__ x, const float* __restrict__ x2,
    float* __restrict__ part, int C, int HW){
  const int s = blockIdx.x, tid = threadIdx.x;
  const int R = B_*HW;
  const int chunk = R / BN_S;
  const int L = C >> 2;
  const int G = 256 / L;
  const int c4 = tid % L, g = tid / L;
  float4v a = {}, q = {};
  const size_t base = (size_t)(s*chunk)*C + 4*c4;
  const float* xb = x + base;
  const float* xb2 = x2 ? x2 + base : nullptr;
  for (int r = g; r < chunk; r += G){
    float4v v = *(const float4v*)(xb + (size_t)r*C);
    if (xb2) v += *(const float4v*)(xb2 + (size_t)r*C);
    a += v; q += v*v;
  }
  __shared__ float4v h1[256], h2[256];
  h1[tid] = a; h2[tid] = q;
  __syncthreads();
  if (tid < L){
    float4v ra = h1[tid], rq = h2[tid];
    for (int gg = 1; gg < G; ++gg){ ra += h1[tid + gg*L]; rq += h2[tid + gg*L]; }
    int c0 = 4*c4;
    part[(size_t)(c0+0)*BN_S + s] = ra.x;
    part[(size_t)(c0+1)*BN_S + s] = ra.y;
    part[(size_t)(c0+2)*BN_S + s] = ra.z;
    part[(size_t)(c0+3)*BN_S + s] = ra.w;
    part[(size_t)(C+c0+0)*BN_S + s] = rq.x;
    part[(size_t)(C+c0+1)*BN_S + s] = rq.y;
    part[(size_t)(C+c0+2)*BN_S + s] = rq.z;
    part[(size_t)(C+c0+3)*BN_S + s] = rq.w;
  }
}

__global__ void k_bnfinal(const float* __restrict__ part, const float* __restrict__ g,
                          const float* __restrict__ bb, float* __restrict__ scale,
                          float* __restrict__ shift, int C, int cnt){
  int c = blockIdx.x, t = threadIdx.x;
  __shared__ float r1[256], r2[256];
  r1[t] = part[(size_t)c*BN_S + t]       + part[(size_t)c*BN_S + t + 256];
  r2[t] = part[(size_t)(C + c)*BN_S + t] + part[(size_t)(C + c)*BN_S + t + 256];
  __syncthreads();
  for (int off = 128; off > 0; off >>= 1){
    if (t < off){ r1[t] += r1[t+off]; r2[t] += r2[t+off]; }
    __syncthreads();
  }
  if (t == 0){
    float m = r1[0]/cnt;
    float v = r2[0]/cnt - m*m;
    float sc = g[c]*rsqrtf(v + 1e-5f);
    scale[c] = sc;
    shift[c] = bb[c] - m*sc;
  }
}

// BN apply + ReLU, fp32 NHWC (+optional partial) -> bf16 NHWC
__global__ void k_bnapply_nhwc(const float* __restrict__ x, const float* __restrict__ x2,
                               ushort* __restrict__ y,
                               const float* __restrict__ scale,
                               const float* __restrict__ shift, int C, int n4){
  int i = blockIdx.x*256 + threadIdx.x;
  if (i >= n4) return;
  float4v v = *(const float4v*)(x + (size_t)4*i);
  if (x2) v += *(const float4v*)(x2 + (size_t)4*i);
  int c0 = (4*i) % C;
  float4v sc = *(const float4v*)(scale + c0);
  float4v sh = *(const float4v*)(shift + c0);
  float r0 = fmaxf(v.x*sc.x + sh.x, 0.f);
  float r1 = fmaxf(v.y*sc.y + sh.y, 0.f);
  float r2 = fmaxf(v.z*sc.z + sh.z, 0.f);
  float r3 = fmaxf(v.w*sc.w + sh.w, 0.f);
  uint2v pk;
  pk.x = (unsigned)f2b(r0) | ((unsigned)f2b(r1) << 16);
  pk.y = (unsigned)f2b(r2) | ((unsigned)f2b(r3) << 16);
  *(uint2v*)(y + (size_t)4*i) = pk;
}

// final 1x1 conv (64ch NHWC bf16 -> 1) + sigmoid
__global__ void k_last_nhwc(const ushort* __restrict__ x, const float* __restrict__ lw,
                            const float* __restrict__ lb, float* __restrict__ out){
  __shared__ float wsm[64];
  int tid = threadIdx.x;
  if (tid < 64) wsm[tid] = lw[tid];
  __syncthreads();
  int i = blockIdx.x*256 + tid;
  const uint4v* xr = (const uint4v*)(x + (size_t)i*64);
  float acc = lb[0];
  #pragma unroll
  for (int q = 0; q < 8; ++q){
    uint4v u = xr[q];
    unsigned uu[4] = {u.x, u.y, u.z, u.w};
    #pragma unroll
    for (int k = 0; k < 4; ++k){
      acc += bits2f(uu[k] << 16)          * wsm[q*8 + 2*k];
      acc += bits2f(uu[k] & 0xffff0000u)  * wsm[q*8 + 2*k + 1];
    }
  }
  out[i] = 1.f/(1.f + __expf(-acc));
}

// ---------------- host ----------------
#define MBx 1048576ull

static inline void run_conv16(const ushort* in, const float* w, ushort* W9,
                              float* out, int Cin, int Cout, int H, int W,
                              int ks, hipStream_t stream){
  int total = Cout*Cin;
  k_w9<<<(total+255)/256, 256, 0, stream>>>(w, W9, Cin, Cout);
  k_conv16<<<dim3((H>>4)*(W>>4), Cout/64, B_*ks), 256, 0, stream>>>(in, W9, out, Cin, Cout, H, W, ks);
}

static inline void run_bn(const float* x, const float* x2, ushort* y, float* part,
                          float* scale, float* shift,
                          const float* g, const float* bb, int C, int HW, hipStream_t stream){
  k_bnstats_nhwc<<<BN_S, 256, 0, stream>>>(x, x2, part, C, HW);
  k_bnfinal<<<C, 256, 0, stream>>>(part, g, bb, scale, shift, C, B_*HW);
  int n4 = B_*HW*C/4;
  k_bnapply_nhwc<<<(n4+255)/256, 256, 0, stream>>>(x, x2, y, scale, shift, C, n4);
}

extern "C" void kernel_launch(void* const* d_in, const int* in_sizes, int n_in,
                              void* d_out, int out_size, void* d_ws, size_t ws_size,
                              hipStream_t stream){
  const float* x     = (const float*)d_in[0];
  const float* feat0 = (const float*)d_in[1];
  const float* feat1 = (const float*)d_in[2];
  const float* feat2 = (const float*)d_in[3];
  const float* pos   = (const float*)d_in[4];
  const float* cb    = (const float*)d_in[5];
  const float* ln_g  = (const float*)d_in[6];
  const float* ln_b  = (const float*)d_in[7];
  const float* wqkv  = (const float*)d_in[8];
  const float* wo    = (const float*)d_in[9];
  const float* bo    = (const float*)d_in[10];
  const float* up_w0 = (const float*)d_in[11];
  const float* up_b0 = (const float*)d_in[12];
  const float* cw0a  = (const float*)d_in[13];
  const float* g0a   = (const float*)d_in[14];
  const float* b0a   = (const float*)d_in[15];
  const float* cw0b  = (const float*)d_in[16];
  const float* g0b   = (const float*)d_in[17];
  const float* b0b   = (const float*)d_in[18];
  const float* up_w1 = (const float*)d_in[19];
  const float* up_b1 = (const float*)d_in[20];
  const float* cw1a  = (const float*)d_in[21];
  const float* g1a   = (const float*)d_in[22];
  const float* b1a   = (const float*)d_in[23];
  const float* cw1b  = (const float*)d_in[24];
  const float* g1b   = (const float*)d_in[25];
  const float* b1b   = (const float*)d_in[26];
  const float* up_w2 = (const float*)d_in[27];
  const float* up_b2 = (const float*)d_in[28];
  const float* cw2a  = (const float*)d_in[29];
  const float* g2a   = (const float*)d_in[30];
  const float* b2a   = (const float*)d_in[31];
  const float* cw2b  = (const float*)d_in[32];
  const float* g2b   = (const float*)d_in[33];
  const float* b2b   = (const float*)d_in[34];
  const float* lw    = (const float*)d_in[35];
  const float* lb    = (const float*)d_in[36];

  char* ws = (char*)d_ws;
  // encoder/VQ scratch (region 0..134MB)
  float*  tok     = (float*) (ws);
  ushort* xn_hi   = (ushort*)(ws +  8388608ull);
  ushort* xn_lo   = (ushort*)(ws + 12582912ull);
  float*  qkv     = (float*) (ws + 16777216ull);
  ushort* at_hi   = (ushort*)(ws + 41943040ull);
  ushort* at_lo   = (ushort*)(ws + 46137344ull);
  ushort* tok_hi  = (ushort*)(ws + 50331648ull);
  ushort* tok_lo  = (ushort*)(ws + 54525952ull);
  ushort* Wq_hi   = (ushort*)(ws + 58720256ull);
  ushort* Wq_lo   = (ushort*)(ws + 77594624ull);
  ushort* Wo_hi   = (ushort*)(ws + 96468992ull);
  ushort* Wo_lo   = (ushort*)(ws + 102760448ull);
  ushort* cb_hi   = (ushort*)(ws + 109051904ull);
  ushort* cb_lo   = (ushort*)(ws + 111149056ull);
  float*  cnorm   = (float*) (ws + 113246208ull);
  int*    idx     = (int*)   (ws + 113254400ull);
  float*  d2      = (float*) (ws + 58720256ull);   // overlaps Wq (dead at VQ time)
  // tail: weights + bn scratch + y0
  ushort* W9   = (ushort*)(ws + 134*MBx);
  float* bnsc  = (float*) (ws + 136*MBx + 524288);
  float* bnsh  = (float*) (ws + 136*MBx + 528384);
  ushort* Wt4  = (ushort*)(ws + 137*MBx);
  float* bnp   = (float*) (ws + 138*MBx);
  ushort* y0   = (ushort*)(ws + 139*MBx);
  // decoder ping-pong
  ushort* cc0  = (ushort*)(ws + 146*MBx);
  float*  va0s = (float*) (ws + 34*MBx);    // stage-0a split-K 2-part (33.6MB, dead encoder scratch)
  ushort* xa0  = (ushort*)(ws + 180*MBx);
  float*  vb0s = (float*) (ws + 0*MBx);     // stage-0b split-K 2-part (cc1 written later)
  ushort* xb0  = (ushort*)(ws + 189*MBx);
  ushort* cc1 = (ushort*)(ws + 0*MBx);
  float*  va1 = (float*) (ws + 34*MBx);
  ushort* xa1 = (ushort*)(ws + 68*MBx);
  float*  vb1 = (float*) (ws + 85*MBx);
  ushort* xb1 = (ushort*)(ws + 146*MBx);
  ushort* cc2 = (ushort*)(ws + 0*MBx);
  float*  va2 = (float*) (ws + 67*MBx);
  ushort* xa2 = (ushort*)(ws + 146*MBx);
  float*  vb2 = (float*) (ws + 0*MBx);
  ushort* xb2 = (ushort*)(ws + 67*MBx);

  // ---- weight prep ----
  k_split_t<<<dim3(1536/32, D_/32, DEPTH), dim3(32,8), 0, stream>>>(wqkv, Wq_hi, Wq_lo, D_, 1536);
  k_split_t<<<dim3(D_/32, D_/32, DEPTH), dim3(32,8), 0, stream>>>(wo, Wo_hi, Wo_lo, D_, D_);
  k_split<<<(KCODE*D_+255)/256, 256, 0, stream>>>(cb, cb_hi, cb_lo, KCODE*D_);
  k_cnorm<<<KCODE, 256, 0, stream>>>(cb, cnorm);

  // ---- encoder ----
  k_tok_init<<<dim3(NTOK/32, D_/32, B_), dim3(32,8), 0, stream>>>(x, pos, tok);
  for (int l = 0; l < DEPTH; ++l){
    k_ln_split<<<M_/4, 256, 0, stream>>>(tok, xn_hi, xn_lo, ln_g + l*D_, ln_b + l*D_);
    k_gemm_split<<<dim3(M_/128, 1536/128), 256, 0, stream>>>(
        xn_hi, xn_lo, Wq_hi + (size_t)l*1536*D_, Wq_lo + (size_t)l*1536*D_,
        qkv, nullptr, nullptr, M_, 1536, D_);
    k_attn2<<<dim3(HEADS, B_), 512, 0, stream>>>(qkv, at_hi, at_lo);
    k_gemm_split<<<dim3(M_/128, D_/128), 256, 0, stream>>>(
        at_hi, at_lo, Wo_hi + (size_t)l*D_*D_, Wo_lo + (size_t)l*D_*D_,
        tok, bo + l*D_, tok, M_, D_, D_);
  }

  // ---- VQ ----
  k_split<<<(M_*D_+255)/256, 256, 0, stream>>>(tok, tok_hi, tok_lo, M_*D_);
  k_gemm_split<<<dim3(M_/128, KCODE/128), 256, 0, stream>>>(
      tok_hi, tok_lo, cb_hi, cb_lo, d2, nullptr, nullptr, M_, KCODE, D_);
  k_argmin<<<M_, 256, 0, stream>>>(d2, cnorm, idx);
  k_gather_nhwc<<<(B_*NTOK*D_)/256, 256, 0, stream>>>(cb, idx, y0);

  // ---- decoder stage 0: 16x16 -> 32x32, Ctot=512 (split-K=2 convs) ----
  k_upw<<<dim3(256/32, 512/32), dim3(32,8), 0, stream>>>(up_w0, Wt4, 512, 256);
  k_upconv_nhwc<<<dim3(256/64, 256/64, B_), 256, 0, stream>>>(y0, Wt4, up_b0, cc0, 512, 256, 16, 16, 512);
  k_feat2cc<<<dim3(1024/32, 256/32, B_), dim3(32,8), 0, stream>>>(feat2, cc0, 256, 256, 512, 1024);
  run_conv16(cc0, cw0a, W9, va0s, 512, 256, 32, 32, 2, stream);
  run_bn(va0s, va0s + (size_t)B_*1024*256, xa0, bnp, bnsc, bnsh, g0a, b0a, 256, 1024, stream);
  run_conv16(xa0, cw0b, W9, vb0s, 256, 256, 32, 32, 2, stream);
  run_bn(vb0s, vb0s + (size_t)B_*1024*256, xb0, bnp, bnsc, bnsh, g0b, b0b, 256, 1024, stream);

  // ---- decoder stage 1: 32x32 -> 64x64, Ctot=256 ----
  k_upw<<<dim3(128/32, 256/32), dim3(32,8), 0, stream>>>(up_w1, Wt4, 256, 128);
  k_upconv_nhwc<<<dim3(1024/64, 128/64, B_), 256, 0, stream>>>(xb0, Wt4, up_b1, cc1, 256, 128, 32, 32, 256);
  k_feat2cc<<<dim3(4096/32, 128/32, B_), dim3(32,8), 0, stream>>>(feat1, cc1, 128, 128, 256, 4096);
  run_conv16(cc1, cw1a, W9, va1, 256, 128, 64, 64, 1, stream);
  run_bn(va1, nullptr, xa1, bnp, bnsc, bnsh, g1a, b1a, 128, 4096, stream);
  run_conv16(xa1, cw1b, W9, vb1, 128, 128, 64, 64, 1, stream);
  run_bn(vb1, nullptr, xb1, bnp, bnsc, bnsh, g1b, b1b, 128, 4096, stream);

  // ---- decoder stage 2: 64x64 -> 128x128, Ctot=128 ----
  k_upw<<<dim3(64/32, 128/32), dim3(32,8), 0, stream>>>(up_w2, Wt4, 128, 64);
  k_upconv_nhwc<<<dim3(4096/64, 64/64, B_), 256, 0, stream>>>(xb1, Wt4, up_b2, cc2, 128, 64, 64, 64, 128);
  k_feat2cc<<<dim3(16384/32, 64/32, B_), dim3(32,8), 0, stream>>>(feat0, cc2, 64, 64, 128, 16384);
  run_conv16(cc2, cw2a, W9, va2, 128, 64, 128, 128, 1, stream);
  run_bn(va2, nullptr, xa2, bnp, bnsc, bnsh, g2a, b2a, 64, 16384, stream);
  run_conv16(xa2, cw2b, W9, vb2, 64, 64, 128, 128, 1, stream);
  run_bn(vb2, nullptr, xb2, bnp, bnsc, bnsh, g2b, b2b, 64, 16384, stream);

  // ---- head ----
  k_last_nhwc<<<(B_*16384)/256, 256, 0, stream>>>(xb2, lw, lb, (float*)d_out);
}